// Round 1
// baseline (1295.558 us; speedup 1.0000x reference)
//
#include <hip/hip_runtime.h>

// ---------------------------------------------------------------------------
// GCN (PyG-style) on MI355X.
//   4 layers: h = relu(Ahat (h W) + b) x3, then Ahat (h W_out) + b_out, mean-pool.
//   Ahat = D^-1/2 (A + I) D^-1/2 with degrees on target index.
// Strategy: build CSR by target once per call, factor dis[col] out of the
// segment sum so each node's aggregation is gather+FMA with ONE coalesced
// write (no float atomics on the feature matrix).
// ---------------------------------------------------------------------------

__global__ __launch_bounds__(256) void k_count(const int* __restrict__ col, int E,
                                               int* __restrict__ cnt) {
    int e = blockIdx.x * 256 + threadIdx.x;
    if (e < E) atomicAdd(&cnt[col[e]], 1);
}

// Single-block exclusive scan of cnt -> rowptr, plus dis = rsqrt(deg+1).
__global__ __launch_bounds__(1024) void k_scan(const int* __restrict__ cnt,
                                               int* __restrict__ rowptr,
                                               float* __restrict__ dis, int N) {
    __shared__ int ssum[1024];
    int t = threadIdx.x;
    int strip = (N + 1023) >> 10;
    int s0 = t * strip;
    int s1 = s0 + strip; if (s1 > N) s1 = N;
    int s = 0;
    for (int i = s0; i < s1; ++i) s += cnt[i];
    ssum[t] = s;
    __syncthreads();
    for (int off = 1; off < 1024; off <<= 1) {
        int v = ssum[t];
        int add = (t >= off) ? ssum[t - off] : 0;
        __syncthreads();
        ssum[t] = v + add;
        __syncthreads();
    }
    int run = (t == 0) ? 0 : ssum[t - 1];
    for (int i = s0; i < s1; ++i) {
        int c = cnt[i];
        rowptr[i] = run;
        run += c;
        dis[i] = rsqrtf((float)(c + 1));   // deg includes self-loop, always >0
    }
    if (t == 1023) rowptr[N] = run;
}

__global__ __launch_bounds__(256) void k_fill(const int* __restrict__ row,
                                              const int* __restrict__ col, int E,
                                              const int* __restrict__ rowptr,
                                              int* __restrict__ fill,
                                              int* __restrict__ csr) {
    int e = blockIdx.x * 256 + threadIdx.x;
    if (e < E) {
        int c = col[e];
        int p = rowptr[c] + atomicAdd(&fill[c], 1);
        csr[p] = row[e];
    }
}

// out[N x 128] = hin[N x 128] @ W[128 x 128].  32 rows/block, h tile in LDS,
// W streamed from L1/L2 (64KB, hot).  Thread = 4 rows x 4 cols.
__global__ __launch_bounds__(256) void k_gemm128(const float* __restrict__ hin,
                                                 const float* __restrict__ W,
                                                 float* __restrict__ out, int N) {
    __shared__ float hS[32 * 128];
    int tid = threadIdx.x;
    int row0 = blockIdx.x * 32;
    int nrows = N - row0; if (nrows > 32) nrows = 32;
    const float4* src = (const float4*)(hin + (size_t)row0 * 128);
    float4* dst = (float4*)hS;
    int nvec = nrows * 32;
    #pragma unroll
    for (int i = 0; i < 4; ++i) {
        int idx = tid + 256 * i;
        if (idx < nvec) dst[idx] = src[idx];
    }
    __syncthreads();

    int c4 = (tid & 31) * 4;
    int r0 = (tid >> 5) * 4;
    float4 a0 = {0.f,0.f,0.f,0.f}, a1 = a0, a2 = a0, a3 = a0;
    #pragma unroll 4
    for (int k = 0; k < 128; ++k) {
        float4 w = *(const float4*)&W[k * 128 + c4];
        float h0 = hS[(r0 + 0) * 128 + k];
        float h1 = hS[(r0 + 1) * 128 + k];
        float h2 = hS[(r0 + 2) * 128 + k];
        float h3 = hS[(r0 + 3) * 128 + k];
        a0.x += h0 * w.x; a0.y += h0 * w.y; a0.z += h0 * w.z; a0.w += h0 * w.w;
        a1.x += h1 * w.x; a1.y += h1 * w.y; a1.z += h1 * w.z; a1.w += h1 * w.w;
        a2.x += h2 * w.x; a2.y += h2 * w.y; a2.z += h2 * w.z; a2.w += h2 * w.w;
        a3.x += h3 * w.x; a3.y += h3 * w.y; a3.z += h3 * w.z; a3.w += h3 * w.w;
    }
    float4 acc[4] = {a0, a1, a2, a3};
    #pragma unroll
    for (int i = 0; i < 4; ++i) {
        int row = row0 + r0 + i;
        if (row < N) *(float4*)&out[(size_t)row * 128 + c4] = acc[i];
    }
}

// h_next[v] = maybe_relu( dis[v]*(sum_in dis[r]*tmp[r] + dis[v]*tmp[v]) + b )
// One wave per node; lane holds 2 features (float2) -> 512B coalesced gathers.
__global__ __launch_bounds__(256) void k_agg128(const float* __restrict__ tmp,
                                                float* __restrict__ hout,
                                                const int* __restrict__ rowptr,
                                                const int* __restrict__ csr,
                                                const float* __restrict__ dis,
                                                const float* __restrict__ bias,
                                                int N, int do_relu) {
    int wave = threadIdx.x >> 6;
    int lane = threadIdx.x & 63;
    int v = blockIdx.x * 4 + wave;
    if (v >= N) return;
    int f = lane * 2;
    float dv = dis[v];
    float2 self = *(const float2*)(tmp + (size_t)v * 128 + f);
    float ax = dv * self.x, ay = dv * self.y;   // self-loop term (dis[v]^2 after final scale)
    int s = rowptr[v], e = rowptr[v + 1];
    int i = s;
    for (; i + 2 <= e; i += 2) {
        int r0 = csr[i], r1 = csr[i + 1];
        float w0 = dis[r0], w1 = dis[r1];
        float2 b0 = *(const float2*)(tmp + (size_t)r0 * 128 + f);
        float2 b1 = *(const float2*)(tmp + (size_t)r1 * 128 + f);
        ax += w0 * b0.x + w1 * b1.x;
        ay += w0 * b0.y + w1 * b1.y;
    }
    if (i < e) {
        int r0 = csr[i];
        float w0 = dis[r0];
        float2 b0 = *(const float2*)(tmp + (size_t)r0 * 128 + f);
        ax += w0 * b0.x;
        ay += w0 * b0.y;
    }
    float2 bb = *(const float2*)(bias + f);
    float ox = dv * ax + bb.x;
    float oy = dv * ay + bb.y;
    if (do_relu) { ox = fmaxf(ox, 0.f); oy = fmaxf(oy, 0.f); }
    *(float2*)(hout + (size_t)v * 128 + f) = make_float2(ox, oy);
}

// out[N x C] = hin[N x 128] @ Wout[128 x C], C<=16.  16 rows/block.
__global__ __launch_bounds__(256) void k_gemmout(const float* __restrict__ hin,
                                                 const float* __restrict__ Wout,
                                                 float* __restrict__ out, int N, int C) {
    __shared__ float hS[16 * 128];
    int tid = threadIdx.x;
    int row0 = blockIdx.x * 16;
    int nrows = N - row0; if (nrows > 16) nrows = 16;
    const float4* src = (const float4*)(hin + (size_t)row0 * 128);
    float4* dst = (float4*)hS;
    int nvec = nrows * 32;
    #pragma unroll
    for (int i = 0; i < 2; ++i) {
        int idx = tid + 256 * i;
        if (idx < nvec) dst[idx] = src[idx];
    }
    __syncthreads();
    int c = tid & 15;
    int rr = tid >> 4;
    int row = row0 + rr;
    if (row < N && c < C) {
        float acc = 0.f;
        #pragma unroll 8
        for (int k = 0; k < 128; ++k) acc += hS[rr * 128 + k] * Wout[k * C + c];
        out[(size_t)row * C + c] = acc;
    }
}

// Aggregate last layer (width C) and pool directly: atomicAdd into pooled sums.
__global__ __launch_bounds__(256) void k_aggout(const float* __restrict__ tmp,
                                                const int* __restrict__ rowptr,
                                                const int* __restrict__ csr,
                                                const float* __restrict__ dis,
                                                const float* __restrict__ bout,
                                                const int* __restrict__ batch,
                                                float* __restrict__ pooled,
                                                int N, int C) {
    int tid = threadIdx.x;
    int c = tid & 15;
    int lv = tid >> 4;
    int v = blockIdx.x * 16 + lv;
    if (v >= N || c >= C) return;
    float dv = dis[v];
    float acc = dv * tmp[(size_t)v * C + c];
    int s = rowptr[v], e = rowptr[v + 1];
    for (int i = s; i < e; ++i) {
        int r = csr[i];
        acc += dis[r] * tmp[(size_t)r * C + c];
    }
    float o = dv * acc + bout[c];
    atomicAdd(&pooled[batch[v] * C + c], o);
}

__global__ __launch_bounds__(256) void k_countnodes(const int* __restrict__ batch, int N,
                                                    float* __restrict__ cntf) {
    int v = blockIdx.x * 256 + threadIdx.x;
    if (v < N) atomicAdd(&cntf[batch[v]], 1.0f);
}

__global__ __launch_bounds__(256) void k_final(const float* __restrict__ pooled,
                                               const float* __restrict__ cntf,
                                               float* __restrict__ out, int G, int C) {
    int i = blockIdx.x * 256 + threadIdx.x;
    if (i < G * C) {
        int g = i / C;
        out[i] = pooled[i] / fmaxf(cntf[g], 1.0f);
    }
}

extern "C" void kernel_launch(void* const* d_in, const int* in_sizes, int n_in,
                              void* d_out, int out_size, void* d_ws, size_t ws_size,
                              hipStream_t stream) {
    const float* x      = (const float*)d_in[0];
    const int*   ei     = (const int*)d_in[1];
    const int*   batch  = (const int*)d_in[2];
    const float* W_init = (const float*)d_in[3];
    const float* b_init = (const float*)d_in[4];
    const float* W_h0   = (const float*)d_in[5];
    const float* b_h0   = (const float*)d_in[6];
    const float* W_h1   = (const float*)d_in[7];
    const float* b_h1   = (const float*)d_in[8];
    const float* W_out  = (const float*)d_in[9];
    const float* b_out  = (const float*)d_in[10];

    int N = in_sizes[0] / 128;
    int E = in_sizes[1] / 2;
    int C = in_sizes[10];          // b_out length
    int G = out_size / C;

    size_t off = 0;
    auto alloc = [&](size_t bytes) -> char* {
        char* p = (char*)d_ws + off;
        off += (bytes + 255) & ~(size_t)255;
        return p;
    };
    float* bufA   = (float*)alloc((size_t)N * 128 * 4);
    float* bufB   = (float*)alloc((size_t)N * 128 * 4);
    float* dis    = (float*)alloc((size_t)N * 4);
    int*   rowptr = (int*)  alloc((size_t)(N + 1) * 4);
    int*   csr    = (int*)  alloc((size_t)E * 4);
    size_t zoff   = off;
    int*   cnt    = (int*)  alloc((size_t)N * 4);
    int*   fill   = (int*)  alloc((size_t)N * 4);
    float* pooled = (float*)alloc((size_t)G * C * 4);
    float* cntf   = (float*)alloc((size_t)G * 4);
    size_t zbytes = off - zoff;

    hipMemsetAsync(cnt, 0, zbytes, stream);

    const int* rowi = ei;       // edge_index[0] = source
    const int* coli = ei + E;   // edge_index[1] = target

    int eb = (E + 255) / 256;
    k_count<<<eb, 256, 0, stream>>>(coli, E, cnt);
    k_scan<<<1, 1024, 0, stream>>>(cnt, rowptr, dis, N);
    k_fill<<<eb, 256, 0, stream>>>(rowi, coli, E, rowptr, fill, csr);

    int gb = (N + 31) / 32;
    int ab = (N + 3) / 4;
    int ob = (N + 15) / 16;

    k_gemm128<<<gb, 256, 0, stream>>>(x,    W_init, bufA, N);
    k_agg128 <<<ab, 256, 0, stream>>>(bufA, bufB, rowptr, csr, dis, b_init, N, 1);
    k_gemm128<<<gb, 256, 0, stream>>>(bufB, W_h0,   bufA, N);
    k_agg128 <<<ab, 256, 0, stream>>>(bufA, bufB, rowptr, csr, dis, b_h0, N, 1);
    k_gemm128<<<gb, 256, 0, stream>>>(bufB, W_h1,   bufA, N);
    k_agg128 <<<ab, 256, 0, stream>>>(bufA, bufB, rowptr, csr, dis, b_h1, N, 1);

    k_gemmout<<<ob, 256, 0, stream>>>(bufB, W_out, bufA, N, C);
    k_aggout <<<ob, 256, 0, stream>>>(bufA, rowptr, csr, dis, b_out, batch, pooled, N, C);
    k_countnodes<<<(N + 255) / 256, 256, 0, stream>>>(batch, N, cntf);
    k_final<<<(G * C + 255) / 256, 256, 0, stream>>>(pooled, cntf, (float*)d_out, G, C);
}

// Round 2
// 1072.634 us; speedup vs baseline: 1.2078x; 1.2078x over previous
//
#include <hip/hip_runtime.h>

// ---------------------------------------------------------------------------
// GCN (PyG-style) on MI355X.
//   4 layers: h = relu(Ahat (h W) + b) x3, then Ahat (h W_out) + b_out, mean-pool.
//   Ahat = D^-1/2 (A + I) D^-1/2 with degrees on target index.
// Strategy: build CSR by target once per call, factor dis[col] out of the
// segment sum so each node's aggregation is gather+FMA with ONE coalesced
// write (no float atomics on the feature matrix).
// R1: replaced 233us single-block scan with 3-phase hierarchical scan.
// ---------------------------------------------------------------------------

#define SCAN_BLOCKS 64
#define SCAN_THREADS (SCAN_BLOCKS * 256)   // 16384

__global__ __launch_bounds__(256) void k_count(const int* __restrict__ col, int E,
                                               int* __restrict__ cnt) {
    int e = blockIdx.x * 256 + threadIdx.x;
    if (e < E) atomicAdd(&cnt[col[e]], 1);
}

// Phase 1: per-thread strip sums.
__global__ __launch_bounds__(256) void k_scan1(const int* __restrict__ cnt,
                                               int* __restrict__ tsum, int N) {
    int t = blockIdx.x * 256 + threadIdx.x;
    int strip = (N + SCAN_THREADS - 1) / SCAN_THREADS;
    int s0 = t * strip;
    int s1 = s0 + strip; if (s1 > N) s1 = N;
    int s = 0;
    for (int i = s0; i < s1; ++i) s += cnt[i];
    tsum[t] = s;
}

// Phase 2: single block scans the 16384 partials (exclusive, in place).
__global__ __launch_bounds__(1024) void k_scan2(int* __restrict__ tsum) {
    __shared__ int part[1024];
    int t = threadIdx.x;
    int base = t * 16;
    int local[16];
    int s = 0;
    #pragma unroll
    for (int i = 0; i < 16; ++i) { local[i] = tsum[base + i]; s += local[i]; }
    part[t] = s;
    __syncthreads();
    for (int off = 1; off < 1024; off <<= 1) {
        int v = part[t];
        int add = (t >= off) ? part[t - off] : 0;
        __syncthreads();
        part[t] = v + add;
        __syncthreads();
    }
    int run = (t == 0) ? 0 : part[t - 1];
    #pragma unroll
    for (int i = 0; i < 16; ++i) { int c = local[i]; tsum[base + i] = run; run += c; }
}

// Phase 3: replay strips, write rowptr + dis.
__global__ __launch_bounds__(256) void k_scan3(const int* __restrict__ cnt,
                                               const int* __restrict__ tsum,
                                               int* __restrict__ rowptr,
                                               float* __restrict__ dis, int N) {
    int t = blockIdx.x * 256 + threadIdx.x;
    int strip = (N + SCAN_THREADS - 1) / SCAN_THREADS;
    int s0 = t * strip;
    int s1 = s0 + strip; if (s1 > N) s1 = N;
    int run = tsum[t];
    for (int i = s0; i < s1; ++i) {
        int c = cnt[i];
        rowptr[i] = run;
        run += c;
        dis[i] = rsqrtf((float)(c + 1));   // deg includes self-loop, always >0
    }
    if (t == SCAN_THREADS - 1) rowptr[N] = run;  // tail threads carry the total
}

__global__ __launch_bounds__(256) void k_fill(const int* __restrict__ row,
                                              const int* __restrict__ col, int E,
                                              const int* __restrict__ rowptr,
                                              int* __restrict__ fill,
                                              int* __restrict__ csr) {
    int e = blockIdx.x * 256 + threadIdx.x;
    if (e < E) {
        int c = col[e];
        int p = rowptr[c] + atomicAdd(&fill[c], 1);
        csr[p] = row[e];
    }
}

// out[N x 128] = hin[N x 128] @ W[128 x 128].  32 rows/block, h tile in LDS,
// W streamed from L1/L2 (64KB, hot).  Thread = 4 rows x 4 cols.
__global__ __launch_bounds__(256) void k_gemm128(const float* __restrict__ hin,
                                                 const float* __restrict__ W,
                                                 float* __restrict__ out, int N) {
    __shared__ float hS[32 * 128];
    int tid = threadIdx.x;
    int row0 = blockIdx.x * 32;
    int nrows = N - row0; if (nrows > 32) nrows = 32;
    const float4* src = (const float4*)(hin + (size_t)row0 * 128);
    float4* dst = (float4*)hS;
    int nvec = nrows * 32;
    #pragma unroll
    for (int i = 0; i < 4; ++i) {
        int idx = tid + 256 * i;
        if (idx < nvec) dst[idx] = src[idx];
    }
    __syncthreads();

    int c4 = (tid & 31) * 4;
    int r0 = (tid >> 5) * 4;
    float4 a0 = {0.f,0.f,0.f,0.f}, a1 = a0, a2 = a0, a3 = a0;
    #pragma unroll 4
    for (int k = 0; k < 128; ++k) {
        float4 w = *(const float4*)&W[k * 128 + c4];
        float h0 = hS[(r0 + 0) * 128 + k];
        float h1 = hS[(r0 + 1) * 128 + k];
        float h2 = hS[(r0 + 2) * 128 + k];
        float h3 = hS[(r0 + 3) * 128 + k];
        a0.x += h0 * w.x; a0.y += h0 * w.y; a0.z += h0 * w.z; a0.w += h0 * w.w;
        a1.x += h1 * w.x; a1.y += h1 * w.y; a1.z += h1 * w.z; a1.w += h1 * w.w;
        a2.x += h2 * w.x; a2.y += h2 * w.y; a2.z += h2 * w.z; a2.w += h2 * w.w;
        a3.x += h3 * w.x; a3.y += h3 * w.y; a3.z += h3 * w.z; a3.w += h3 * w.w;
    }
    float4 acc[4] = {a0, a1, a2, a3};
    #pragma unroll
    for (int i = 0; i < 4; ++i) {
        int row = row0 + r0 + i;
        if (row < N) *(float4*)&out[(size_t)row * 128 + c4] = acc[i];
    }
}

// h_next[v] = maybe_relu( dis[v]*(sum_in dis[r]*tmp[r] + dis[v]*tmp[v]) + b )
// One wave per node; lane holds 2 features (float2) -> 512B coalesced gathers.
__global__ __launch_bounds__(256) void k_agg128(const float* __restrict__ tmp,
                                                float* __restrict__ hout,
                                                const int* __restrict__ rowptr,
                                                const int* __restrict__ csr,
                                                const float* __restrict__ dis,
                                                const float* __restrict__ bias,
                                                int N, int do_relu) {
    int wave = threadIdx.x >> 6;
    int lane = threadIdx.x & 63;
    int v = blockIdx.x * 4 + wave;
    if (v >= N) return;
    int f = lane * 2;
    float dv = dis[v];
    float2 self = *(const float2*)(tmp + (size_t)v * 128 + f);
    float ax = dv * self.x, ay = dv * self.y;   // self-loop term (dis[v]^2 after final scale)
    int s = rowptr[v], e = rowptr[v + 1];
    int i = s;
    for (; i + 2 <= e; i += 2) {
        int r0 = csr[i], r1 = csr[i + 1];
        float w0 = dis[r0], w1 = dis[r1];
        float2 b0 = *(const float2*)(tmp + (size_t)r0 * 128 + f);
        float2 b1 = *(const float2*)(tmp + (size_t)r1 * 128 + f);
        ax += w0 * b0.x + w1 * b1.x;
        ay += w0 * b0.y + w1 * b1.y;
    }
    if (i < e) {
        int r0 = csr[i];
        float w0 = dis[r0];
        float2 b0 = *(const float2*)(tmp + (size_t)r0 * 128 + f);
        ax += w0 * b0.x;
        ay += w0 * b0.y;
    }
    float2 bb = *(const float2*)(bias + f);
    float ox = dv * ax + bb.x;
    float oy = dv * ay + bb.y;
    if (do_relu) { ox = fmaxf(ox, 0.f); oy = fmaxf(oy, 0.f); }
    *(float2*)(hout + (size_t)v * 128 + f) = make_float2(ox, oy);
}

// out[N x C] = hin[N x 128] @ Wout[128 x C], C<=16.  16 rows/block.
__global__ __launch_bounds__(256) void k_gemmout(const float* __restrict__ hin,
                                                 const float* __restrict__ Wout,
                                                 float* __restrict__ out, int N, int C) {
    __shared__ float hS[16 * 128];
    int tid = threadIdx.x;
    int row0 = blockIdx.x * 16;
    int nrows = N - row0; if (nrows > 16) nrows = 16;
    const float4* src = (const float4*)(hin + (size_t)row0 * 128);
    float4* dst = (float4*)hS;
    int nvec = nrows * 32;
    #pragma unroll
    for (int i = 0; i < 2; ++i) {
        int idx = tid + 256 * i;
        if (idx < nvec) dst[idx] = src[idx];
    }
    __syncthreads();
    int c = tid & 15;
    int rr = tid >> 4;
    int row = row0 + rr;
    if (row < N && c < C) {
        float acc = 0.f;
        #pragma unroll 8
        for (int k = 0; k < 128; ++k) acc += hS[rr * 128 + k] * Wout[k * C + c];
        out[(size_t)row * C + c] = acc;
    }
}

// Aggregate last layer (width C) and pool directly: atomicAdd into pooled sums.
__global__ __launch_bounds__(256) void k_aggout(const float* __restrict__ tmp,
                                                const int* __restrict__ rowptr,
                                                const int* __restrict__ csr,
                                                const float* __restrict__ dis,
                                                const float* __restrict__ bout,
                                                const int* __restrict__ batch,
                                                float* __restrict__ pooled,
                                                int N, int C) {
    int tid = threadIdx.x;
    int c = tid & 15;
    int lv = tid >> 4;
    int v = blockIdx.x * 16 + lv;
    if (v >= N || c >= C) return;
    float dv = dis[v];
    float acc = dv * tmp[(size_t)v * C + c];
    int s = rowptr[v], e = rowptr[v + 1];
    for (int i = s; i < e; ++i) {
        int r = csr[i];
        acc += dis[r] * tmp[(size_t)r * C + c];
    }
    float o = dv * acc + bout[c];
    atomicAdd(&pooled[batch[v] * C + c], o);
}

__global__ __launch_bounds__(256) void k_countnodes(const int* __restrict__ batch, int N,
                                                    float* __restrict__ cntf) {
    int v = blockIdx.x * 256 + threadIdx.x;
    if (v < N) atomicAdd(&cntf[batch[v]], 1.0f);
}

__global__ __launch_bounds__(256) void k_final(const float* __restrict__ pooled,
                                               const float* __restrict__ cntf,
                                               float* __restrict__ out, int G, int C) {
    int i = blockIdx.x * 256 + threadIdx.x;
    if (i < G * C) {
        int g = i / C;
        out[i] = pooled[i] / fmaxf(cntf[g], 1.0f);
    }
}

extern "C" void kernel_launch(void* const* d_in, const int* in_sizes, int n_in,
                              void* d_out, int out_size, void* d_ws, size_t ws_size,
                              hipStream_t stream) {
    const float* x      = (const float*)d_in[0];
    const int*   ei     = (const int*)d_in[1];
    const int*   batch  = (const int*)d_in[2];
    const float* W_init = (const float*)d_in[3];
    const float* b_init = (const float*)d_in[4];
    const float* W_h0   = (const float*)d_in[5];
    const float* b_h0   = (const float*)d_in[6];
    const float* W_h1   = (const float*)d_in[7];
    const float* b_h1   = (const float*)d_in[8];
    const float* W_out  = (const float*)d_in[9];
    const float* b_out  = (const float*)d_in[10];

    int N = in_sizes[0] / 128;
    int E = in_sizes[1] / 2;
    int C = in_sizes[10];          // b_out length
    int G = out_size / C;

    size_t off = 0;
    auto alloc = [&](size_t bytes) -> char* {
        char* p = (char*)d_ws + off;
        off += (bytes + 255) & ~(size_t)255;
        return p;
    };
    float* bufA   = (float*)alloc((size_t)N * 128 * 4);
    float* bufB   = (float*)alloc((size_t)N * 128 * 4);
    float* dis    = (float*)alloc((size_t)N * 4);
    int*   rowptr = (int*)  alloc((size_t)(N + 1) * 4);
    int*   csr    = (int*)  alloc((size_t)E * 4);
    int*   tsum   = (int*)  alloc((size_t)SCAN_THREADS * 4);
    size_t zoff   = off;
    int*   cnt    = (int*)  alloc((size_t)N * 4);
    int*   fill   = (int*)  alloc((size_t)N * 4);
    float* pooled = (float*)alloc((size_t)G * C * 4);
    float* cntf   = (float*)alloc((size_t)G * 4);
    size_t zbytes = off - zoff;

    hipMemsetAsync(cnt, 0, zbytes, stream);

    const int* rowi = ei;       // edge_index[0] = source
    const int* coli = ei + E;   // edge_index[1] = target

    int eb = (E + 255) / 256;
    k_count<<<eb, 256, 0, stream>>>(coli, E, cnt);
    k_scan1<<<SCAN_BLOCKS, 256, 0, stream>>>(cnt, tsum, N);
    k_scan2<<<1, 1024, 0, stream>>>(tsum);
    k_scan3<<<SCAN_BLOCKS, 256, 0, stream>>>(cnt, tsum, rowptr, dis, N);
    k_fill<<<eb, 256, 0, stream>>>(rowi, coli, E, rowptr, fill, csr);

    int gb = (N + 31) / 32;
    int ab = (N + 3) / 4;
    int ob = (N + 15) / 16;

    k_gemm128<<<gb, 256, 0, stream>>>(x,    W_init, bufA, N);
    k_agg128 <<<ab, 256, 0, stream>>>(bufA, bufB, rowptr, csr, dis, b_init, N, 1);
    k_gemm128<<<gb, 256, 0, stream>>>(bufB, W_h0,   bufA, N);
    k_agg128 <<<ab, 256, 0, stream>>>(bufA, bufB, rowptr, csr, dis, b_h0, N, 1);
    k_gemm128<<<gb, 256, 0, stream>>>(bufB, W_h1,   bufA, N);
    k_agg128 <<<ab, 256, 0, stream>>>(bufA, bufB, rowptr, csr, dis, b_h1, N, 1);

    k_gemmout<<<ob, 256, 0, stream>>>(bufB, W_out, bufA, N, C);
    k_aggout <<<ob, 256, 0, stream>>>(bufA, rowptr, csr, dis, b_out, batch, pooled, N, C);
    k_countnodes<<<(N + 255) / 256, 256, 0, stream>>>(batch, N, cntf);
    k_final<<<(G * C + 255) / 256, 256, 0, stream>>>(pooled, cntf, (float*)d_out, G, C);
}

// Round 3
// 1003.517 us; speedup vs baseline: 1.2910x; 1.0689x over previous
//
#include <hip/hip_runtime.h>

// ---------------------------------------------------------------------------
// GCN (PyG-style) on MI355X.
//   h = relu(Ahat (h W) + b) x3, then Ahat (h W_out) + b_out, mean-pool.
//   Ahat = D^-1/2 (A+I) D^-1/2, degrees on target index.
// R1: hierarchical scan.
// R2: algebraic fusion: Ahat (h W) = (Ahat h) W, so gather+GEMM fuse into one
//     kernel per hidden layer. Gather fills a 32x128 LDS tile of s = Ahat h,
//     then the register-blocked GEMM runs from LDS. Kills the tmp roundtrip
//     (100MB/layer) and hides GEMM FMA under gather memory stalls.
// ---------------------------------------------------------------------------

#define SCAN_BLOCKS 64
#define SCAN_THREADS (SCAN_BLOCKS * 256)   // 16384

__global__ __launch_bounds__(256) void k_count(const int* __restrict__ col, int E,
                                               int* __restrict__ cnt) {
    int e = blockIdx.x * 256 + threadIdx.x;
    if (e < E) atomicAdd(&cnt[col[e]], 1);
}

__global__ __launch_bounds__(256) void k_scan1(const int* __restrict__ cnt,
                                               int* __restrict__ tsum, int N) {
    int t = blockIdx.x * 256 + threadIdx.x;
    int strip = (N + SCAN_THREADS - 1) / SCAN_THREADS;
    int s0 = t * strip;
    int s1 = s0 + strip; if (s1 > N) s1 = N;
    int s = 0;
    for (int i = s0; i < s1; ++i) s += cnt[i];
    tsum[t] = s;
}

__global__ __launch_bounds__(1024) void k_scan2(int* __restrict__ tsum) {
    __shared__ int part[1024];
    int t = threadIdx.x;
    int base = t * 16;
    int local[16];
    int s = 0;
    #pragma unroll
    for (int i = 0; i < 16; ++i) { local[i] = tsum[base + i]; s += local[i]; }
    part[t] = s;
    __syncthreads();
    for (int off = 1; off < 1024; off <<= 1) {
        int v = part[t];
        int add = (t >= off) ? part[t - off] : 0;
        __syncthreads();
        part[t] = v + add;
        __syncthreads();
    }
    int run = (t == 0) ? 0 : part[t - 1];
    #pragma unroll
    for (int i = 0; i < 16; ++i) { int c = local[i]; tsum[base + i] = run; run += c; }
}

__global__ __launch_bounds__(256) void k_scan3(const int* __restrict__ cnt,
                                               const int* __restrict__ tsum,
                                               int* __restrict__ rowptr,
                                               float* __restrict__ dis, int N) {
    int t = blockIdx.x * 256 + threadIdx.x;
    int strip = (N + SCAN_THREADS - 1) / SCAN_THREADS;
    int s0 = t * strip;
    int s1 = s0 + strip; if (s1 > N) s1 = N;
    int run = tsum[t];
    for (int i = s0; i < s1; ++i) {
        int c = cnt[i];
        rowptr[i] = run;
        run += c;
        dis[i] = rsqrtf((float)(c + 1));
    }
    if (t == SCAN_THREADS - 1) rowptr[N] = run;
}

__global__ __launch_bounds__(256) void k_fill(const int* __restrict__ row,
                                              const int* __restrict__ col, int E,
                                              const int* __restrict__ rowptr,
                                              int* __restrict__ fill,
                                              int* __restrict__ csr) {
    int e = blockIdx.x * 256 + threadIdx.x;
    if (e < E) {
        int c = col[e];
        int p = rowptr[c] + atomicAdd(&fill[c], 1);
        csr[p] = row[e];
    }
}

// Fused hidden layer: hout = relu( (Ahat hin) W + b ).
// Phase A: 4 waves x 8 nodes gather s = dv*(sum dis[r] h[r] + dv h[v]) -> LDS.
// Phase B: 32x128 @ 128x128 register-blocked GEMM from LDS, bias+relu.
__global__ __launch_bounds__(256) void k_fused(const float* __restrict__ hin,
                                               const float* __restrict__ W,
                                               const float* __restrict__ bias,
                                               float* __restrict__ hout,
                                               const int* __restrict__ rowptr,
                                               const int* __restrict__ csr,
                                               const float* __restrict__ dis,
                                               int N) {
    __shared__ float hS[32 * 128];
    int tid = threadIdx.x;
    int wave = tid >> 6;
    int lane = tid & 63;
    int f = lane * 2;
    int row0 = blockIdx.x * 32;

    // ---- Phase A: gather-aggregate 8 nodes per wave ----
    for (int j = 0; j < 8; ++j) {
        int v = row0 + wave * 8 + j;
        if (v >= N) break;
        float dv = dis[v];
        float2 self = *(const float2*)(hin + (size_t)v * 128 + f);
        float ax = dv * self.x, ay = dv * self.y;
        int s = rowptr[v], e = rowptr[v + 1];
        int i = s;
        for (; i + 4 <= e; i += 4) {
            int r0 = csr[i], r1 = csr[i + 1], r2 = csr[i + 2], r3 = csr[i + 3];
            float w0 = dis[r0], w1 = dis[r1], w2 = dis[r2], w3 = dis[r3];
            float2 b0 = *(const float2*)(hin + (size_t)r0 * 128 + f);
            float2 b1 = *(const float2*)(hin + (size_t)r1 * 128 + f);
            float2 b2 = *(const float2*)(hin + (size_t)r2 * 128 + f);
            float2 b3 = *(const float2*)(hin + (size_t)r3 * 128 + f);
            ax += w0 * b0.x + w1 * b1.x + w2 * b2.x + w3 * b3.x;
            ay += w0 * b0.y + w1 * b1.y + w2 * b2.y + w3 * b3.y;
        }
        for (; i < e; ++i) {
            int r0 = csr[i];
            float w0 = dis[r0];
            float2 b0 = *(const float2*)(hin + (size_t)r0 * 128 + f);
            ax += w0 * b0.x;
            ay += w0 * b0.y;
        }
        *(float2*)&hS[(wave * 8 + j) * 128 + f] = make_float2(dv * ax, dv * ay);
    }
    __syncthreads();

    // ---- Phase B: (s tile) @ W, bias + relu ----
    int c4 = (tid & 31) * 4;
    int r0 = (tid >> 5) * 4;
    float4 a0 = {0.f,0.f,0.f,0.f}, a1 = a0, a2 = a0, a3 = a0;
    #pragma unroll 4
    for (int k = 0; k < 128; ++k) {
        float4 w = *(const float4*)&W[k * 128 + c4];
        float h0 = hS[(r0 + 0) * 128 + k];
        float h1 = hS[(r0 + 1) * 128 + k];
        float h2 = hS[(r0 + 2) * 128 + k];
        float h3 = hS[(r0 + 3) * 128 + k];
        a0.x += h0 * w.x; a0.y += h0 * w.y; a0.z += h0 * w.z; a0.w += h0 * w.w;
        a1.x += h1 * w.x; a1.y += h1 * w.y; a1.z += h1 * w.z; a1.w += h1 * w.w;
        a2.x += h2 * w.x; a2.y += h2 * w.y; a2.z += h2 * w.z; a2.w += h2 * w.w;
        a3.x += h3 * w.x; a3.y += h3 * w.y; a3.z += h3 * w.z; a3.w += h3 * w.w;
    }
    float4 bb = *(const float4*)&bias[c4];
    float4 acc[4] = {a0, a1, a2, a3};
    #pragma unroll
    for (int i = 0; i < 4; ++i) {
        int row = row0 + r0 + i;
        if (row < N) {
            float4 o;
            o.x = fmaxf(acc[i].x + bb.x, 0.f);
            o.y = fmaxf(acc[i].y + bb.y, 0.f);
            o.z = fmaxf(acc[i].z + bb.z, 0.f);
            o.w = fmaxf(acc[i].w + bb.w, 0.f);
            *(float4*)&hout[(size_t)row * 128 + c4] = o;
        }
    }
}

// out[N x C] = hin[N x 128] @ Wout[128 x C], C<=16.  16 rows/block.
__global__ __launch_bounds__(256) void k_gemmout(const float* __restrict__ hin,
                                                 const float* __restrict__ Wout,
                                                 float* __restrict__ out, int N, int C) {
    __shared__ float hS[16 * 128];
    int tid = threadIdx.x;
    int row0 = blockIdx.x * 16;
    int nrows = N - row0; if (nrows > 16) nrows = 16;
    const float4* src = (const float4*)(hin + (size_t)row0 * 128);
    float4* dst = (float4*)hS;
    int nvec = nrows * 32;
    #pragma unroll
    for (int i = 0; i < 2; ++i) {
        int idx = tid + 256 * i;
        if (idx < nvec) dst[idx] = src[idx];
    }
    __syncthreads();
    int c = tid & 15;
    int rr = tid >> 4;
    int row = row0 + rr;
    if (row < N && c < C) {
        float acc = 0.f;
        #pragma unroll 8
        for (int k = 0; k < 128; ++k) acc += hS[rr * 128 + k] * Wout[k * C + c];
        out[(size_t)row * C + c] = acc;
    }
}

// Aggregate last layer (width C) and pool directly.
__global__ __launch_bounds__(256) void k_aggout(const float* __restrict__ tmp,
                                                const int* __restrict__ rowptr,
                                                const int* __restrict__ csr,
                                                const float* __restrict__ dis,
                                                const float* __restrict__ bout,
                                                const int* __restrict__ batch,
                                                float* __restrict__ pooled,
                                                int N, int C) {
    int tid = threadIdx.x;
    int c = tid & 15;
    int lv = tid >> 4;
    int v = blockIdx.x * 16 + lv;
    if (v >= N || c >= C) return;
    float dv = dis[v];
    float acc = dv * tmp[(size_t)v * C + c];
    int s = rowptr[v], e = rowptr[v + 1];
    for (int i = s; i < e; ++i) {
        int r = csr[i];
        acc += dis[r] * tmp[(size_t)r * C + c];
    }
    float o = dv * acc + bout[c];
    atomicAdd(&pooled[batch[v] * C + c], o);
}

__global__ __launch_bounds__(256) void k_countnodes(const int* __restrict__ batch, int N,
                                                    float* __restrict__ cntf) {
    int v = blockIdx.x * 256 + threadIdx.x;
    if (v < N) atomicAdd(&cntf[batch[v]], 1.0f);
}

__global__ __launch_bounds__(256) void k_final(const float* __restrict__ pooled,
                                               const float* __restrict__ cntf,
                                               float* __restrict__ out, int G, int C) {
    int i = blockIdx.x * 256 + threadIdx.x;
    if (i < G * C) {
        int g = i / C;
        out[i] = pooled[i] / fmaxf(cntf[g], 1.0f);
    }
}

extern "C" void kernel_launch(void* const* d_in, const int* in_sizes, int n_in,
                              void* d_out, int out_size, void* d_ws, size_t ws_size,
                              hipStream_t stream) {
    const float* x      = (const float*)d_in[0];
    const int*   ei     = (const int*)d_in[1];
    const int*   batch  = (const int*)d_in[2];
    const float* W_init = (const float*)d_in[3];
    const float* b_init = (const float*)d_in[4];
    const float* W_h0   = (const float*)d_in[5];
    const float* b_h0   = (const float*)d_in[6];
    const float* W_h1   = (const float*)d_in[7];
    const float* b_h1   = (const float*)d_in[8];
    const float* W_out  = (const float*)d_in[9];
    const float* b_out  = (const float*)d_in[10];

    int N = in_sizes[0] / 128;
    int E = in_sizes[1] / 2;
    int C = in_sizes[10];
    int G = out_size / C;

    size_t off = 0;
    auto alloc = [&](size_t bytes) -> char* {
        char* p = (char*)d_ws + off;
        off += (bytes + 255) & ~(size_t)255;
        return p;
    };
    float* bufA   = (float*)alloc((size_t)N * 128 * 4);
    float* bufB   = (float*)alloc((size_t)N * 128 * 4);
    float* dis    = (float*)alloc((size_t)N * 4);
    int*   rowptr = (int*)  alloc((size_t)(N + 1) * 4);
    int*   csr    = (int*)  alloc((size_t)E * 4);
    int*   tsum   = (int*)  alloc((size_t)SCAN_THREADS * 4);
    size_t zoff   = off;
    int*   cnt    = (int*)  alloc((size_t)N * 4);
    int*   fill   = (int*)  alloc((size_t)N * 4);
    float* pooled = (float*)alloc((size_t)G * C * 4);
    float* cntf   = (float*)alloc((size_t)G * 4);
    size_t zbytes = off - zoff;

    hipMemsetAsync(cnt, 0, zbytes, stream);

    const int* rowi = ei;       // edge_index[0] = source
    const int* coli = ei + E;   // edge_index[1] = target

    int eb = (E + 255) / 256;
    k_count<<<eb, 256, 0, stream>>>(coli, E, cnt);
    k_scan1<<<SCAN_BLOCKS, 256, 0, stream>>>(cnt, tsum, N);
    k_scan2<<<1, 1024, 0, stream>>>(tsum);
    k_scan3<<<SCAN_BLOCKS, 256, 0, stream>>>(cnt, tsum, rowptr, dis, N);
    k_fill<<<eb, 256, 0, stream>>>(rowi, coli, E, rowptr, fill, csr);

    int fb = (N + 31) / 32;
    int ob = (N + 15) / 16;

    // hidden layers: hout = relu((Ahat hin) W + b)
    k_fused<<<fb, 256, 0, stream>>>(x,    W_init, b_init, bufA, rowptr, csr, dis, N);
    k_fused<<<fb, 256, 0, stream>>>(bufA, W_h0,   b_h0,   bufB, rowptr, csr, dis, N);
    k_fused<<<fb, 256, 0, stream>>>(bufB, W_h1,   b_h1,   bufA, rowptr, csr, dis, N);

    // last layer: transform-first (narrow gather), then aggregate+pool
    k_gemmout<<<ob, 256, 0, stream>>>(bufA, W_out, bufB, N, C);
    k_aggout <<<ob, 256, 0, stream>>>(bufB, rowptr, csr, dis, b_out, batch, pooled, N, C);
    k_countnodes<<<(N + 255) / 256, 256, 0, stream>>>(batch, N, cntf);
    k_final<<<(G * C + 255) / 256, 256, 0, stream>>>(pooled, cntf, (float*)d_out, G, C);
}

// Round 4
// 902.125 us; speedup vs baseline: 1.4361x; 1.1124x over previous
//
#include <hip/hip_runtime.h>

// ---------------------------------------------------------------------------
// GCN (PyG-style) on MI355X.
//   h = relu(Ahat (h W) + b) x3, then Ahat (h W_out) + b_out, mean-pool.
//   Ahat = D^-1/2 (A+I) D^-1/2, degrees on target index.
// R1: hierarchical scan (233us single-block scan -> ~10us).
// R2: algebraic fusion Ahat(hW) = (Ahat h)W -> gather+GEMM in one kernel.
// R3: bf16 storage for inter-layer activations: gather bytes halve
//     (512B -> 256B per row, one dword/lane), all math stays fp32.
// ---------------------------------------------------------------------------

#define SCAN_BLOCKS 64
#define SCAN_THREADS (SCAN_BLOCKS * 256)   // 16384

typedef unsigned short u16;
typedef unsigned int   u32;

static __device__ __forceinline__ u16 f2bf(float x) {
    u32 u = __float_as_uint(x);
    u32 r = (u + 0x7fffu + ((u >> 16) & 1u)) >> 16;   // RNE
    return (u16)r;
}
static __device__ __forceinline__ float bf_lo(u32 p) { return __uint_as_float(p << 16); }
static __device__ __forceinline__ float bf_hi(u32 p) { return __uint_as_float(p & 0xffff0000u); }

__global__ __launch_bounds__(256) void k_count(const int* __restrict__ col, int E,
                                               int* __restrict__ cnt) {
    int e = blockIdx.x * 256 + threadIdx.x;
    if (e < E) atomicAdd(&cnt[col[e]], 1);
}

__global__ __launch_bounds__(256) void k_scan1(const int* __restrict__ cnt,
                                               int* __restrict__ tsum, int N) {
    int t = blockIdx.x * 256 + threadIdx.x;
    int strip = (N + SCAN_THREADS - 1) / SCAN_THREADS;
    int s0 = t * strip;
    int s1 = s0 + strip; if (s1 > N) s1 = N;
    int s = 0;
    for (int i = s0; i < s1; ++i) s += cnt[i];
    tsum[t] = s;
}

__global__ __launch_bounds__(1024) void k_scan2(int* __restrict__ tsum) {
    __shared__ int part[1024];
    int t = threadIdx.x;
    int base = t * 16;
    int local[16];
    int s = 0;
    #pragma unroll
    for (int i = 0; i < 16; ++i) { local[i] = tsum[base + i]; s += local[i]; }
    part[t] = s;
    __syncthreads();
    for (int off = 1; off < 1024; off <<= 1) {
        int v = part[t];
        int add = (t >= off) ? part[t - off] : 0;
        __syncthreads();
        part[t] = v + add;
        __syncthreads();
    }
    int run = (t == 0) ? 0 : part[t - 1];
    #pragma unroll
    for (int i = 0; i < 16; ++i) { int c = local[i]; tsum[base + i] = run; run += c; }
}

__global__ __launch_bounds__(256) void k_scan3(const int* __restrict__ cnt,
                                               const int* __restrict__ tsum,
                                               int* __restrict__ rowptr,
                                               float* __restrict__ dis, int N) {
    int t = blockIdx.x * 256 + threadIdx.x;
    int strip = (N + SCAN_THREADS - 1) / SCAN_THREADS;
    int s0 = t * strip;
    int s1 = s0 + strip; if (s1 > N) s1 = N;
    int run = tsum[t];
    for (int i = s0; i < s1; ++i) {
        int c = cnt[i];
        rowptr[i] = run;
        run += c;
        dis[i] = rsqrtf((float)(c + 1));
    }
    if (t == SCAN_THREADS - 1) rowptr[N] = run;
}

__global__ __launch_bounds__(256) void k_fill(const int* __restrict__ row,
                                              const int* __restrict__ col, int E,
                                              const int* __restrict__ rowptr,
                                              int* __restrict__ fill,
                                              int* __restrict__ csr) {
    int e = blockIdx.x * 256 + threadIdx.x;
    if (e < E) {
        int c = col[e];
        int p = rowptr[c] + atomicAdd(&fill[c], 1);
        csr[p] = row[e];
    }
}

// fp32 -> bf16 cast of the input features (once).
__global__ __launch_bounds__(256) void k_cast(const float* __restrict__ src,
                                              u16* __restrict__ dst, int n4) {
    int i = blockIdx.x * 256 + threadIdx.x;
    if (i < n4) {
        float4 v = ((const float4*)src)[i];
        ushort4 o;
        o.x = f2bf(v.x); o.y = f2bf(v.y); o.z = f2bf(v.z); o.w = f2bf(v.w);
        ((ushort4*)dst)[i] = o;
    }
}

// Fused hidden layer: hout = bf16( relu( (Ahat hin) W + b ) ), hin bf16.
// Phase A: 4 waves x 8 nodes gather s = dv*(sum dis[r] h[r] + dv h[v]) -> LDS (fp32).
// Phase B: 32x128 @ 128x128 register-blocked fp32 GEMM from LDS, bias+relu, bf16 store.
__global__ __launch_bounds__(256) void k_fused(const u16* __restrict__ hin,
                                               const float* __restrict__ W,
                                               const float* __restrict__ bias,
                                               u16* __restrict__ hout,
                                               const int* __restrict__ rowptr,
                                               const int* __restrict__ csr,
                                               const float* __restrict__ dis,
                                               int N) {
    __shared__ float hS[32 * 128];
    int tid = threadIdx.x;
    int wave = tid >> 6;
    int lane = tid & 63;
    int row0 = blockIdx.x * 32;
    const u32* hin32 = (const u32*)hin;   // row stride 64 dwords

    // ---- Phase A: gather-aggregate 8 nodes per wave ----
    for (int j = 0; j < 8; ++j) {
        int v = row0 + wave * 8 + j;
        if (v >= N) break;
        float dv = dis[v];
        u32 ps = hin32[(size_t)v * 64 + lane];
        float ax = dv * bf_lo(ps), ay = dv * bf_hi(ps);
        int s = rowptr[v], e = rowptr[v + 1];
        int i = s;
        for (; i + 8 <= e; i += 8) {
            int r0 = csr[i],     r1 = csr[i + 1], r2 = csr[i + 2], r3 = csr[i + 3];
            int r4 = csr[i + 4], r5 = csr[i + 5], r6 = csr[i + 6], r7 = csr[i + 7];
            u32 p0 = hin32[(size_t)r0 * 64 + lane];
            u32 p1 = hin32[(size_t)r1 * 64 + lane];
            u32 p2 = hin32[(size_t)r2 * 64 + lane];
            u32 p3 = hin32[(size_t)r3 * 64 + lane];
            u32 p4 = hin32[(size_t)r4 * 64 + lane];
            u32 p5 = hin32[(size_t)r5 * 64 + lane];
            u32 p6 = hin32[(size_t)r6 * 64 + lane];
            u32 p7 = hin32[(size_t)r7 * 64 + lane];
            float w0 = dis[r0], w1 = dis[r1], w2 = dis[r2], w3 = dis[r3];
            float w4 = dis[r4], w5 = dis[r5], w6 = dis[r6], w7 = dis[r7];
            ax += w0 * bf_lo(p0) + w1 * bf_lo(p1) + w2 * bf_lo(p2) + w3 * bf_lo(p3);
            ay += w0 * bf_hi(p0) + w1 * bf_hi(p1) + w2 * bf_hi(p2) + w3 * bf_hi(p3);
            ax += w4 * bf_lo(p4) + w5 * bf_lo(p5) + w6 * bf_lo(p6) + w7 * bf_lo(p7);
            ay += w4 * bf_hi(p4) + w5 * bf_hi(p5) + w6 * bf_hi(p6) + w7 * bf_hi(p7);
        }
        for (; i < e; ++i) {
            int r0 = csr[i];
            float w0 = dis[r0];
            u32 p0 = hin32[(size_t)r0 * 64 + lane];
            ax += w0 * bf_lo(p0);
            ay += w0 * bf_hi(p0);
        }
        *(float2*)&hS[(wave * 8 + j) * 128 + lane * 2] = make_float2(dv * ax, dv * ay);
    }
    __syncthreads();

    // ---- Phase B: (s tile) @ W, bias + relu, bf16 store ----
    int c4 = (tid & 31) * 4;
    int r0 = (tid >> 5) * 4;
    float4 a0 = {0.f,0.f,0.f,0.f}, a1 = a0, a2 = a0, a3 = a0;
    #pragma unroll 4
    for (int k = 0; k < 128; ++k) {
        float4 w = *(const float4*)&W[k * 128 + c4];
        float h0 = hS[(r0 + 0) * 128 + k];
        float h1 = hS[(r0 + 1) * 128 + k];
        float h2 = hS[(r0 + 2) * 128 + k];
        float h3 = hS[(r0 + 3) * 128 + k];
        a0.x += h0 * w.x; a0.y += h0 * w.y; a0.z += h0 * w.z; a0.w += h0 * w.w;
        a1.x += h1 * w.x; a1.y += h1 * w.y; a1.z += h1 * w.z; a1.w += h1 * w.w;
        a2.x += h2 * w.x; a2.y += h2 * w.y; a2.z += h2 * w.z; a2.w += h2 * w.w;
        a3.x += h3 * w.x; a3.y += h3 * w.y; a3.z += h3 * w.z; a3.w += h3 * w.w;
    }
    float4 bb = *(const float4*)&bias[c4];
    float4 acc[4] = {a0, a1, a2, a3};
    #pragma unroll
    for (int i = 0; i < 4; ++i) {
        int row = row0 + r0 + i;
        if (row < N) {
            ushort4 o;
            o.x = f2bf(fmaxf(acc[i].x + bb.x, 0.f));
            o.y = f2bf(fmaxf(acc[i].y + bb.y, 0.f));
            o.z = f2bf(fmaxf(acc[i].z + bb.z, 0.f));
            o.w = f2bf(fmaxf(acc[i].w + bb.w, 0.f));
            *(ushort4*)&hout[(size_t)row * 128 + c4] = o;
        }
    }
}

// out[N x C] = bf16 hin[N x 128] @ Wout[128 x C], C<=16.  16 rows/block.
__global__ __launch_bounds__(256) void k_gemmout(const u16* __restrict__ hin,
                                                 const float* __restrict__ Wout,
                                                 float* __restrict__ out, int N, int C) {
    __shared__ float hS[16 * 128];
    int tid = threadIdx.x;
    int row0 = blockIdx.x * 16;
    int nrows = N - row0; if (nrows > 16) nrows = 16;
    const u32* src = (const u32*)(hin + (size_t)row0 * 128);
    int nvec = nrows * 64;   // dwords
    #pragma unroll
    for (int i = 0; i < 4; ++i) {
        int idx = tid + 256 * i;
        if (idx < nvec) {
            u32 p = src[idx];
            int r = idx >> 6, j = idx & 63;
            hS[r * 128 + 2 * j]     = bf_lo(p);
            hS[r * 128 + 2 * j + 1] = bf_hi(p);
        }
    }
    __syncthreads();
    int c = tid & 15;
    int rr = tid >> 4;
    int row = row0 + rr;
    if (row < N && c < C) {
        float acc = 0.f;
        #pragma unroll 8
        for (int k = 0; k < 128; ++k) acc += hS[rr * 128 + k] * Wout[k * C + c];
        out[(size_t)row * C + c] = acc;
    }
}

// Aggregate last layer (width C) and pool directly.
__global__ __launch_bounds__(256) void k_aggout(const float* __restrict__ tmp,
                                                const int* __restrict__ rowptr,
                                                const int* __restrict__ csr,
                                                const float* __restrict__ dis,
                                                const float* __restrict__ bout,
                                                const int* __restrict__ batch,
                                                float* __restrict__ pooled,
                                                int N, int C) {
    int tid = threadIdx.x;
    int c = tid & 15;
    int lv = tid >> 4;
    int v = blockIdx.x * 16 + lv;
    if (v >= N || c >= C) return;
    float dv = dis[v];
    float acc = dv * tmp[(size_t)v * C + c];
    int s = rowptr[v], e = rowptr[v + 1];
    for (int i = s; i < e; ++i) {
        int r = csr[i];
        acc += dis[r] * tmp[(size_t)r * C + c];
    }
    float o = dv * acc + bout[c];
    atomicAdd(&pooled[batch[v] * C + c], o);
}

__global__ __launch_bounds__(256) void k_countnodes(const int* __restrict__ batch, int N,
                                                    float* __restrict__ cntf) {
    int v = blockIdx.x * 256 + threadIdx.x;
    if (v < N) atomicAdd(&cntf[batch[v]], 1.0f);
}

__global__ __launch_bounds__(256) void k_final(const float* __restrict__ pooled,
                                               const float* __restrict__ cntf,
                                               float* __restrict__ out, int G, int C) {
    int i = blockIdx.x * 256 + threadIdx.x;
    if (i < G * C) {
        int g = i / C;
        out[i] = pooled[i] / fmaxf(cntf[g], 1.0f);
    }
}

extern "C" void kernel_launch(void* const* d_in, const int* in_sizes, int n_in,
                              void* d_out, int out_size, void* d_ws, size_t ws_size,
                              hipStream_t stream) {
    const float* x      = (const float*)d_in[0];
    const int*   ei     = (const int*)d_in[1];
    const int*   batch  = (const int*)d_in[2];
    const float* W_init = (const float*)d_in[3];
    const float* b_init = (const float*)d_in[4];
    const float* W_h0   = (const float*)d_in[5];
    const float* b_h0   = (const float*)d_in[6];
    const float* W_h1   = (const float*)d_in[7];
    const float* b_h1   = (const float*)d_in[8];
    const float* W_out  = (const float*)d_in[9];
    const float* b_out  = (const float*)d_in[10];

    int N = in_sizes[0] / 128;
    int E = in_sizes[1] / 2;
    int C = in_sizes[10];
    int G = out_size / C;

    size_t off = 0;
    auto alloc = [&](size_t bytes) -> char* {
        char* p = (char*)d_ws + off;
        off += (bytes + 255) & ~(size_t)255;
        return p;
    };
    u16*   bufX   = (u16*)  alloc((size_t)N * 128 * 2);
    u16*   bufA   = (u16*)  alloc((size_t)N * 128 * 2);
    u16*   bufB   = (u16*)  alloc((size_t)N * 128 * 2);
    float* tmpC   = (float*)alloc((size_t)N * C * 4);
    float* dis    = (float*)alloc((size_t)N * 4);
    int*   rowptr = (int*)  alloc((size_t)(N + 1) * 4);
    int*   csr    = (int*)  alloc((size_t)E * 4);
    int*   tsum   = (int*)  alloc((size_t)SCAN_THREADS * 4);
    size_t zoff   = off;
    int*   cnt    = (int*)  alloc((size_t)N * 4);
    int*   fill   = (int*)  alloc((size_t)N * 4);
    float* pooled = (float*)alloc((size_t)G * C * 4);
    float* cntf   = (float*)alloc((size_t)G * 4);
    size_t zbytes = off - zoff;

    hipMemsetAsync(cnt, 0, zbytes, stream);

    const int* rowi = ei;       // edge_index[0] = source
    const int* coli = ei + E;   // edge_index[1] = target

    int eb = (E + 255) / 256;
    k_count<<<eb, 256, 0, stream>>>(coli, E, cnt);
    k_scan1<<<SCAN_BLOCKS, 256, 0, stream>>>(cnt, tsum, N);
    k_scan2<<<1, 1024, 0, stream>>>(tsum);
    k_scan3<<<SCAN_BLOCKS, 256, 0, stream>>>(cnt, tsum, rowptr, dis, N);
    k_fill<<<eb, 256, 0, stream>>>(rowi, coli, E, rowptr, fill, csr);

    int n4 = N * 32;   // float4 groups in x
    k_cast<<<(n4 + 255) / 256, 256, 0, stream>>>(x, bufX, n4);

    int fb = (N + 31) / 32;
    int ob = (N + 15) / 16;

    // hidden layers: hout = relu((Ahat hin) W + b)
    k_fused<<<fb, 256, 0, stream>>>(bufX, W_init, b_init, bufA, rowptr, csr, dis, N);
    k_fused<<<fb, 256, 0, stream>>>(bufA, W_h0,   b_h0,   bufB, rowptr, csr, dis, N);
    k_fused<<<fb, 256, 0, stream>>>(bufB, W_h1,   b_h1,   bufA, rowptr, csr, dis, N);

    // last layer: transform-first (narrow gather), then aggregate+pool
    k_gemmout<<<ob, 256, 0, stream>>>(bufA, W_out, tmpC, N, C);
    k_aggout <<<ob, 256, 0, stream>>>(tmpC, rowptr, csr, dis, b_out, batch, pooled, N, C);
    k_countnodes<<<(N + 255) / 256, 256, 0, stream>>>(batch, N, cntf);
    k_final<<<(G * C + 255) / 256, 256, 0, stream>>>(pooled, cntf, (float*)d_out, G, C);
}

// Round 5
// 746.286 us; speedup vs baseline: 1.7360x; 1.2088x over previous
//
#include <hip/hip_runtime.h>

// ---------------------------------------------------------------------------
// GCN (PyG-style) on MI355X.
//   h = relu(Ahat (h W) + b) x3, then Ahat (h W_out) + b_out, mean-pool.
//   Ahat = D^-1/2 (A+I) D^-1/2, degrees on target index.
// R1: hierarchical scan. R2: fusion Ahat(hW)=(Ahat h)W. R3: bf16 activations.
// R4: activations stored pre-scaled by dis ( g = dis*h ) so the gather needs
//     NO per-edge dis load/mul: s_v = dv*(sum g[r] + g[v]). 16-deep gather
//     unroll. Wave-per-node aggout with shfl reduce. Batch counts via binary
//     search on sorted batch (kills 100k atomics).
// ---------------------------------------------------------------------------

#define SCAN_BLOCKS 64
#define SCAN_THREADS (SCAN_BLOCKS * 256)   // 16384

typedef unsigned short u16;
typedef unsigned int   u32;

static __device__ __forceinline__ u16 f2bf(float x) {
    u32 u = __float_as_uint(x);
    u32 r = (u + 0x7fffu + ((u >> 16) & 1u)) >> 16;   // RNE
    return (u16)r;
}
static __device__ __forceinline__ float bf_lo(u32 p) { return __uint_as_float(p << 16); }
static __device__ __forceinline__ float bf_hi(u32 p) { return __uint_as_float(p & 0xffff0000u); }

__global__ __launch_bounds__(256) void k_count(const int* __restrict__ col, int E,
                                               int* __restrict__ cnt) {
    int e = blockIdx.x * 256 + threadIdx.x;
    if (e < E) atomicAdd(&cnt[col[e]], 1);
}

__global__ __launch_bounds__(256) void k_scan1(const int* __restrict__ cnt,
                                               int* __restrict__ tsum, int N) {
    int t = blockIdx.x * 256 + threadIdx.x;
    int strip = (N + SCAN_THREADS - 1) / SCAN_THREADS;
    int s0 = t * strip;
    int s1 = s0 + strip; if (s1 > N) s1 = N;
    int s = 0;
    for (int i = s0; i < s1; ++i) s += cnt[i];
    tsum[t] = s;
}

__global__ __launch_bounds__(1024) void k_scan2(int* __restrict__ tsum) {
    __shared__ int part[1024];
    int t = threadIdx.x;
    int base = t * 16;
    int local[16];
    int s = 0;
    #pragma unroll
    for (int i = 0; i < 16; ++i) { local[i] = tsum[base + i]; s += local[i]; }
    part[t] = s;
    __syncthreads();
    for (int off = 1; off < 1024; off <<= 1) {
        int v = part[t];
        int add = (t >= off) ? part[t - off] : 0;
        __syncthreads();
        part[t] = v + add;
        __syncthreads();
    }
    int run = (t == 0) ? 0 : part[t - 1];
    #pragma unroll
    for (int i = 0; i < 16; ++i) { int c = local[i]; tsum[base + i] = run; run += c; }
}

__global__ __launch_bounds__(256) void k_scan3(const int* __restrict__ cnt,
                                               const int* __restrict__ tsum,
                                               int* __restrict__ rowptr,
                                               float* __restrict__ dis, int N) {
    int t = blockIdx.x * 256 + threadIdx.x;
    int strip = (N + SCAN_THREADS - 1) / SCAN_THREADS;
    int s0 = t * strip;
    int s1 = s0 + strip; if (s1 > N) s1 = N;
    int run = tsum[t];
    for (int i = s0; i < s1; ++i) {
        int c = cnt[i];
        rowptr[i] = run;
        run += c;
        dis[i] = rsqrtf((float)(c + 1));
    }
    if (t == SCAN_THREADS - 1) rowptr[N] = run;
}

__global__ __launch_bounds__(256) void k_fill(const int* __restrict__ row,
                                              const int* __restrict__ col, int E,
                                              const int* __restrict__ rowptr,
                                              int* __restrict__ fill,
                                              int* __restrict__ csr) {
    int e = blockIdx.x * 256 + threadIdx.x;
    if (e < E) {
        int c = col[e];
        int p = rowptr[c] + atomicAdd(&fill[c], 1);
        csr[p] = row[e];
    }
}

// fp32 -> bf16 cast of input features, pre-scaled by dis[v].
__global__ __launch_bounds__(256) void k_cast(const float* __restrict__ src,
                                              const float* __restrict__ dis,
                                              u16* __restrict__ dst, int n4) {
    int i = blockIdx.x * 256 + threadIdx.x;
    if (i < n4) {
        int v = i >> 5;                // 32 float4 groups per 128-wide row
        float dv = dis[v];
        float4 val = ((const float4*)src)[i];
        ushort4 o;
        o.x = f2bf(dv * val.x); o.y = f2bf(dv * val.y);
        o.z = f2bf(dv * val.z); o.w = f2bf(dv * val.w);
        ((ushort4*)dst)[i] = o;
    }
}

// Fused hidden layer. Input hin holds g = dis*h (bf16). Phase A computes
// s_v = dis[v]*(sum_in g[r] + g[v]) -> LDS fp32. Phase B: 32x128 @ 128x128
// fp32 GEMM from LDS, bias+relu, store bf16 (scaled by dis if scale_out).
__global__ __launch_bounds__(256) void k_fused(const u16* __restrict__ hin,
                                               const float* __restrict__ W,
                                               const float* __restrict__ bias,
                                               u16* __restrict__ hout,
                                               const int* __restrict__ rowptr,
                                               const int* __restrict__ csr,
                                               const float* __restrict__ dis,
                                               int N, int scale_out) {
    __shared__ float hS[32 * 128];
    int tid = threadIdx.x;
    int wave = tid >> 6;
    int lane = tid & 63;
    int row0 = blockIdx.x * 32;
    const u32* hin32 = (const u32*)hin;   // row stride 64 dwords

    // ---- Phase A: gather-aggregate 8 nodes per wave, 16-deep unroll ----
    for (int j = 0; j < 8; ++j) {
        int v = row0 + wave * 8 + j;
        if (v >= N) break;
        u32 ps = hin32[(size_t)v * 64 + lane];
        float ax = bf_lo(ps), ay = bf_hi(ps);
        int s = rowptr[v], e = rowptr[v + 1];
        int i = s;
        for (; i + 16 <= e; i += 16) {
            int r[16];
            u32 p[16];
            #pragma unroll
            for (int t = 0; t < 16; ++t) r[t] = csr[i + t];
            #pragma unroll
            for (int t = 0; t < 16; ++t) p[t] = hin32[(size_t)r[t] * 64 + lane];
            #pragma unroll
            for (int t = 0; t < 16; ++t) { ax += bf_lo(p[t]); ay += bf_hi(p[t]); }
        }
        for (; i + 4 <= e; i += 4) {
            int r0 = csr[i], r1 = csr[i + 1], r2 = csr[i + 2], r3 = csr[i + 3];
            u32 p0 = hin32[(size_t)r0 * 64 + lane];
            u32 p1 = hin32[(size_t)r1 * 64 + lane];
            u32 p2 = hin32[(size_t)r2 * 64 + lane];
            u32 p3 = hin32[(size_t)r3 * 64 + lane];
            ax += bf_lo(p0) + bf_lo(p1) + bf_lo(p2) + bf_lo(p3);
            ay += bf_hi(p0) + bf_hi(p1) + bf_hi(p2) + bf_hi(p3);
        }
        for (; i < e; ++i) {
            u32 p0 = hin32[(size_t)csr[i] * 64 + lane];
            ax += bf_lo(p0);
            ay += bf_hi(p0);
        }
        float dv = dis[v];
        *(float2*)&hS[(wave * 8 + j) * 128 + lane * 2] = make_float2(dv * ax, dv * ay);
    }
    __syncthreads();

    // ---- Phase B: (s tile) @ W, bias + relu, optional dis scale, bf16 store ----
    int c4 = (tid & 31) * 4;
    int r0 = (tid >> 5) * 4;
    float4 a0 = {0.f,0.f,0.f,0.f}, a1 = a0, a2 = a0, a3 = a0;
    #pragma unroll 4
    for (int k = 0; k < 128; ++k) {
        float4 w = *(const float4*)&W[k * 128 + c4];
        float h0 = hS[(r0 + 0) * 128 + k];
        float h1 = hS[(r0 + 1) * 128 + k];
        float h2 = hS[(r0 + 2) * 128 + k];
        float h3 = hS[(r0 + 3) * 128 + k];
        a0.x += h0 * w.x; a0.y += h0 * w.y; a0.z += h0 * w.z; a0.w += h0 * w.w;
        a1.x += h1 * w.x; a1.y += h1 * w.y; a1.z += h1 * w.z; a1.w += h1 * w.w;
        a2.x += h2 * w.x; a2.y += h2 * w.y; a2.z += h2 * w.z; a2.w += h2 * w.w;
        a3.x += h3 * w.x; a3.y += h3 * w.y; a3.z += h3 * w.z; a3.w += h3 * w.w;
    }
    float4 bb = *(const float4*)&bias[c4];
    float4 acc[4] = {a0, a1, a2, a3};
    #pragma unroll
    for (int i = 0; i < 4; ++i) {
        int row = row0 + r0 + i;
        if (row < N) {
            float dsc = scale_out ? dis[row] : 1.0f;
            ushort4 o;
            o.x = f2bf(dsc * fmaxf(acc[i].x + bb.x, 0.f));
            o.y = f2bf(dsc * fmaxf(acc[i].y + bb.y, 0.f));
            o.z = f2bf(dsc * fmaxf(acc[i].z + bb.z, 0.f));
            o.w = f2bf(dsc * fmaxf(acc[i].w + bb.w, 0.f));
            *(ushort4*)&hout[(size_t)row * 128 + c4] = o;
        }
    }
}

// out[N x C] = bf16 hin[N x 128] @ Wout[128 x C], C<=16.  16 rows/block.
__global__ __launch_bounds__(256) void k_gemmout(const u16* __restrict__ hin,
                                                 const float* __restrict__ Wout,
                                                 float* __restrict__ out, int N, int C) {
    __shared__ float hS[16 * 128];
    int tid = threadIdx.x;
    int row0 = blockIdx.x * 16;
    int nrows = N - row0; if (nrows > 16) nrows = 16;
    const u32* src = (const u32*)(hin + (size_t)row0 * 128);
    int nvec = nrows * 64;   // dwords
    #pragma unroll
    for (int i = 0; i < 4; ++i) {
        int idx = tid + 256 * i;
        if (idx < nvec) {
            u32 p = src[idx];
            int r = idx >> 6, j = idx & 63;
            hS[r * 128 + 2 * j]     = bf_lo(p);
            hS[r * 128 + 2 * j + 1] = bf_hi(p);
        }
    }
    __syncthreads();
    int c = tid & 15;
    int rr = tid >> 4;
    int row = row0 + rr;
    if (row < N && c < C) {
        float acc = 0.f;
        #pragma unroll 8
        for (int k = 0; k < 128; ++k) acc += hS[rr * 128 + k] * Wout[k * C + c];
        out[(size_t)row * C + c] = acc;
    }
}

// Last-layer aggregate + pool. One wave per node: 4-way edge parallelism
// (g = lane>>4) x 16 feature lanes (c = lane&15); shfl_xor reduce.
__global__ __launch_bounds__(256) void k_aggout(const float* __restrict__ tmp,
                                                const int* __restrict__ rowptr,
                                                const int* __restrict__ csr,
                                                const float* __restrict__ dis,
                                                const float* __restrict__ bout,
                                                const int* __restrict__ batch,
                                                float* __restrict__ pooled,
                                                int N, int C) {
    int wave = threadIdx.x >> 6;
    int lane = threadIdx.x & 63;
    int v = blockIdx.x * 4 + wave;
    if (v >= N) return;
    int g = lane >> 4;
    int c = lane & 15;
    bool cv = (c < C);
    float dv = dis[v];
    float acc = 0.f;
    if (g == 0 && cv) acc = dv * tmp[(size_t)v * C + c];
    int s = rowptr[v], e = rowptr[v + 1];
    if (cv) {
        for (int i = s + g; i < e; i += 4) {
            int r = csr[i];
            acc += dis[r] * tmp[(size_t)r * C + c];
        }
    }
    acc += __shfl_xor(acc, 16);
    acc += __shfl_xor(acc, 32);
    if (g == 0 && cv) {
        float o = dv * acc + bout[c];
        atomicAdd(&pooled[batch[v] * C + c], o);
    }
}

// Per-graph node counts via binary search on the sorted batch array.
__global__ __launch_bounds__(256) void k_gcount(const int* __restrict__ batch,
                                                int N, int G, float* __restrict__ cntf) {
    int g = blockIdx.x * 256 + threadIdx.x;
    if (g >= G) return;
    int lo = 0, hi = N;
    while (lo < hi) { int m = (lo + hi) >> 1; if (batch[m] < g) lo = m + 1; else hi = m; }
    int lb = lo;
    lo = 0; hi = N;
    while (lo < hi) { int m = (lo + hi) >> 1; if (batch[m] <= g) lo = m + 1; else hi = m; }
    cntf[g] = (float)(lo - lb);
}

__global__ __launch_bounds__(256) void k_final(const float* __restrict__ pooled,
                                               const float* __restrict__ cntf,
                                               float* __restrict__ out, int G, int C) {
    int i = blockIdx.x * 256 + threadIdx.x;
    if (i < G * C) {
        int g = i / C;
        out[i] = pooled[i] / fmaxf(cntf[g], 1.0f);
    }
}

extern "C" void kernel_launch(void* const* d_in, const int* in_sizes, int n_in,
                              void* d_out, int out_size, void* d_ws, size_t ws_size,
                              hipStream_t stream) {
    const float* x      = (const float*)d_in[0];
    const int*   ei     = (const int*)d_in[1];
    const int*   batch  = (const int*)d_in[2];
    const float* W_init = (const float*)d_in[3];
    const float* b_init = (const float*)d_in[4];
    const float* W_h0   = (const float*)d_in[5];
    const float* b_h0   = (const float*)d_in[6];
    const float* W_h1   = (const float*)d_in[7];
    const float* b_h1   = (const float*)d_in[8];
    const float* W_out  = (const float*)d_in[9];
    const float* b_out  = (const float*)d_in[10];

    int N = in_sizes[0] / 128;
    int E = in_sizes[1] / 2;
    int C = in_sizes[10];
    int G = out_size / C;

    size_t off = 0;
    auto alloc = [&](size_t bytes) -> char* {
        char* p = (char*)d_ws + off;
        off += (bytes + 255) & ~(size_t)255;
        return p;
    };
    u16*   bufX   = (u16*)  alloc((size_t)N * 128 * 2);
    u16*   bufA   = (u16*)  alloc((size_t)N * 128 * 2);
    u16*   bufB   = (u16*)  alloc((size_t)N * 128 * 2);
    float* tmpC   = (float*)alloc((size_t)N * C * 4);
    float* dis    = (float*)alloc((size_t)N * 4);
    int*   rowptr = (int*)  alloc((size_t)(N + 1) * 4);
    int*   csr    = (int*)  alloc((size_t)E * 4);
    int*   tsum   = (int*)  alloc((size_t)SCAN_THREADS * 4);
    float* cntf   = (float*)alloc((size_t)G * 4);
    size_t zoff   = off;
    int*   cnt    = (int*)  alloc((size_t)N * 4);
    int*   fill   = (int*)  alloc((size_t)N * 4);
    float* pooled = (float*)alloc((size_t)G * C * 4);
    size_t zbytes = off - zoff;

    hipMemsetAsync(cnt, 0, zbytes, stream);

    const int* rowi = ei;       // edge_index[0] = source
    const int* coli = ei + E;   // edge_index[1] = target

    int eb = (E + 255) / 256;
    k_count<<<eb, 256, 0, stream>>>(coli, E, cnt);
    k_scan1<<<SCAN_BLOCKS, 256, 0, stream>>>(cnt, tsum, N);
    k_scan2<<<1, 1024, 0, stream>>>(tsum);
    k_scan3<<<SCAN_BLOCKS, 256, 0, stream>>>(cnt, tsum, rowptr, dis, N);
    k_fill<<<eb, 256, 0, stream>>>(rowi, coli, E, rowptr, fill, csr);

    int n4 = N * 32;   // float4 groups in x
    k_cast<<<(n4 + 255) / 256, 256, 0, stream>>>(x, dis, bufX, n4);

    int fb = (N + 31) / 32;
    int ob = (N + 15) / 16;
    int ab4 = (N + 3) / 4;

    // hidden layers (activations stored as dis*h except the last)
    k_fused<<<fb, 256, 0, stream>>>(bufX, W_init, b_init, bufA, rowptr, csr, dis, N, 1);
    k_fused<<<fb, 256, 0, stream>>>(bufA, W_h0,   b_h0,   bufB, rowptr, csr, dis, N, 1);
    k_fused<<<fb, 256, 0, stream>>>(bufB, W_h1,   b_h1,   bufA, rowptr, csr, dis, N, 0);

    // output head: transform-first (narrow), aggregate+pool
    k_gemmout<<<ob, 256, 0, stream>>>(bufA, W_out, tmpC, N, C);
    k_aggout <<<ab4, 256, 0, stream>>>(tmpC, rowptr, csr, dis, b_out, batch, pooled, N, C);
    k_gcount <<<(G + 255) / 256, 256, 0, stream>>>(batch, N, G, cntf);
    k_final  <<<(G * C + 255) / 256, 256, 0, stream>>>(pooled, cntf, (float*)d_out, G, C);
}

// Round 6
// 729.525 us; speedup vs baseline: 1.7759x; 1.0230x over previous
//
#include <hip/hip_runtime.h>

// ---------------------------------------------------------------------------
// GCN (PyG-style) on MI355X.
//   h = relu(Ahat (h W) + b) x3, then Ahat (h W_out) + b_out, mean-pool.
// R1: hierarchical scan. R2: fusion Ahat(hW)=(Ahat h)W. R3: bf16 activations.
// R4: dis-prescaled activations, deeper unroll, shfl aggout, bsearch counts.
// R5: 4-aligned padded CSR (pad slots -> dummy node N with zero row) so csr
//     reads are int4 and tails vanish; pair-interleaved 8-deep gather keeps
//     16 row-loads in flight for ~97% of edge mass; 32-bit addressing.
// ---------------------------------------------------------------------------

#define SCAN_BLOCKS 64
#define SCAN_THREADS (SCAN_BLOCKS * 256)   // 16384

typedef unsigned short u16;
typedef unsigned int   u32;

static __device__ __forceinline__ u16 f2bf(float x) {
    u32 u = __float_as_uint(x);
    u32 r = (u + 0x7fffu + ((u >> 16) & 1u)) >> 16;   // RNE
    return (u16)r;
}
static __device__ __forceinline__ float bf_lo(u32 p) { return __uint_as_float(p << 16); }
static __device__ __forceinline__ float bf_hi(u32 p) { return __uint_as_float(p & 0xffff0000u); }

__global__ __launch_bounds__(256) void k_count(const int* __restrict__ col, int E,
                                               int* __restrict__ cnt) {
    int e = blockIdx.x * 256 + threadIdx.x;
    if (e < E) atomicAdd(&cnt[col[e]], 1);
}

// Phase 1 of scan: per-thread strip sums of ROUNDED counts.
__global__ __launch_bounds__(256) void k_scan1(const int* __restrict__ cnt,
                                               int* __restrict__ tsum, int N) {
    int t = blockIdx.x * 256 + threadIdx.x;
    int strip = (N + SCAN_THREADS - 1) / SCAN_THREADS;
    int s0 = t * strip;
    int s1 = s0 + strip; if (s1 > N) s1 = N;
    int s = 0;
    for (int i = s0; i < s1; ++i) s += (cnt[i] + 3) & ~3;
    tsum[t] = s;
}

__global__ __launch_bounds__(1024) void k_scan2(int* __restrict__ tsum) {
    __shared__ int part[1024];
    int t = threadIdx.x;
    int base = t * 16;
    int local[16];
    int s = 0;
    #pragma unroll
    for (int i = 0; i < 16; ++i) { local[i] = tsum[base + i]; s += local[i]; }
    part[t] = s;
    __syncthreads();
    for (int off = 1; off < 1024; off <<= 1) {
        int v = part[t];
        int add = (t >= off) ? part[t - off] : 0;
        __syncthreads();
        part[t] = v + add;
        __syncthreads();
    }
    int run = (t == 0) ? 0 : part[t - 1];
    #pragma unroll
    for (int i = 0; i < 16; ++i) { int c = local[i]; tsum[base + i] = run; run += c; }
}

// Phase 3: rowptr (rounded), dis, and csr pad slots = N (dummy zero row).
__global__ __launch_bounds__(256) void k_scan3(const int* __restrict__ cnt,
                                               const int* __restrict__ tsum,
                                               int* __restrict__ rowptr,
                                               float* __restrict__ dis,
                                               int* __restrict__ csr, int N) {
    int t = blockIdx.x * 256 + threadIdx.x;
    int strip = (N + SCAN_THREADS - 1) / SCAN_THREADS;
    int s0 = t * strip;
    int s1 = s0 + strip; if (s1 > N) s1 = N;
    int run = tsum[t];
    for (int i = s0; i < s1; ++i) {
        int c = cnt[i];
        int r = (c + 3) & ~3;
        rowptr[i] = run;
        for (int p = run + c; p < run + r; ++p) csr[p] = N;   // pads
        run += r;
        dis[i] = rsqrtf((float)(c + 1));
    }
    if (t == SCAN_THREADS - 1) rowptr[N] = run;
}

__global__ __launch_bounds__(256) void k_fill(const int* __restrict__ row,
                                              const int* __restrict__ col, int E,
                                              const int* __restrict__ rowptr,
                                              int* __restrict__ fill,
                                              int* __restrict__ csr) {
    int e = blockIdx.x * 256 + threadIdx.x;
    if (e < E) {
        int c = col[e];
        int p = rowptr[c] + atomicAdd(&fill[c], 1);
        csr[p] = row[e];
    }
}

// fp32 -> bf16 cast pre-scaled by dis[v]; also zeroes dummy row N of all bufs.
__global__ __launch_bounds__(256) void k_cast(const float* __restrict__ src,
                                              const float* __restrict__ dis,
                                              u16* __restrict__ bX,
                                              u16* __restrict__ bA,
                                              u16* __restrict__ bB, int N) {
    int i = blockIdx.x * 256 + threadIdx.x;   // float4-group index over N+1 rows
    int total = (N + 1) * 32;
    if (i >= total) return;
    int v = i >> 5;
    if (v < N) {
        float dv = dis[v];
        float4 val = ((const float4*)src)[i];
        ushort4 o;
        o.x = f2bf(dv * val.x); o.y = f2bf(dv * val.y);
        o.z = f2bf(dv * val.z); o.w = f2bf(dv * val.w);
        ((ushort4*)bX)[i] = o;
    } else {
        ushort4 z = {0, 0, 0, 0};
        ((ushort4*)bX)[i] = z;
        ((ushort4*)bA)[i] = z;
        ((ushort4*)bB)[i] = z;
    }
}

// Fused hidden layer. hin holds g = dis*h (bf16, N+1 rows, row N zero).
// Phase A: pair-interleaved gather, 16 row-loads in flight, int4 csr reads.
// Phase B: 32x128 @ 128x128 fp32 GEMM from LDS, bias+relu, bf16 store.
__global__ __launch_bounds__(256) void k_fused(const u16* __restrict__ hin,
                                               const float* __restrict__ W,
                                               const float* __restrict__ bias,
                                               u16* __restrict__ hout,
                                               const int* __restrict__ rowptr,
                                               const int* __restrict__ csr,
                                               const float* __restrict__ dis,
                                               int N, int scale_out) {
    __shared__ float hS[32 * 128];
    int tid = threadIdx.x;
    int wave = tid >> 6;
    int lane = tid & 63;
    int row0 = blockIdx.x * 32;
    const u32* hin32 = (const u32*)hin;       // row stride 64 dwords
    const int4* csr4 = (const int4*)csr;      // rowptr always multiple of 4

    for (int j = 0; j < 8; j += 2) {
        int va = row0 + wave * 8 + j;
        int vb = va + 1;
        bool hA = va < N, hB = vb < N;
        float ax = 0.f, ay = 0.f, bx = 0.f, by = 0.f;
        int ia = 0, ea = 0, ib = 0, eb = 0;
        if (hA) {
            u32 p = hin32[((u32)va << 6) + lane];
            ax = bf_lo(p); ay = bf_hi(p);
            ia = rowptr[va]; ea = rowptr[va + 1];
        }
        if (hB) {
            u32 p = hin32[((u32)vb << 6) + lane];
            bx = bf_lo(p); by = bf_hi(p);
            ib = rowptr[vb]; eb = rowptr[vb + 1];
        }
        // paired main loop: 2 nodes x 8 edges -> 16 gathers in flight
        while ((ia + 8 <= ea) & (ib + 8 <= eb)) {
            int4 a0 = csr4[(u32)ia >> 2];
            int4 a1 = csr4[((u32)ia >> 2) + 1];
            int4 b0 = csr4[(u32)ib >> 2];
            int4 b1 = csr4[((u32)ib >> 2) + 1];
            u32 pa0 = hin32[((u32)a0.x << 6) + lane];
            u32 pa1 = hin32[((u32)a0.y << 6) + lane];
            u32 pa2 = hin32[((u32)a0.z << 6) + lane];
            u32 pa3 = hin32[((u32)a0.w << 6) + lane];
            u32 pa4 = hin32[((u32)a1.x << 6) + lane];
            u32 pa5 = hin32[((u32)a1.y << 6) + lane];
            u32 pa6 = hin32[((u32)a1.z << 6) + lane];
            u32 pa7 = hin32[((u32)a1.w << 6) + lane];
            u32 pb0 = hin32[((u32)b0.x << 6) + lane];
            u32 pb1 = hin32[((u32)b0.y << 6) + lane];
            u32 pb2 = hin32[((u32)b0.z << 6) + lane];
            u32 pb3 = hin32[((u32)b0.w << 6) + lane];
            u32 pb4 = hin32[((u32)b1.x << 6) + lane];
            u32 pb5 = hin32[((u32)b1.y << 6) + lane];
            u32 pb6 = hin32[((u32)b1.z << 6) + lane];
            u32 pb7 = hin32[((u32)b1.w << 6) + lane];
            ax += bf_lo(pa0) + bf_lo(pa1) + bf_lo(pa2) + bf_lo(pa3);
            ay += bf_hi(pa0) + bf_hi(pa1) + bf_hi(pa2) + bf_hi(pa3);
            ax += bf_lo(pa4) + bf_lo(pa5) + bf_lo(pa6) + bf_lo(pa7);
            ay += bf_hi(pa4) + bf_hi(pa5) + bf_hi(pa6) + bf_hi(pa7);
            bx += bf_lo(pb0) + bf_lo(pb1) + bf_lo(pb2) + bf_lo(pb3);
            by += bf_hi(pb0) + bf_hi(pb1) + bf_hi(pb2) + bf_hi(pb3);
            bx += bf_lo(pb4) + bf_lo(pb5) + bf_lo(pb6) + bf_lo(pb7);
            by += bf_hi(pb4) + bf_hi(pb5) + bf_hi(pb6) + bf_hi(pb7);
            ia += 8; ib += 8;
        }
        // drain A
        while (ia + 8 <= ea) {
            int4 a0 = csr4[(u32)ia >> 2];
            int4 a1 = csr4[((u32)ia >> 2) + 1];
            u32 p0 = hin32[((u32)a0.x << 6) + lane];
            u32 p1 = hin32[((u32)a0.y << 6) + lane];
            u32 p2 = hin32[((u32)a0.z << 6) + lane];
            u32 p3 = hin32[((u32)a0.w << 6) + lane];
            u32 p4 = hin32[((u32)a1.x << 6) + lane];
            u32 p5 = hin32[((u32)a1.y << 6) + lane];
            u32 p6 = hin32[((u32)a1.z << 6) + lane];
            u32 p7 = hin32[((u32)a1.w << 6) + lane];
            ax += bf_lo(p0) + bf_lo(p1) + bf_lo(p2) + bf_lo(p3);
            ay += bf_hi(p0) + bf_hi(p1) + bf_hi(p2) + bf_hi(p3);
            ax += bf_lo(p4) + bf_lo(p5) + bf_lo(p6) + bf_lo(p7);
            ay += bf_hi(p4) + bf_hi(p5) + bf_hi(p6) + bf_hi(p7);
            ia += 8;
        }
        if (ia < ea) {   // remainder is exactly 4 (rowptr diffs are x4)
            int4 a0 = csr4[(u32)ia >> 2];
            u32 p0 = hin32[((u32)a0.x << 6) + lane];
            u32 p1 = hin32[((u32)a0.y << 6) + lane];
            u32 p2 = hin32[((u32)a0.z << 6) + lane];
            u32 p3 = hin32[((u32)a0.w << 6) + lane];
            ax += bf_lo(p0) + bf_lo(p1) + bf_lo(p2) + bf_lo(p3);
            ay += bf_hi(p0) + bf_hi(p1) + bf_hi(p2) + bf_hi(p3);
        }
        // drain B
        while (ib + 8 <= eb) {
            int4 b0 = csr4[(u32)ib >> 2];
            int4 b1 = csr4[((u32)ib >> 2) + 1];
            u32 p0 = hin32[((u32)b0.x << 6) + lane];
            u32 p1 = hin32[((u32)b0.y << 6) + lane];
            u32 p2 = hin32[((u32)b0.z << 6) + lane];
            u32 p3 = hin32[((u32)b0.w << 6) + lane];
            u32 p4 = hin32[((u32)b1.x << 6) + lane];
            u32 p5 = hin32[((u32)b1.y << 6) + lane];
            u32 p6 = hin32[((u32)b1.z << 6) + lane];
            u32 p7 = hin32[((u32)b1.w << 6) + lane];
            bx += bf_lo(p0) + bf_lo(p1) + bf_lo(p2) + bf_lo(p3);
            by += bf_hi(p0) + bf_hi(p1) + bf_hi(p2) + bf_hi(p3);
            bx += bf_lo(p4) + bf_lo(p5) + bf_lo(p6) + bf_lo(p7);
            by += bf_hi(p4) + bf_hi(p5) + bf_hi(p6) + bf_hi(p7);
            ib += 8;
        }
        if (ib < eb) {
            int4 b0 = csr4[(u32)ib >> 2];
            u32 p0 = hin32[((u32)b0.x << 6) + lane];
            u32 p1 = hin32[((u32)b0.y << 6) + lane];
            u32 p2 = hin32[((u32)b0.z << 6) + lane];
            u32 p3 = hin32[((u32)b0.w << 6) + lane];
            bx += bf_lo(p0) + bf_lo(p1) + bf_lo(p2) + bf_lo(p3);
            by += bf_hi(p0) + bf_hi(p1) + bf_hi(p2) + bf_hi(p3);
        }
        if (hA) {
            float dv = dis[va];
            *(float2*)&hS[(wave * 8 + j) * 128 + lane * 2] = make_float2(dv * ax, dv * ay);
        }
        if (hB) {
            float dv = dis[vb];
            *(float2*)&hS[(wave * 8 + j + 1) * 128 + lane * 2] = make_float2(dv * bx, dv * by);
        }
    }
    __syncthreads();

    // ---- Phase B ----
    int c4 = (tid & 31) * 4;
    int r0 = (tid >> 5) * 4;
    float4 a0 = {0.f,0.f,0.f,0.f}, a1 = a0, a2 = a0, a3 = a0;
    #pragma unroll 4
    for (int k = 0; k < 128; ++k) {
        float4 w = *(const float4*)&W[k * 128 + c4];
        float h0 = hS[(r0 + 0) * 128 + k];
        float h1 = hS[(r0 + 1) * 128 + k];
        float h2 = hS[(r0 + 2) * 128 + k];
        float h3 = hS[(r0 + 3) * 128 + k];
        a0.x += h0 * w.x; a0.y += h0 * w.y; a0.z += h0 * w.z; a0.w += h0 * w.w;
        a1.x += h1 * w.x; a1.y += h1 * w.y; a1.z += h1 * w.z; a1.w += h1 * w.w;
        a2.x += h2 * w.x; a2.y += h2 * w.y; a2.z += h2 * w.z; a2.w += h2 * w.w;
        a3.x += h3 * w.x; a3.y += h3 * w.y; a3.z += h3 * w.z; a3.w += h3 * w.w;
    }
    float4 bb = *(const float4*)&bias[c4];
    float4 acc[4] = {a0, a1, a2, a3};
    #pragma unroll
    for (int i = 0; i < 4; ++i) {
        int row = row0 + r0 + i;
        if (row < N) {
            float dsc = scale_out ? dis[row] : 1.0f;
            ushort4 o;
            o.x = f2bf(dsc * fmaxf(acc[i].x + bb.x, 0.f));
            o.y = f2bf(dsc * fmaxf(acc[i].y + bb.y, 0.f));
            o.z = f2bf(dsc * fmaxf(acc[i].z + bb.z, 0.f));
            o.w = f2bf(dsc * fmaxf(acc[i].w + bb.w, 0.f));
            *(ushort4*)&hout[((u32)row << 7) + c4] = o;
        }
    }
}

// out[N x C] = bf16 hin[N x 128] @ Wout[128 x C], C<=16.  16 rows/block.
__global__ __launch_bounds__(256) void k_gemmout(const u16* __restrict__ hin,
                                                 const float* __restrict__ Wout,
                                                 float* __restrict__ out, int N, int C) {
    __shared__ float hS[16 * 128];
    int tid = threadIdx.x;
    int row0 = blockIdx.x * 16;
    int nrows = N - row0; if (nrows > 16) nrows = 16;
    const u32* src = (const u32*)(hin + (size_t)row0 * 128);
    int nvec = nrows * 64;   // dwords
    #pragma unroll
    for (int i = 0; i < 4; ++i) {
        int idx = tid + 256 * i;
        if (idx < nvec) {
            u32 p = src[idx];
            int r = idx >> 6, j = idx & 63;
            hS[r * 128 + 2 * j]     = bf_lo(p);
            hS[r * 128 + 2 * j + 1] = bf_hi(p);
        }
    }
    __syncthreads();
    int c = tid & 15;
    int rr = tid >> 4;
    int row = row0 + rr;
    if (row < N && c < C) {
        float acc = 0.f;
        #pragma unroll 8
        for (int k = 0; k < 128; ++k) acc += hS[rr * 128 + k] * Wout[k * C + c];
        out[(size_t)row * C + c] = acc;
    }
}

// Last-layer aggregate + pool. Wave per node, 4-way edge parallelism,
// true edge count from cnt (skips csr pads).
__global__ __launch_bounds__(256) void k_aggout(const float* __restrict__ tmp,
                                                const int* __restrict__ rowptr,
                                                const int* __restrict__ cnt,
                                                const int* __restrict__ csr,
                                                const float* __restrict__ dis,
                                                const float* __restrict__ bout,
                                                const int* __restrict__ batch,
                                                float* __restrict__ pooled,
                                                int N, int C) {
    int wave = threadIdx.x >> 6;
    int lane = threadIdx.x & 63;
    int v = blockIdx.x * 4 + wave;
    if (v >= N) return;
    int g = lane >> 4;
    int c = lane & 15;
    bool cv = (c < C);
    float dv = dis[v];
    float acc = 0.f;
    if (g == 0 && cv) acc = dv * tmp[(u32)v * C + c];
    int s = rowptr[v], e = s + cnt[v];
    if (cv) {
        for (int i = s + g; i < e; i += 4) {
            int r = csr[i];
            acc += dis[r] * tmp[(u32)r * C + c];
        }
    }
    acc += __shfl_xor(acc, 16);
    acc += __shfl_xor(acc, 32);
    if (g == 0 && cv) {
        float o = dv * acc + bout[c];
        atomicAdd(&pooled[batch[v] * C + c], o);
    }
}

// Final: per-graph mean via binary search on sorted batch (no atomics).
__global__ __launch_bounds__(256) void k_final(const float* __restrict__ pooled,
                                               const int* __restrict__ batch, int N,
                                               float* __restrict__ out, int G, int C) {
    int i = blockIdx.x * 256 + threadIdx.x;
    if (i >= G * C) return;
    int g = i / C;
    int lo = 0, hi = N;
    while (lo < hi) { int m = (lo + hi) >> 1; if (batch[m] < g) lo = m + 1; else hi = m; }
    int lb = lo;
    lo = 0; hi = N;
    while (lo < hi) { int m = (lo + hi) >> 1; if (batch[m] <= g) lo = m + 1; else hi = m; }
    float cntv = (float)(lo - lb);
    out[i] = pooled[i] / fmaxf(cntv, 1.0f);
}

extern "C" void kernel_launch(void* const* d_in, const int* in_sizes, int n_in,
                              void* d_out, int out_size, void* d_ws, size_t ws_size,
                              hipStream_t stream) {
    const float* x      = (const float*)d_in[0];
    const int*   ei     = (const int*)d_in[1];
    const int*   batch  = (const int*)d_in[2];
    const float* W_init = (const float*)d_in[3];
    const float* b_init = (const float*)d_in[4];
    const float* W_h0   = (const float*)d_in[5];
    const float* b_h0   = (const float*)d_in[6];
    const float* W_h1   = (const float*)d_in[7];
    const float* b_h1   = (const float*)d_in[8];
    const float* W_out  = (const float*)d_in[9];
    const float* b_out  = (const float*)d_in[10];

    int N = in_sizes[0] / 128;
    int E = in_sizes[1] / 2;
    int C = in_sizes[10];
    int G = out_size / C;

    size_t off = 0;
    auto alloc = [&](size_t bytes) -> char* {
        char* p = (char*)d_ws + off;
        off += (bytes + 255) & ~(size_t)255;
        return p;
    };
    u16*   bufX   = (u16*)  alloc((size_t)(N + 1) * 128 * 2);
    u16*   bufA   = (u16*)  alloc((size_t)(N + 1) * 128 * 2);
    u16*   bufB   = (u16*)  alloc((size_t)(N + 1) * 128 * 2);
    float* tmpC   = (float*)alloc((size_t)N * C * 4);
    float* dis    = (float*)alloc((size_t)N * 4);
    int*   rowptr = (int*)  alloc((size_t)(N + 1) * 4);
    int*   csr    = (int*)  alloc(((size_t)E + 3 * (size_t)N + 8) * 4);
    int*   tsum   = (int*)  alloc((size_t)SCAN_THREADS * 4);
    size_t zoff   = off;
    int*   cnt    = (int*)  alloc((size_t)N * 4);
    int*   fill   = (int*)  alloc((size_t)N * 4);
    float* pooled = (float*)alloc((size_t)G * C * 4);
    size_t zbytes = off - zoff;

    hipMemsetAsync(cnt, 0, zbytes, stream);

    const int* rowi = ei;       // edge_index[0] = source
    const int* coli = ei + E;   // edge_index[1] = target

    int eb = (E + 255) / 256;
    k_count<<<eb, 256, 0, stream>>>(coli, E, cnt);
    k_scan1<<<SCAN_BLOCKS, 256, 0, stream>>>(cnt, tsum, N);
    k_scan2<<<1, 1024, 0, stream>>>(tsum);
    k_scan3<<<SCAN_BLOCKS, 256, 0, stream>>>(cnt, tsum, rowptr, dis, csr, N);
    k_fill<<<eb, 256, 0, stream>>>(rowi, coli, E, rowptr, fill, csr);

    int cg = ((N + 1) * 32 + 255) / 256;
    k_cast<<<cg, 256, 0, stream>>>(x, dis, bufX, bufA, bufB, N);

    int fb = (N + 31) / 32;
    int ob = (N + 15) / 16;
    int ab4 = (N + 3) / 4;

    // hidden layers (activations stored as dis*h except the last)
    k_fused<<<fb, 256, 0, stream>>>(bufX, W_init, b_init, bufA, rowptr, csr, dis, N, 1);
    k_fused<<<fb, 256, 0, stream>>>(bufA, W_h0,   b_h0,   bufB, rowptr, csr, dis, N, 1);
    k_fused<<<fb, 256, 0, stream>>>(bufB, W_h1,   b_h1,   bufA, rowptr, csr, dis, N, 0);

    // output head: transform-first (narrow), aggregate+pool, mean
    k_gemmout<<<ob, 256, 0, stream>>>(bufA, W_out, tmpC, N, C);
    k_aggout <<<ab4, 256, 0, stream>>>(tmpC, rowptr, cnt, csr, dis, b_out, batch, pooled, N, C);
    k_final  <<<(G * C + 255) / 256, 256, 0, stream>>>(pooled, batch, N, (float*)d_out, G, C);
}

// Round 7
// 585.862 us; speedup vs baseline: 2.2114x; 1.2452x over previous
//
#include <hip/hip_runtime.h>

// ---------------------------------------------------------------------------
// GCN (PyG-style) on MI355X.
//   h = relu(Ahat (h W) + b) x3, then Ahat (h W_out) + b_out, mean-pool.
// R1: hierarchical scan. R2: fusion Ahat(hW)=(Ahat h)W. R3: bf16 activations.
// R4: dis-prescaled activations. R5: padded CSR + paired 16-deep gather.
// R6: phase B on MFMA (16x16x32 bf16), double-pumped W = Whi+Wlo (bf16 pair,
//     ~fp19 effective W precision) accumulating fp32; packed-bf16 s-tile in
//     LDS (8.3KB, stride 65); W pre-swizzled to B-fragment order. k_fill via
//     rank-from-count (no 2nd atomic pass). tmpC stride 16 (line-aligned).
// ---------------------------------------------------------------------------

#define SCAN_BLOCKS 64
#define SCAN_THREADS (SCAN_BLOCKS * 256)   // 16384

typedef unsigned short u16;
typedef unsigned int   u32;
typedef __attribute__((ext_vector_type(8))) short bf16x8;   // 8 bf16 (4 VGPRs)
typedef __attribute__((ext_vector_type(4))) float f32x4;

static __device__ __forceinline__ u16 f2bf(float x) {
    u32 u = __float_as_uint(x);
    u32 r = (u + 0x7fffu + ((u >> 16) & 1u)) >> 16;   // RNE
    return (u16)r;
}
static __device__ __forceinline__ float bf_lo(u32 p) { return __uint_as_float(p << 16); }
static __device__ __forceinline__ float bf_hi(u32 p) { return __uint_as_float(p & 0xffff0000u); }

__global__ __launch_bounds__(256) void k_count(const int* __restrict__ col, int E,
                                               int* __restrict__ cnt,
                                               int* __restrict__ rank) {
    int e = blockIdx.x * 256 + threadIdx.x;
    if (e < E) rank[e] = atomicAdd(&cnt[col[e]], 1);
}

__global__ __launch_bounds__(256) void k_scan1(const int* __restrict__ cnt,
                                               int* __restrict__ tsum, int N) {
    int t = blockIdx.x * 256 + threadIdx.x;
    int strip = (N + SCAN_THREADS - 1) / SCAN_THREADS;
    int s0 = t * strip;
    int s1 = s0 + strip; if (s1 > N) s1 = N;
    int s = 0;
    for (int i = s0; i < s1; ++i) s += (cnt[i] + 3) & ~3;
    tsum[t] = s;
}

__global__ __launch_bounds__(1024) void k_scan2(int* __restrict__ tsum) {
    __shared__ int part[1024];
    int t = threadIdx.x;
    int base = t * 16;
    int local[16];
    int s = 0;
    #pragma unroll
    for (int i = 0; i < 16; ++i) { local[i] = tsum[base + i]; s += local[i]; }
    part[t] = s;
    __syncthreads();
    for (int off = 1; off < 1024; off <<= 1) {
        int v = part[t];
        int add = (t >= off) ? part[t - off] : 0;
        __syncthreads();
        part[t] = v + add;
        __syncthreads();
    }
    int run = (t == 0) ? 0 : part[t - 1];
    #pragma unroll
    for (int i = 0; i < 16; ++i) { int c = local[i]; tsum[base + i] = run; run += c; }
}

__global__ __launch_bounds__(256) void k_scan3(const int* __restrict__ cnt,
                                               const int* __restrict__ tsum,
                                               int* __restrict__ rowptr,
                                               float* __restrict__ dis,
                                               int* __restrict__ csr, int N) {
    int t = blockIdx.x * 256 + threadIdx.x;
    int strip = (N + SCAN_THREADS - 1) / SCAN_THREADS;
    int s0 = t * strip;
    int s1 = s0 + strip; if (s1 > N) s1 = N;
    int run = tsum[t];
    for (int i = s0; i < s1; ++i) {
        int c = cnt[i];
        int r = (c + 3) & ~3;
        rowptr[i] = run;
        for (int p = run + c; p < run + r; ++p) csr[p] = N;   // pads -> zero row
        run += r;
        dis[i] = rsqrtf((float)(c + 1));
    }
    if (t == SCAN_THREADS - 1) rowptr[N] = run;
}

// Scatter without atomics: rank captured during k_count.
__global__ __launch_bounds__(256) void k_fill(const int* __restrict__ row,
                                              const int* __restrict__ col, int E,
                                              const int* __restrict__ rowptr,
                                              const int* __restrict__ rank,
                                              int* __restrict__ csr) {
    int e = blockIdx.x * 256 + threadIdx.x;
    if (e < E) {
        int c = col[e];
        csr[rowptr[c] + rank[e]] = row[e];
    }
}

// fp32 -> bf16 cast pre-scaled by dis[v]; also zeroes dummy row N of all bufs.
__global__ __launch_bounds__(256) void k_cast(const float* __restrict__ src,
                                              const float* __restrict__ dis,
                                              u16* __restrict__ bX,
                                              u16* __restrict__ bA,
                                              u16* __restrict__ bB, int N) {
    int i = blockIdx.x * 256 + threadIdx.x;   // float4-group index over N+1 rows
    int total = (N + 1) * 32;
    if (i >= total) return;
    int v = i >> 5;
    if (v < N) {
        float dv = dis[v];
        float4 val = ((const float4*)src)[i];
        ushort4 o;
        o.x = f2bf(dv * val.x); o.y = f2bf(dv * val.y);
        o.z = f2bf(dv * val.z); o.w = f2bf(dv * val.w);
        ((ushort4*)bX)[i] = o;
    } else {
        ushort4 z = {0, 0, 0, 0};
        ((ushort4*)bX)[i] = z;
        ((ushort4*)bA)[i] = z;
        ((ushort4*)bB)[i] = z;
    }
}

// Pre-swizzle W (128x128 fp32) into MFMA B-fragment order, split hi+lo bf16.
// Layout: [ntile(8)][k0(4)][lane(64)] -> uint4 (4 packed bf16 pairs, j=0..7).
// Element j of lane's frag = W[k0*32 + (lane>>4)*8 + j][ntile*16 + (lane&15)].
__global__ __launch_bounds__(256) void k_wprep(const float* __restrict__ W,
                                               u32* __restrict__ whi,
                                               u32* __restrict__ wlo) {
    int t = blockIdx.x * 256 + threadIdx.x;   // 2048 = 8*4*64
    if (t >= 2048) return;
    int lane = t & 63;
    int nk = t >> 6;
    int k0 = nk & 3;
    int ntile = nk >> 2;
    int n = ntile * 16 + (lane & 15);
    int kbase = k0 * 32 + (lane >> 4) * 8;
    u32 hi[4], lo[4];
    #pragma unroll
    for (int tt = 0; tt < 4; ++tt) {
        float w0 = W[(kbase + 2 * tt) * 128 + n];
        float w1 = W[(kbase + 2 * tt + 1) * 128 + n];
        u16 h0 = f2bf(w0), h1 = f2bf(w1);
        u16 l0 = f2bf(w0 - __uint_as_float((u32)h0 << 16));
        u16 l1 = f2bf(w1 - __uint_as_float((u32)h1 << 16));
        hi[tt] = (u32)h0 | ((u32)h1 << 16);
        lo[tt] = (u32)l0 | ((u32)l1 << 16);
    }
    uint4 qh = {hi[0], hi[1], hi[2], hi[3]};
    uint4 ql = {lo[0], lo[1], lo[2], lo[3]};
    ((uint4*)whi)[t] = qh;
    ((uint4*)wlo)[t] = ql;
}

// Fused hidden layer. hin holds g = dis*h (bf16, N+1 rows, row N zero).
// Phase A: paired 16-deep gather -> packed-bf16 s-tile in LDS (stride 65).
// Phase B: MFMA 16x16x32 bf16, W double-pumped (hi+lo), fp32 acc, bias+relu.
__global__ __launch_bounds__(256) void k_fused(const u16* __restrict__ hin,
                                               const u32* __restrict__ whi,
                                               const u32* __restrict__ wlo,
                                               const float* __restrict__ bias,
                                               u16* __restrict__ hout,
                                               const int* __restrict__ rowptr,
                                               const int* __restrict__ csr,
                                               const float* __restrict__ dis,
                                               int N, int scale_out) {
    __shared__ u32 sS[32 * 65];
    __shared__ float dS[32];
    int tid = threadIdx.x;
    int wave = tid >> 6;
    int lane = tid & 63;
    int row0 = blockIdx.x * 32;
    const u32* hin32 = (const u32*)hin;       // row stride 64 dwords
    const int4* csr4 = (const int4*)csr;      // rowptr always multiple of 4

    // ---- Phase A ----
    for (int j = 0; j < 8; j += 2) {
        int va = row0 + wave * 8 + j;
        int vb = va + 1;
        bool hA = va < N, hB = vb < N;
        float ax = 0.f, ay = 0.f, bx = 0.f, by = 0.f;
        int ia = 0, ea = 0, ib = 0, eb = 0;
        float dva = 1.f, dvb = 1.f;
        if (hA) {
            u32 p = hin32[((u32)va << 6) + lane];
            ax = bf_lo(p); ay = bf_hi(p);
            ia = rowptr[va]; ea = rowptr[va + 1];
            dva = dis[va];
        }
        if (hB) {
            u32 p = hin32[((u32)vb << 6) + lane];
            bx = bf_lo(p); by = bf_hi(p);
            ib = rowptr[vb]; eb = rowptr[vb + 1];
            dvb = dis[vb];
        }
        while ((ia + 8 <= ea) & (ib + 8 <= eb)) {
            int4 a0 = csr4[(u32)ia >> 2];
            int4 a1 = csr4[((u32)ia >> 2) + 1];
            int4 b0 = csr4[(u32)ib >> 2];
            int4 b1 = csr4[((u32)ib >> 2) + 1];
            u32 pa0 = hin32[((u32)a0.x << 6) + lane];
            u32 pa1 = hin32[((u32)a0.y << 6) + lane];
            u32 pa2 = hin32[((u32)a0.z << 6) + lane];
            u32 pa3 = hin32[((u32)a0.w << 6) + lane];
            u32 pa4 = hin32[((u32)a1.x << 6) + lane];
            u32 pa5 = hin32[((u32)a1.y << 6) + lane];
            u32 pa6 = hin32[((u32)a1.z << 6) + lane];
            u32 pa7 = hin32[((u32)a1.w << 6) + lane];
            u32 pb0 = hin32[((u32)b0.x << 6) + lane];
            u32 pb1 = hin32[((u32)b0.y << 6) + lane];
            u32 pb2 = hin32[((u32)b0.z << 6) + lane];
            u32 pb3 = hin32[((u32)b0.w << 6) + lane];
            u32 pb4 = hin32[((u32)b1.x << 6) + lane];
            u32 pb5 = hin32[((u32)b1.y << 6) + lane];
            u32 pb6 = hin32[((u32)b1.z << 6) + lane];
            u32 pb7 = hin32[((u32)b1.w << 6) + lane];
            ax += bf_lo(pa0) + bf_lo(pa1) + bf_lo(pa2) + bf_lo(pa3);
            ay += bf_hi(pa0) + bf_hi(pa1) + bf_hi(pa2) + bf_hi(pa3);
            ax += bf_lo(pa4) + bf_lo(pa5) + bf_lo(pa6) + bf_lo(pa7);
            ay += bf_hi(pa4) + bf_hi(pa5) + bf_hi(pa6) + bf_hi(pa7);
            bx += bf_lo(pb0) + bf_lo(pb1) + bf_lo(pb2) + bf_lo(pb3);
            by += bf_hi(pb0) + bf_hi(pb1) + bf_hi(pb2) + bf_hi(pb3);
            bx += bf_lo(pb4) + bf_lo(pb5) + bf_lo(pb6) + bf_lo(pb7);
            by += bf_hi(pb4) + bf_hi(pb5) + bf_hi(pb6) + bf_hi(pb7);
            ia += 8; ib += 8;
        }
        while (ia + 8 <= ea) {
            int4 a0 = csr4[(u32)ia >> 2];
            int4 a1 = csr4[((u32)ia >> 2) + 1];
            u32 p0 = hin32[((u32)a0.x << 6) + lane];
            u32 p1 = hin32[((u32)a0.y << 6) + lane];
            u32 p2 = hin32[((u32)a0.z << 6) + lane];
            u32 p3 = hin32[((u32)a0.w << 6) + lane];
            u32 p4 = hin32[((u32)a1.x << 6) + lane];
            u32 p5 = hin32[((u32)a1.y << 6) + lane];
            u32 p6 = hin32[((u32)a1.z << 6) + lane];
            u32 p7 = hin32[((u32)a1.w << 6) + lane];
            ax += bf_lo(p0) + bf_lo(p1) + bf_lo(p2) + bf_lo(p3);
            ay += bf_hi(p0) + bf_hi(p1) + bf_hi(p2) + bf_hi(p3);
            ax += bf_lo(p4) + bf_lo(p5) + bf_lo(p6) + bf_lo(p7);
            ay += bf_hi(p4) + bf_hi(p5) + bf_hi(p6) + bf_hi(p7);
            ia += 8;
        }
        if (ia < ea) {
            int4 a0 = csr4[(u32)ia >> 2];
            u32 p0 = hin32[((u32)a0.x << 6) + lane];
            u32 p1 = hin32[((u32)a0.y << 6) + lane];
            u32 p2 = hin32[((u32)a0.z << 6) + lane];
            u32 p3 = hin32[((u32)a0.w << 6) + lane];
            ax += bf_lo(p0) + bf_lo(p1) + bf_lo(p2) + bf_lo(p3);
            ay += bf_hi(p0) + bf_hi(p1) + bf_hi(p2) + bf_hi(p3);
        }
        while (ib + 8 <= eb) {
            int4 b0 = csr4[(u32)ib >> 2];
            int4 b1 = csr4[((u32)ib >> 2) + 1];
            u32 p0 = hin32[((u32)b0.x << 6) + lane];
            u32 p1 = hin32[((u32)b0.y << 6) + lane];
            u32 p2 = hin32[((u32)b0.z << 6) + lane];
            u32 p3 = hin32[((u32)b0.w << 6) + lane];
            u32 p4 = hin32[((u32)b1.x << 6) + lane];
            u32 p5 = hin32[((u32)b1.y << 6) + lane];
            u32 p6 = hin32[((u32)b1.z << 6) + lane];
            u32 p7 = hin32[((u32)b1.w << 6) + lane];
            bx += bf_lo(p0) + bf_lo(p1) + bf_lo(p2) + bf_lo(p3);
            by += bf_hi(p0) + bf_hi(p1) + bf_hi(p2) + bf_hi(p3);
            bx += bf_lo(p4) + bf_lo(p5) + bf_lo(p6) + bf_lo(p7);
            by += bf_hi(p4) + bf_hi(p5) + bf_hi(p6) + bf_hi(p7);
            ib += 8;
        }
        if (ib < eb) {
            int4 b0 = csr4[(u32)ib >> 2];
            u32 p0 = hin32[((u32)b0.x << 6) + lane];
            u32 p1 = hin32[((u32)b0.y << 6) + lane];
            u32 p2 = hin32[((u32)b0.z << 6) + lane];
            u32 p3 = hin32[((u32)b0.w << 6) + lane];
            bx += bf_lo(p0) + bf_lo(p1) + bf_lo(p2) + bf_lo(p3);
            by += bf_hi(p0) + bf_hi(p1) + bf_hi(p2) + bf_hi(p3);
        }
        if (hA) {
            sS[(wave * 8 + j) * 65 + lane] =
                (u32)f2bf(dva * ax) | ((u32)f2bf(dva * ay) << 16);
            if (lane == 0) dS[wave * 8 + j] = dva;
        }
        if (hB) {
            sS[(wave * 8 + j + 1) * 65 + lane] =
                (u32)f2bf(dvb * bx) | ((u32)f2bf(dvb * by) << 16);
            if (lane == 0) dS[wave * 8 + j + 1] = dvb;
        }
    }
    __syncthreads();

    // ---- Phase B: MFMA. Wave handles col-tiles {2w, 2w+1} x row-tiles {0,1}.
    f32x4 acc[2][2] = {{{0.f,0.f,0.f,0.f},{0.f,0.f,0.f,0.f}},
                       {{0.f,0.f,0.f,0.f},{0.f,0.f,0.f,0.f}}};
    int mA = lane & 15;
    int qA = lane >> 4;
    #pragma unroll
    for (int k0 = 0; k0 < 4; ++k0) {
        union { u32 u[4]; bf16x8 v; } A0, A1;
        int ub = k0 * 16 + qA * 4;
        #pragma unroll
        for (int tt = 0; tt < 4; ++tt) {
            A0.u[tt] = sS[mA * 65 + ub + tt];
            A1.u[tt] = sS[(mA + 16) * 65 + ub + tt];
        }
        #pragma unroll
        for (int ct = 0; ct < 2; ++ct) {
            int ntk = ((2 * wave + ct) * 4 + k0) * 64 + lane;
            union { uint4 q; bf16x8 v; } BH, BL;
            BH.q = ((const uint4*)whi)[ntk];
            BL.q = ((const uint4*)wlo)[ntk];
            acc[0][ct] = __builtin_amdgcn_mfma_f32_16x16x32_bf16(A0.v, BH.v, acc[0][ct], 0, 0, 0);
            acc[0][ct] = __builtin_amdgcn_mfma_f32_16x16x32_bf16(A0.v, BL.v, acc[0][ct], 0, 0, 0);
            acc[1][ct] = __builtin_amdgcn_mfma_f32_16x16x32_bf16(A1.v, BH.v, acc[1][ct], 0, 0, 0);
            acc[1][ct] = __builtin_amdgcn_mfma_f32_16x16x32_bf16(A1.v, BL.v, acc[1][ct], 0, 0, 0);
        }
    }
    // epilogue: D[col=lane&15, row=(lane>>4)*4+reg], bias+relu, bf16 store
    #pragma unroll
    for (int rt = 0; rt < 2; ++rt) {
        #pragma unroll
        for (int ct = 0; ct < 2; ++ct) {
            int col = (2 * wave + ct) * 16 + (lane & 15);
            float bb = bias[col];
            #pragma unroll
            for (int r = 0; r < 4; ++r) {
                int rloc = rt * 16 + (lane >> 4) * 4 + r;
                int row = row0 + rloc;
                if (row < N) {
                    float o = fmaxf(acc[rt][ct][r] + bb, 0.f);
                    if (scale_out) o *= dS[rloc];
                    hout[((u32)row << 7) + col] = f2bf(o);
                }
            }
        }
    }
}

// out[N x 16pad] = bf16 hin[N x 128] @ Wout[128 x C], C<=16.  16 rows/block.
__global__ __launch_bounds__(256) void k_gemmout(const u16* __restrict__ hin,
                                                 const float* __restrict__ Wout,
                                                 float* __restrict__ out, int N, int C) {
    __shared__ float hS[16 * 128];
    int tid = threadIdx.x;
    int row0 = blockIdx.x * 16;
    int nrows = N - row0; if (nrows > 16) nrows = 16;
    const u32* src = (const u32*)(hin + (size_t)row0 * 128);
    int nvec = nrows * 64;   // dwords
    #pragma unroll
    for (int i = 0; i < 4; ++i) {
        int idx = tid + 256 * i;
        if (idx < nvec) {
            u32 p = src[idx];
            int r = idx >> 6, j = idx & 63;
            hS[r * 128 + 2 * j]     = bf_lo(p);
            hS[r * 128 + 2 * j + 1] = bf_hi(p);
        }
    }
    __syncthreads();
    int c = tid & 15;
    int rr = tid >> 4;
    int row = row0 + rr;
    if (row < N && c < C) {
        float acc = 0.f;
        #pragma unroll 8
        for (int k = 0; k < 128; ++k) acc += hS[rr * 128 + k] * Wout[k * C + c];
        out[((u32)row << 4) + c] = acc;
    }
}

// Last-layer aggregate + pool. Wave per node, 4-way edge parallelism,
// true edge count from cnt (skips csr pads). tmp stride 16 (line-aligned).
__global__ __launch_bounds__(256) void k_aggout(const float* __restrict__ tmp,
                                                const int* __restrict__ rowptr,
                                                const int* __restrict__ cnt,
                                                const int* __restrict__ csr,
                                                const float* __restrict__ dis,
                                                const float* __restrict__ bout,
                                                const int* __restrict__ batch,
                                                float* __restrict__ pooled,
                                                int N, int C) {
    int wave = threadIdx.x >> 6;
    int lane = threadIdx.x & 63;
    int v = blockIdx.x * 4 + wave;
    if (v >= N) return;
    int g = lane >> 4;
    int c = lane & 15;
    bool cv = (c < C);
    float dv = dis[v];
    float acc = 0.f;
    if (g == 0 && cv) acc = dv * tmp[((u32)v << 4) + c];
    int s = rowptr[v], e = s + cnt[v];
    if (cv) {
        for (int i = s + g; i < e; i += 4) {
            int r = csr[i];
            acc += dis[r] * tmp[((u32)r << 4) + c];
        }
    }
    acc += __shfl_xor(acc, 16);
    acc += __shfl_xor(acc, 32);
    if (g == 0 && cv) {
        float o = dv * acc + bout[c];
        atomicAdd(&pooled[batch[v] * C + c], o);
    }
}

// Final: per-graph mean via binary search on sorted batch.
__global__ __launch_bounds__(256) void k_final(const float* __restrict__ pooled,
                                               const int* __restrict__ batch, int N,
                                               float* __restrict__ out, int G, int C) {
    int i = blockIdx.x * 256 + threadIdx.x;
    if (i >= G * C) return;
    int g = i / C;
    int lo = 0, hi = N;
    while (lo < hi) { int m = (lo + hi) >> 1; if (batch[m] < g) lo = m + 1; else hi = m; }
    int lb = lo;
    lo = 0; hi = N;
    while (lo < hi) { int m = (lo + hi) >> 1; if (batch[m] <= g) lo = m + 1; else hi = m; }
    float cntv = (float)(lo - lb);
    out[i] = pooled[i] / fmaxf(cntv, 1.0f);
}

extern "C" void kernel_launch(void* const* d_in, const int* in_sizes, int n_in,
                              void* d_out, int out_size, void* d_ws, size_t ws_size,
                              hipStream_t stream) {
    const float* x      = (const float*)d_in[0];
    const int*   ei     = (const int*)d_in[1];
    const int*   batch  = (const int*)d_in[2];
    const float* W_init = (const float*)d_in[3];
    const float* b_init = (const float*)d_in[4];
    const float* W_h0   = (const float*)d_in[5];
    const float* b_h0   = (const float*)d_in[6];
    const float* W_h1   = (const float*)d_in[7];
    const float* b_h1   = (const float*)d_in[8];
    const float* W_out  = (const float*)d_in[9];
    const float* b_out  = (const float*)d_in[10];

    int N = in_sizes[0] / 128;
    int E = in_sizes[1] / 2;
    int C = in_sizes[10];
    int G = out_size / C;

    size_t off = 0;
    auto alloc = [&](size_t bytes) -> char* {
        char* p = (char*)d_ws + off;
        off += (bytes + 255) & ~(size_t)255;
        return p;
    };
    u16*   bufX   = (u16*)  alloc((size_t)(N + 1) * 128 * 2);
    u16*   bufA   = (u16*)  alloc((size_t)(N + 1) * 128 * 2);
    u16*   bufB   = (u16*)  alloc((size_t)(N + 1) * 128 * 2);
    float* dis    = (float*)alloc((size_t)N * 4);
    int*   rowptr = (int*)  alloc((size_t)(N + 1) * 4);
    int*   csr    = (int*)  alloc(((size_t)E + 3 * (size_t)N + 8) * 4);
    int*   tsum   = (int*)  alloc((size_t)SCAN_THREADS * 4);
    u32*   whiA   = (u32*)  alloc(2048 * 16);
    u32*   wloA   = (u32*)  alloc(2048 * 16);
    u32*   whiB   = (u32*)  alloc(2048 * 16);
    u32*   wloB   = (u32*)  alloc(2048 * 16);
    u32*   whiC   = (u32*)  alloc(2048 * 16);
    u32*   wloC   = (u32*)  alloc(2048 * 16);
    size_t zoff   = off;
    int*   cnt    = (int*)  alloc((size_t)N * 4);
    float* pooled = (float*)alloc((size_t)G * C * 4);
    size_t zbytes = off - zoff;

    // aliases into dead regions (saves ws):
    int*   rank   = (int*)bufB;    // used between k_count and k_fill, before
                                   // bufB is first written (k_cast zero-row)
    float* tmpC   = (float*)bufX;  // used after bufX (layer-1 input) is dead

    hipMemsetAsync(cnt, 0, zbytes, stream);

    const int* rowi = ei;       // edge_index[0] = source
    const int* coli = ei + E;   // edge_index[1] = target

    int eb = (E + 255) / 256;
    k_count<<<eb, 256, 0, stream>>>(coli, E, cnt, rank);
    k_scan1<<<SCAN_BLOCKS, 256, 0, stream>>>(cnt, tsum, N);
    k_scan2<<<1, 1024, 0, stream>>>(tsum);
    k_scan3<<<SCAN_BLOCKS, 256, 0, stream>>>(cnt, tsum, rowptr, dis, csr, N);
    k_fill<<<eb, 256, 0, stream>>>(rowi, coli, E, rowptr, rank, csr);

    k_wprep<<<8, 256, 0, stream>>>(W_init, whiA, wloA);
    k_wprep<<<8, 256, 0, stream>>>(W_h0,   whiB, wloB);
    k_wprep<<<8, 256, 0, stream>>>(W_h1,   whiC, wloC);

    int cg = ((N + 1) * 32 + 255) / 256;
    k_cast<<<cg, 256, 0, stream>>>(x, dis, bufX, bufA, bufB, N);

    int fb = (N + 31) / 32;
    int ob = (N + 15) / 16;
    int ab4 = (N + 3) / 4;

    // hidden layers (activations stored as dis*h except the last)
    k_fused<<<fb, 256, 0, stream>>>(bufX, whiA, wloA, b_init, bufA, rowptr, csr, dis, N, 1);
    k_fused<<<fb, 256, 0, stream>>>(bufA, whiB, wloB, b_h0,   bufB, rowptr, csr, dis, N, 1);
    k_fused<<<fb, 256, 0, stream>>>(bufB, whiC, wloC, b_h1,   bufA, rowptr, csr, dis, N, 0);

    // output head: transform-first (narrow), aggregate+pool, mean
    k_gemmout<<<ob, 256, 0, stream>>>(bufA, W_out, tmpC, N, C);
    k_aggout <<<ab4, 256, 0, stream>>>(tmpC, rowptr, cnt, csr, dis, b_out, batch, pooled, N, C);
    k_final  <<<(G * C + 255) / 256, 256, 0, stream>>>(pooled, batch, N, (float*)d_out, G, C);
}

// Round 8
// 573.633 us; speedup vs baseline: 2.2585x; 1.0213x over previous
//
#include <hip/hip_runtime.h>

// ---------------------------------------------------------------------------
// GCN (PyG-style) on MI355X.
//   h = relu(Ahat (h W) + b) x3, then Ahat (h W_out) + b_out, mean-pool.
// R1: hierarchical scan. R2: fusion Ahat(hW)=(Ahat h)W. R3: bf16 activations.
// R4: dis-prescaled activations. R5: padded CSR + paired 16-deep gather.
// R6: MFMA phase B (double-pumped W=Whi+Wlo), rank-based fill.
// R7: aggout restructured for MLP: 4 nodes/wave x 16 feature lanes, 8-deep
//     unroll over padded CSR (pads -> zero row, no cnt mask), t pre-scaled
//     by dis in gemmout epilogue (no per-edge dis loads). wprep merged.
// ---------------------------------------------------------------------------

#define SCAN_BLOCKS 64
#define SCAN_THREADS (SCAN_BLOCKS * 256)   // 16384

typedef unsigned short u16;
typedef unsigned int   u32;
typedef __attribute__((ext_vector_type(8))) short bf16x8;   // 8 bf16 (4 VGPRs)
typedef __attribute__((ext_vector_type(4))) float f32x4;

static __device__ __forceinline__ u16 f2bf(float x) {
    u32 u = __float_as_uint(x);
    u32 r = (u + 0x7fffu + ((u >> 16) & 1u)) >> 16;   // RNE
    return (u16)r;
}
static __device__ __forceinline__ float bf_lo(u32 p) { return __uint_as_float(p << 16); }
static __device__ __forceinline__ float bf_hi(u32 p) { return __uint_as_float(p & 0xffff0000u); }

__global__ __launch_bounds__(256) void k_count(const int* __restrict__ col, int E,
                                               int* __restrict__ cnt,
                                               int* __restrict__ rank) {
    int e = blockIdx.x * 256 + threadIdx.x;
    if (e < E) rank[e] = atomicAdd(&cnt[col[e]], 1);
}

__global__ __launch_bounds__(256) void k_scan1(const int* __restrict__ cnt,
                                               int* __restrict__ tsum, int N) {
    int t = blockIdx.x * 256 + threadIdx.x;
    int strip = (N + SCAN_THREADS - 1) / SCAN_THREADS;
    int s0 = t * strip;
    int s1 = s0 + strip; if (s1 > N) s1 = N;
    int s = 0;
    for (int i = s0; i < s1; ++i) s += (cnt[i] + 3) & ~3;
    tsum[t] = s;
}

__global__ __launch_bounds__(1024) void k_scan2(int* __restrict__ tsum) {
    __shared__ int part[1024];
    int t = threadIdx.x;
    int base = t * 16;
    int local[16];
    int s = 0;
    #pragma unroll
    for (int i = 0; i < 16; ++i) { local[i] = tsum[base + i]; s += local[i]; }
    part[t] = s;
    __syncthreads();
    for (int off = 1; off < 1024; off <<= 1) {
        int v = part[t];
        int add = (t >= off) ? part[t - off] : 0;
        __syncthreads();
        part[t] = v + add;
        __syncthreads();
    }
    int run = (t == 0) ? 0 : part[t - 1];
    #pragma unroll
    for (int i = 0; i < 16; ++i) { int c = local[i]; tsum[base + i] = run; run += c; }
}

__global__ __launch_bounds__(256) void k_scan3(const int* __restrict__ cnt,
                                               const int* __restrict__ tsum,
                                               int* __restrict__ rowptr,
                                               float* __restrict__ dis,
                                               int* __restrict__ csr, int N) {
    int t = blockIdx.x * 256 + threadIdx.x;
    int strip = (N + SCAN_THREADS - 1) / SCAN_THREADS;
    int s0 = t * strip;
    int s1 = s0 + strip; if (s1 > N) s1 = N;
    int run = tsum[t];
    for (int i = s0; i < s1; ++i) {
        int c = cnt[i];
        int r = (c + 3) & ~3;
        rowptr[i] = run;
        for (int p = run + c; p < run + r; ++p) csr[p] = N;   // pads -> zero row
        run += r;
        dis[i] = rsqrtf((float)(c + 1));
    }
    if (t == SCAN_THREADS - 1) rowptr[N] = run;
}

// Scatter without atomics: rank captured during k_count.
__global__ __launch_bounds__(256) void k_fill(const int* __restrict__ row,
                                              const int* __restrict__ col, int E,
                                              const int* __restrict__ rowptr,
                                              const int* __restrict__ rank,
                                              int* __restrict__ csr) {
    int e = blockIdx.x * 256 + threadIdx.x;
    if (e < E) {
        int c = col[e];
        csr[rowptr[c] + rank[e]] = row[e];
    }
}

// fp32 -> bf16 cast pre-scaled by dis[v]; also zeroes dummy row N of all bufs.
__global__ __launch_bounds__(256) void k_cast(const float* __restrict__ src,
                                              const float* __restrict__ dis,
                                              u16* __restrict__ bX,
                                              u16* __restrict__ bA,
                                              u16* __restrict__ bB, int N) {
    int i = blockIdx.x * 256 + threadIdx.x;   // float4-group index over N+1 rows
    int total = (N + 1) * 32;
    if (i >= total) return;
    int v = i >> 5;
    if (v < N) {
        float dv = dis[v];
        float4 val = ((const float4*)src)[i];
        ushort4 o;
        o.x = f2bf(dv * val.x); o.y = f2bf(dv * val.y);
        o.z = f2bf(dv * val.z); o.w = f2bf(dv * val.w);
        ((ushort4*)bX)[i] = o;
    } else {
        ushort4 z = {0, 0, 0, 0};
        ((ushort4*)bX)[i] = z;
        ((ushort4*)bA)[i] = z;
        ((ushort4*)bB)[i] = z;
    }
}

// Pre-swizzle 3 weight matrices (128x128 fp32) into MFMA B-fragment order,
// split hi+lo bf16. One launch, grid 24: blockIdx/8 selects the matrix.
// Layout per matrix: [ntile(8)][k0(4)][lane(64)] -> uint4.
// Element j of lane's frag = W[k0*32 + (lane>>4)*8 + j][ntile*16 + (lane&15)].
__global__ __launch_bounds__(256) void k_wprep3(const float* __restrict__ W0,
                                                const float* __restrict__ W1,
                                                const float* __restrict__ W2,
                                                u32* __restrict__ whi,
                                                u32* __restrict__ wlo) {
    int which = blockIdx.x >> 3;
    const float* W = (which == 0) ? W0 : (which == 1) ? W1 : W2;
    int t = (blockIdx.x & 7) * 256 + threadIdx.x;   // 0..2047
    int lane = t & 63;
    int nk = t >> 6;
    int k0 = nk & 3;
    int ntile = nk >> 2;
    int n = ntile * 16 + (lane & 15);
    int kbase = k0 * 32 + (lane >> 4) * 8;
    u32 hi[4], lo[4];
    #pragma unroll
    for (int tt = 0; tt < 4; ++tt) {
        float w0 = W[(kbase + 2 * tt) * 128 + n];
        float w1 = W[(kbase + 2 * tt + 1) * 128 + n];
        u16 h0 = f2bf(w0), h1 = f2bf(w1);
        u16 l0 = f2bf(w0 - __uint_as_float((u32)h0 << 16));
        u16 l1 = f2bf(w1 - __uint_as_float((u32)h1 << 16));
        hi[tt] = (u32)h0 | ((u32)h1 << 16);
        lo[tt] = (u32)l0 | ((u32)l1 << 16);
    }
    uint4 qh = {hi[0], hi[1], hi[2], hi[3]};
    uint4 ql = {lo[0], lo[1], lo[2], lo[3]};
    int base = which * 2048;
    ((uint4*)whi)[base + t] = qh;
    ((uint4*)wlo)[base + t] = ql;
}

// Fused hidden layer. hin holds g = dis*h (bf16, N+1 rows, row N zero).
// Phase A: paired 16-deep gather -> packed-bf16 s-tile in LDS (stride 65).
// Phase B: MFMA 16x16x32 bf16, W double-pumped (hi+lo), fp32 acc, bias+relu.
__global__ __launch_bounds__(256) void k_fused(const u16* __restrict__ hin,
                                               const u32* __restrict__ whi,
                                               const u32* __restrict__ wlo,
                                               const float* __restrict__ bias,
                                               u16* __restrict__ hout,
                                               const int* __restrict__ rowptr,
                                               const int* __restrict__ csr,
                                               const float* __restrict__ dis,
                                               int N, int scale_out) {
    __shared__ u32 sS[32 * 65];
    __shared__ float dS[32];
    int tid = threadIdx.x;
    int wave = tid >> 6;
    int lane = tid & 63;
    int row0 = blockIdx.x * 32;
    const u32* hin32 = (const u32*)hin;       // row stride 64 dwords
    const int4* csr4 = (const int4*)csr;      // rowptr always multiple of 4

    // ---- Phase A ----
    for (int j = 0; j < 8; j += 2) {
        int va = row0 + wave * 8 + j;
        int vb = va + 1;
        bool hA = va < N, hB = vb < N;
        float ax = 0.f, ay = 0.f, bx = 0.f, by = 0.f;
        int ia = 0, ea = 0, ib = 0, eb = 0;
        float dva = 1.f, dvb = 1.f;
        if (hA) {
            u32 p = hin32[((u32)va << 6) + lane];
            ax = bf_lo(p); ay = bf_hi(p);
            ia = rowptr[va]; ea = rowptr[va + 1];
            dva = dis[va];
        }
        if (hB) {
            u32 p = hin32[((u32)vb << 6) + lane];
            bx = bf_lo(p); by = bf_hi(p);
            ib = rowptr[vb]; eb = rowptr[vb + 1];
            dvb = dis[vb];
        }
        while ((ia + 8 <= ea) & (ib + 8 <= eb)) {
            int4 a0 = csr4[(u32)ia >> 2];
            int4 a1 = csr4[((u32)ia >> 2) + 1];
            int4 b0 = csr4[(u32)ib >> 2];
            int4 b1 = csr4[((u32)ib >> 2) + 1];
            u32 pa0 = hin32[((u32)a0.x << 6) + lane];
            u32 pa1 = hin32[((u32)a0.y << 6) + lane];
            u32 pa2 = hin32[((u32)a0.z << 6) + lane];
            u32 pa3 = hin32[((u32)a0.w << 6) + lane];
            u32 pa4 = hin32[((u32)a1.x << 6) + lane];
            u32 pa5 = hin32[((u32)a1.y << 6) + lane];
            u32 pa6 = hin32[((u32)a1.z << 6) + lane];
            u32 pa7 = hin32[((u32)a1.w << 6) + lane];
            u32 pb0 = hin32[((u32)b0.x << 6) + lane];
            u32 pb1 = hin32[((u32)b0.y << 6) + lane];
            u32 pb2 = hin32[((u32)b0.z << 6) + lane];
            u32 pb3 = hin32[((u32)b0.w << 6) + lane];
            u32 pb4 = hin32[((u32)b1.x << 6) + lane];
            u32 pb5 = hin32[((u32)b1.y << 6) + lane];
            u32 pb6 = hin32[((u32)b1.z << 6) + lane];
            u32 pb7 = hin32[((u32)b1.w << 6) + lane];
            ax += bf_lo(pa0) + bf_lo(pa1) + bf_lo(pa2) + bf_lo(pa3);
            ay += bf_hi(pa0) + bf_hi(pa1) + bf_hi(pa2) + bf_hi(pa3);
            ax += bf_lo(pa4) + bf_lo(pa5) + bf_lo(pa6) + bf_lo(pa7);
            ay += bf_hi(pa4) + bf_hi(pa5) + bf_hi(pa6) + bf_hi(pa7);
            bx += bf_lo(pb0) + bf_lo(pb1) + bf_lo(pb2) + bf_lo(pb3);
            by += bf_hi(pb0) + bf_hi(pb1) + bf_hi(pb2) + bf_hi(pb3);
            bx += bf_lo(pb4) + bf_lo(pb5) + bf_lo(pb6) + bf_lo(pb7);
            by += bf_hi(pb4) + bf_hi(pb5) + bf_hi(pb6) + bf_hi(pb7);
            ia += 8; ib += 8;
        }
        while (ia + 8 <= ea) {
            int4 a0 = csr4[(u32)ia >> 2];
            int4 a1 = csr4[((u32)ia >> 2) + 1];
            u32 p0 = hin32[((u32)a0.x << 6) + lane];
            u32 p1 = hin32[((u32)a0.y << 6) + lane];
            u32 p2 = hin32[((u32)a0.z << 6) + lane];
            u32 p3 = hin32[((u32)a0.w << 6) + lane];
            u32 p4 = hin32[((u32)a1.x << 6) + lane];
            u32 p5 = hin32[((u32)a1.y << 6) + lane];
            u32 p6 = hin32[((u32)a1.z << 6) + lane];
            u32 p7 = hin32[((u32)a1.w << 6) + lane];
            ax += bf_lo(p0) + bf_lo(p1) + bf_lo(p2) + bf_lo(p3);
            ay += bf_hi(p0) + bf_hi(p1) + bf_hi(p2) + bf_hi(p3);
            ax += bf_lo(p4) + bf_lo(p5) + bf_lo(p6) + bf_lo(p7);
            ay += bf_hi(p4) + bf_hi(p5) + bf_hi(p6) + bf_hi(p7);
            ia += 8;
        }
        if (ia < ea) {
            int4 a0 = csr4[(u32)ia >> 2];
            u32 p0 = hin32[((u32)a0.x << 6) + lane];
            u32 p1 = hin32[((u32)a0.y << 6) + lane];
            u32 p2 = hin32[((u32)a0.z << 6) + lane];
            u32 p3 = hin32[((u32)a0.w << 6) + lane];
            ax += bf_lo(p0) + bf_lo(p1) + bf_lo(p2) + bf_lo(p3);
            ay += bf_hi(p0) + bf_hi(p1) + bf_hi(p2) + bf_hi(p3);
        }
        while (ib + 8 <= eb) {
            int4 b0 = csr4[(u32)ib >> 2];
            int4 b1 = csr4[((u32)ib >> 2) + 1];
            u32 p0 = hin32[((u32)b0.x << 6) + lane];
            u32 p1 = hin32[((u32)b0.y << 6) + lane];
            u32 p2 = hin32[((u32)b0.z << 6) + lane];
            u32 p3 = hin32[((u32)b0.w << 6) + lane];
            u32 p4 = hin32[((u32)b1.x << 6) + lane];
            u32 p5 = hin32[((u32)b1.y << 6) + lane];
            u32 p6 = hin32[((u32)b1.z << 6) + lane];
            u32 p7 = hin32[((u32)b1.w << 6) + lane];
            bx += bf_lo(p0) + bf_lo(p1) + bf_lo(p2) + bf_lo(p3);
            by += bf_hi(p0) + bf_hi(p1) + bf_hi(p2) + bf_hi(p3);
            bx += bf_lo(p4) + bf_lo(p5) + bf_lo(p6) + bf_lo(p7);
            by += bf_hi(p4) + bf_hi(p5) + bf_hi(p6) + bf_hi(p7);
            ib += 8;
        }
        if (ib < eb) {
            int4 b0 = csr4[(u32)ib >> 2];
            u32 p0 = hin32[((u32)b0.x << 6) + lane];
            u32 p1 = hin32[((u32)b0.y << 6) + lane];
            u32 p2 = hin32[((u32)b0.z << 6) + lane];
            u32 p3 = hin32[((u32)b0.w << 6) + lane];
            bx += bf_lo(p0) + bf_lo(p1) + bf_lo(p2) + bf_lo(p3);
            by += bf_hi(p0) + bf_hi(p1) + bf_hi(p2) + bf_hi(p3);
        }
        if (hA) {
            sS[(wave * 8 + j) * 65 + lane] =
                (u32)f2bf(dva * ax) | ((u32)f2bf(dva * ay) << 16);
            if (lane == 0) dS[wave * 8 + j] = dva;
        }
        if (hB) {
            sS[(wave * 8 + j + 1) * 65 + lane] =
                (u32)f2bf(dvb * bx) | ((u32)f2bf(dvb * by) << 16);
            if (lane == 0) dS[wave * 8 + j + 1] = dvb;
        }
    }
    __syncthreads();

    // ---- Phase B: MFMA. Wave handles col-tiles {2w, 2w+1} x row-tiles {0,1}.
    f32x4 acc[2][2] = {{{0.f,0.f,0.f,0.f},{0.f,0.f,0.f,0.f}},
                       {{0.f,0.f,0.f,0.f},{0.f,0.f,0.f,0.f}}};
    int mA = lane & 15;
    int qA = lane >> 4;
    #pragma unroll
    for (int k0 = 0; k0 < 4; ++k0) {
        union { u32 u[4]; bf16x8 v; } A0, A1;
        int ub = k0 * 16 + qA * 4;
        #pragma unroll
        for (int tt = 0; tt < 4; ++tt) {
            A0.u[tt] = sS[mA * 65 + ub + tt];
            A1.u[tt] = sS[(mA + 16) * 65 + ub + tt];
        }
        #pragma unroll
        for (int ct = 0; ct < 2; ++ct) {
            int ntk = ((2 * wave + ct) * 4 + k0) * 64 + lane;
            union { uint4 q; bf16x8 v; } BH, BL;
            BH.q = ((const uint4*)whi)[ntk];
            BL.q = ((const uint4*)wlo)[ntk];
            acc[0][ct] = __builtin_amdgcn_mfma_f32_16x16x32_bf16(A0.v, BH.v, acc[0][ct], 0, 0, 0);
            acc[0][ct] = __builtin_amdgcn_mfma_f32_16x16x32_bf16(A0.v, BL.v, acc[0][ct], 0, 0, 0);
            acc[1][ct] = __builtin_amdgcn_mfma_f32_16x16x32_bf16(A1.v, BH.v, acc[1][ct], 0, 0, 0);
            acc[1][ct] = __builtin_amdgcn_mfma_f32_16x16x32_bf16(A1.v, BL.v, acc[1][ct], 0, 0, 0);
        }
    }
    // epilogue: D[col=lane&15, row=(lane>>4)*4+reg], bias+relu, bf16 store
    #pragma unroll
    for (int rt = 0; rt < 2; ++rt) {
        #pragma unroll
        for (int ct = 0; ct < 2; ++ct) {
            int col = (2 * wave + ct) * 16 + (lane & 15);
            float bb = bias[col];
            #pragma unroll
            for (int r = 0; r < 4; ++r) {
                int rloc = rt * 16 + (lane >> 4) * 4 + r;
                int row = row0 + rloc;
                if (row < N) {
                    float o = fmaxf(acc[rt][ct][r] + bb, 0.f);
                    if (scale_out) o *= dS[rloc];
                    hout[((u32)row << 7) + col] = f2bf(o);
                }
            }
        }
    }
}

// out[(N+1) x 16] = dis * (bf16 hin[N x 128] @ Wout[128 x C]); row N zeroed.
__global__ __launch_bounds__(256) void k_gemmout(const u16* __restrict__ hin,
                                                 const float* __restrict__ Wout,
                                                 const float* __restrict__ dis,
                                                 float* __restrict__ out, int N, int C) {
    __shared__ float hS[16 * 128];
    int tid = threadIdx.x;
    int row0 = blockIdx.x * 16;
    if (blockIdx.x == 0 && tid < 16) out[((u32)N << 4) + tid] = 0.f;  // dummy row
    int nrows = N - row0; if (nrows > 16) nrows = 16;
    const u32* src = (const u32*)(hin + (size_t)row0 * 128);
    int nvec = nrows * 64;   // dwords
    #pragma unroll
    for (int i = 0; i < 4; ++i) {
        int idx = tid + 256 * i;
        if (idx < nvec) {
            u32 p = src[idx];
            int r = idx >> 6, j = idx & 63;
            hS[r * 128 + 2 * j]     = bf_lo(p);
            hS[r * 128 + 2 * j + 1] = bf_hi(p);
        }
    }
    __syncthreads();
    int c = tid & 15;
    int rr = tid >> 4;
    int row = row0 + rr;
    if (row < N) {
        float acc = 0.f;
        if (c < C) {
            #pragma unroll 8
            for (int k = 0; k < 128; ++k) acc += hS[rr * 128 + k] * Wout[k * C + c];
            acc *= dis[row];   // pre-scale: t' = dis * t
        }
        out[((u32)row << 4) + c] = acc;   // c>=C lanes write 0 (acc=0)
    }
}

// Last-layer aggregate + pool over t' = dis*t (stride 16, row N = zeros).
// Wave = 4 groups x 16 feature lanes; each group one node, 8-deep unroll over
// the PADDED csr (pads gather the zero row). 16 nodes/block -> 32 loads in
// flight per wave.
__global__ __launch_bounds__(256) void k_aggout(const float* __restrict__ tp,
                                                const int* __restrict__ rowptr,
                                                const int* __restrict__ csr,
                                                const float* __restrict__ dis,
                                                const float* __restrict__ bout,
                                                const int* __restrict__ batch,
                                                float* __restrict__ pooled,
                                                int N, int C) {
    int tid = threadIdx.x;
    int wave = tid >> 6;
    int lane = tid & 63;
    int g = lane >> 4;
    int c = lane & 15;
    int v = blockIdx.x * 16 + wave * 4 + g;
    if (v >= N) return;
    const int4* csr4 = (const int4*)csr;
    float acc = tp[((u32)v << 4) + c];          // self term (t'_v)
    int i = rowptr[v], e = rowptr[v + 1];
    for (; i + 8 <= e; i += 8) {
        int4 q0 = csr4[(u32)i >> 2];
        int4 q1 = csr4[((u32)i >> 2) + 1];
        float p0 = tp[((u32)q0.x << 4) + c];
        float p1 = tp[((u32)q0.y << 4) + c];
        float p2 = tp[((u32)q0.z << 4) + c];
        float p3 = tp[((u32)q0.w << 4) + c];
        float p4 = tp[((u32)q1.x << 4) + c];
        float p5 = tp[((u32)q1.y << 4) + c];
        float p6 = tp[((u32)q1.z << 4) + c];
        float p7 = tp[((u32)q1.w << 4) + c];
        acc += p0 + p1 + p2 + p3 + p4 + p5 + p6 + p7;
    }
    if (i < e) {   // remainder is exactly 4
        int4 q0 = csr4[(u32)i >> 2];
        float p0 = tp[((u32)q0.x << 4) + c];
        float p1 = tp[((u32)q0.y << 4) + c];
        float p2 = tp[((u32)q0.z << 4) + c];
        float p3 = tp[((u32)q0.w << 4) + c];
        acc += p0 + p1 + p2 + p3;
    }
    if (c < C) {
        float o = dis[v] * acc + bout[c];
        atomicAdd(&pooled[batch[v] * C + c], o);
    }
}

// Final: per-graph mean via binary search on sorted batch.
__global__ __launch_bounds__(256) void k_final(const float* __restrict__ pooled,
                                               const int* __restrict__ batch, int N,
                                               float* __restrict__ out, int G, int C) {
    int i = blockIdx.x * 256 + threadIdx.x;
    if (i >= G * C) return;
    int g = i / C;
    int lo = 0, hi = N;
    while (lo < hi) { int m = (lo + hi) >> 1; if (batch[m] < g) lo = m + 1; else hi = m; }
    int lb = lo;
    lo = 0; hi = N;
    while (lo < hi) { int m = (lo + hi) >> 1; if (batch[m] <= g) lo = m + 1; else hi = m; }
    float cntv = (float)(lo - lb);
    out[i] = pooled[i] / fmaxf(cntv, 1.0f);
}

extern "C" void kernel_launch(void* const* d_in, const int* in_sizes, int n_in,
                              void* d_out, int out_size, void* d_ws, size_t ws_size,
                              hipStream_t stream) {
    const float* x      = (const float*)d_in[0];
    const int*   ei     = (const int*)d_in[1];
    const int*   batch  = (const int*)d_in[2];
    const float* W_init = (const float*)d_in[3];
    const float* b_init = (const float*)d_in[4];
    const float* W_h0   = (const float*)d_in[5];
    const float* b_h0   = (const float*)d_in[6];
    const float* W_h1   = (const float*)d_in[7];
    const float* b_h1   = (const float*)d_in[8];
    const float* W_out  = (const float*)d_in[9];
    const float* b_out  = (const float*)d_in[10];

    int N = in_sizes[0] / 128;
    int E = in_sizes[1] / 2;
    int C = in_sizes[10];
    int G = out_size / C;

    size_t off = 0;
    auto alloc = [&](size_t bytes) -> char* {
        char* p = (char*)d_ws + off;
        off += (bytes + 255) & ~(size_t)255;
        return p;
    };
    u16*   bufX   = (u16*)  alloc((size_t)(N + 1) * 128 * 2);
    u16*   bufA   = (u16*)  alloc((size_t)(N + 1) * 128 * 2);
    u16*   bufB   = (u16*)  alloc((size_t)(N + 1) * 128 * 2);
    float* dis    = (float*)alloc((size_t)N * 4);
    int*   rowptr = (int*)  alloc((size_t)(N + 1) * 4);
    int*   csr    = (int*)  alloc(((size_t)E + 3 * (size_t)N + 8) * 4);
    int*   tsum   = (int*)  alloc((size_t)SCAN_THREADS * 4);
    u32*   whi    = (u32*)  alloc(3 * 2048 * 16);
    u32*   wlo    = (u32*)  alloc(3 * 2048 * 16);
    size_t zoff   = off;
    int*   cnt    = (int*)  alloc((size_t)N * 4);
    float* pooled = (float*)alloc((size_t)G * C * 4);
    size_t zbytes = off - zoff;

    // aliases into dead regions:
    int*   rank   = (int*)bufB;    // live between k_count and k_fill, before
                                   // bufB's first write (k_cast zero-row)
    float* tmpC   = (float*)bufX;  // (N+1)x16 fp32; live after bufX is dead

    hipMemsetAsync(cnt, 0, zbytes, stream);

    const int* rowi = ei;       // edge_index[0] = source
    const int* coli = ei + E;   // edge_index[1] = target

    int eb = (E + 255) / 256;
    k_count<<<eb, 256, 0, stream>>>(coli, E, cnt, rank);
    k_scan1<<<SCAN_BLOCKS, 256, 0, stream>>>(cnt, tsum, N);
    k_scan2<<<1, 1024, 0, stream>>>(tsum);
    k_scan3<<<SCAN_BLOCKS, 256, 0, stream>>>(cnt, tsum, rowptr, dis, csr, N);
    k_fill<<<eb, 256, 0, stream>>>(rowi, coli, E, rowptr, rank, csr);

    k_wprep3<<<24, 256, 0, stream>>>(W_init, W_h0, W_h1, whi, wlo);

    int cg = ((N + 1) * 32 + 255) / 256;
    k_cast<<<cg, 256, 0, stream>>>(x, dis, bufX, bufA, bufB, N);

    int fb = (N + 31) / 32;
    int ob = (N + 15) / 16;

    // hidden layers (activations stored as dis*h except the last)
    k_fused<<<fb, 256, 0, stream>>>(bufX, whi,        wlo,        b_init, bufA, rowptr, csr, dis, N, 1);
    k_fused<<<fb, 256, 0, stream>>>(bufA, whi + 8192, wlo + 8192, b_h0,   bufB, rowptr, csr, dis, N, 1);
    k_fused<<<fb, 256, 0, stream>>>(bufB, whi + 16384, wlo + 16384, b_h1, bufA, rowptr, csr, dis, N, 0);

    // output head: transform-first (t' = dis*t, stride 16), aggregate+pool, mean
    k_gemmout<<<ob, 256, 0, stream>>>(bufA, W_out, dis, tmpC, N, C);
    k_aggout <<<ob, 256, 0, stream>>>(tmpC, rowptr, csr, dis, b_out, batch, pooled, N, C);
    k_final  <<<(G * C + 255) / 256, 256, 0, stream>>>(pooled, batch, N, (float*)d_out, G, C);
}

// Round 10
// 515.582 us; speedup vs baseline: 2.5128x; 1.1126x over previous
//
#include <hip/hip_runtime.h>

// ---------------------------------------------------------------------------
// GCN (PyG-style) on MI355X.
//   h = relu(Ahat (h W) + b) x3, then Ahat (h W_out) + b_out, mean-pool.
// R1: hierarchical scan. R2: fusion Ahat(hW)=(Ahat h)W. R3: bf16 activations.
// R4: dis-prescaled activations. R5: padded CSR + paired 16-deep gather.
// R6: MFMA phase B (double-pumped W=Whi+Wlo), rank-based fill.
// R7: aggout 4 nodes/wave, t' = dis*t stride 16.
// R8: KILL the pooled-array atomics (1M device-scope RMWs on 20KB = the ~95us
//     invariant across all aggout variants). aggout now stores per-node rows
//     coalesced; new k_pool does a block-per-graph segmented reduction over
//     the sorted batch (binary-searched range, LDS tree reduce), absorbing
//     k_final. Bias folded as cnt*b to preserve empty-graph semantics.
// R9: resubmit of R8 (container-level infra failure, no kernel diagnostics).
// ---------------------------------------------------------------------------

#define SCAN_BLOCKS 64
#define SCAN_THREADS (SCAN_BLOCKS * 256)   // 16384

typedef unsigned short u16;
typedef unsigned int   u32;
typedef __attribute__((ext_vector_type(8))) short bf16x8;   // 8 bf16 (4 VGPRs)
typedef __attribute__((ext_vector_type(4))) float f32x4;

static __device__ __forceinline__ u16 f2bf(float x) {
    u32 u = __float_as_uint(x);
    u32 r = (u + 0x7fffu + ((u >> 16) & 1u)) >> 16;   // RNE
    return (u16)r;
}
static __device__ __forceinline__ float bf_lo(u32 p) { return __uint_as_float(p << 16); }
static __device__ __forceinline__ float bf_hi(u32 p) { return __uint_as_float(p & 0xffff0000u); }

__global__ __launch_bounds__(256) void k_count(const int* __restrict__ col, int E,
                                               int* __restrict__ cnt,
                                               int* __restrict__ rank) {
    int e = blockIdx.x * 256 + threadIdx.x;
    if (e < E) rank[e] = atomicAdd(&cnt[col[e]], 1);
}

__global__ __launch_bounds__(256) void k_scan1(const int* __restrict__ cnt,
                                               int* __restrict__ tsum, int N) {
    int t = blockIdx.x * 256 + threadIdx.x;
    int strip = (N + SCAN_THREADS - 1) / SCAN_THREADS;
    int s0 = t * strip;
    int s1 = s0 + strip; if (s1 > N) s1 = N;
    int s = 0;
    for (int i = s0; i < s1; ++i) s += (cnt[i] + 3) & ~3;
    tsum[t] = s;
}

__global__ __launch_bounds__(1024) void k_scan2(int* __restrict__ tsum) {
    __shared__ int part[1024];
    int t = threadIdx.x;
    int base = t * 16;
    int local[16];
    int s = 0;
    #pragma unroll
    for (int i = 0; i < 16; ++i) { local[i] = tsum[base + i]; s += local[i]; }
    part[t] = s;
    __syncthreads();
    for (int off = 1; off < 1024; off <<= 1) {
        int v = part[t];
        int add = (t >= off) ? part[t - off] : 0;
        __syncthreads();
        part[t] = v + add;
        __syncthreads();
    }
    int run = (t == 0) ? 0 : part[t - 1];
    #pragma unroll
    for (int i = 0; i < 16; ++i) { int c = local[i]; tsum[base + i] = run; run += c; }
}

__global__ __launch_bounds__(256) void k_scan3(const int* __restrict__ cnt,
                                               const int* __restrict__ tsum,
                                               int* __restrict__ rowptr,
                                               float* __restrict__ dis,
                                               int* __restrict__ csr, int N) {
    int t = blockIdx.x * 256 + threadIdx.x;
    int strip = (N + SCAN_THREADS - 1) / SCAN_THREADS;
    int s0 = t * strip;
    int s1 = s0 + strip; if (s1 > N) s1 = N;
    int run = tsum[t];
    for (int i = s0; i < s1; ++i) {
        int c = cnt[i];
        int r = (c + 3) & ~3;
        rowptr[i] = run;
        for (int p = run + c; p < run + r; ++p) csr[p] = N;   // pads -> zero row
        run += r;
        dis[i] = rsqrtf((float)(c + 1));
    }
    if (t == SCAN_THREADS - 1) rowptr[N] = run;
}

// Scatter without atomics: rank captured during k_count.
__global__ __launch_bounds__(256) void k_fill(const int* __restrict__ row,
                                              const int* __restrict__ col, int E,
                                              const int* __restrict__ rowptr,
                                              const int* __restrict__ rank,
                                              int* __restrict__ csr) {
    int e = blockIdx.x * 256 + threadIdx.x;
    if (e < E) {
        int c = col[e];
        csr[rowptr[c] + rank[e]] = row[e];
    }
}

// fp32 -> bf16 cast pre-scaled by dis[v]; also zeroes dummy row N of all bufs.
__global__ __launch_bounds__(256) void k_cast(const float* __restrict__ src,
                                              const float* __restrict__ dis,
                                              u16* __restrict__ bX,
                                              u16* __restrict__ bA,
                                              u16* __restrict__ bB, int N) {
    int i = blockIdx.x * 256 + threadIdx.x;   // float4-group index over N+1 rows
    int total = (N + 1) * 32;
    if (i >= total) return;
    int v = i >> 5;
    if (v < N) {
        float dv = dis[v];
        float4 val = ((const float4*)src)[i];
        ushort4 o;
        o.x = f2bf(dv * val.x); o.y = f2bf(dv * val.y);
        o.z = f2bf(dv * val.z); o.w = f2bf(dv * val.w);
        ((ushort4*)bX)[i] = o;
    } else {
        ushort4 z = {0, 0, 0, 0};
        ((ushort4*)bX)[i] = z;
        ((ushort4*)bA)[i] = z;
        ((ushort4*)bB)[i] = z;
    }
}

// Pre-swizzle 3 weight matrices (128x128 fp32) into MFMA B-fragment order,
// split hi+lo bf16. One launch, grid 24: blockIdx/8 selects the matrix.
__global__ __launch_bounds__(256) void k_wprep3(const float* __restrict__ W0,
                                                const float* __restrict__ W1,
                                                const float* __restrict__ W2,
                                                u32* __restrict__ whi,
                                                u32* __restrict__ wlo) {
    int which = blockIdx.x >> 3;
    const float* W = (which == 0) ? W0 : (which == 1) ? W1 : W2;
    int t = (blockIdx.x & 7) * 256 + threadIdx.x;   // 0..2047
    int lane = t & 63;
    int nk = t >> 6;
    int k0 = nk & 3;
    int ntile = nk >> 2;
    int n = ntile * 16 + (lane & 15);
    int kbase = k0 * 32 + (lane >> 4) * 8;
    u32 hi[4], lo[4];
    #pragma unroll
    for (int tt = 0; tt < 4; ++tt) {
        float w0 = W[(kbase + 2 * tt) * 128 + n];
        float w1 = W[(kbase + 2 * tt + 1) * 128 + n];
        u16 h0 = f2bf(w0), h1 = f2bf(w1);
        u16 l0 = f2bf(w0 - __uint_as_float((u32)h0 << 16));
        u16 l1 = f2bf(w1 - __uint_as_float((u32)h1 << 16));
        hi[tt] = (u32)h0 | ((u32)h1 << 16);
        lo[tt] = (u32)l0 | ((u32)l1 << 16);
    }
    uint4 qh = {hi[0], hi[1], hi[2], hi[3]};
    uint4 ql = {lo[0], lo[1], lo[2], lo[3]};
    int base = which * 2048;
    ((uint4*)whi)[base + t] = qh;
    ((uint4*)wlo)[base + t] = ql;
}

// Fused hidden layer. hin holds g = dis*h (bf16, N+1 rows, row N zero).
// Phase A: paired 16-deep gather -> packed-bf16 s-tile in LDS (stride 65).
// Phase B: MFMA 16x16x32 bf16, W double-pumped (hi+lo), fp32 acc, bias+relu.
__global__ __launch_bounds__(256) void k_fused(const u16* __restrict__ hin,
                                               const u32* __restrict__ whi,
                                               const u32* __restrict__ wlo,
                                               const float* __restrict__ bias,
                                               u16* __restrict__ hout,
                                               const int* __restrict__ rowptr,
                                               const int* __restrict__ csr,
                                               const float* __restrict__ dis,
                                               int N, int scale_out) {
    __shared__ u32 sS[32 * 65];
    __shared__ float dS[32];
    int tid = threadIdx.x;
    int wave = tid >> 6;
    int lane = tid & 63;
    int row0 = blockIdx.x * 32;
    const u32* hin32 = (const u32*)hin;       // row stride 64 dwords
    const int4* csr4 = (const int4*)csr;      // rowptr always multiple of 4

    // ---- Phase A ----
    for (int j = 0; j < 8; j += 2) {
        int va = row0 + wave * 8 + j;
        int vb = va + 1;
        bool hA = va < N, hB = vb < N;
        float ax = 0.f, ay = 0.f, bx = 0.f, by = 0.f;
        int ia = 0, ea = 0, ib = 0, eb = 0;
        float dva = 1.f, dvb = 1.f;
        if (hA) {
            u32 p = hin32[((u32)va << 6) + lane];
            ax = bf_lo(p); ay = bf_hi(p);
            ia = rowptr[va]; ea = rowptr[va + 1];
            dva = dis[va];
        }
        if (hB) {
            u32 p = hin32[((u32)vb << 6) + lane];
            bx = bf_lo(p); by = bf_hi(p);
            ib = rowptr[vb]; eb = rowptr[vb + 1];
            dvb = dis[vb];
        }
        while ((ia + 8 <= ea) & (ib + 8 <= eb)) {
            int4 a0 = csr4[(u32)ia >> 2];
            int4 a1 = csr4[((u32)ia >> 2) + 1];
            int4 b0 = csr4[(u32)ib >> 2];
            int4 b1 = csr4[((u32)ib >> 2) + 1];
            u32 pa0 = hin32[((u32)a0.x << 6) + lane];
            u32 pa1 = hin32[((u32)a0.y << 6) + lane];
            u32 pa2 = hin32[((u32)a0.z << 6) + lane];
            u32 pa3 = hin32[((u32)a0.w << 6) + lane];
            u32 pa4 = hin32[((u32)a1.x << 6) + lane];
            u32 pa5 = hin32[((u32)a1.y << 6) + lane];
            u32 pa6 = hin32[((u32)a1.z << 6) + lane];
            u32 pa7 = hin32[((u32)a1.w << 6) + lane];
            u32 pb0 = hin32[((u32)b0.x << 6) + lane];
            u32 pb1 = hin32[((u32)b0.y << 6) + lane];
            u32 pb2 = hin32[((u32)b0.z << 6) + lane];
            u32 pb3 = hin32[((u32)b0.w << 6) + lane];
            u32 pb4 = hin32[((u32)b1.x << 6) + lane];
            u32 pb5 = hin32[((u32)b1.y << 6) + lane];
            u32 pb6 = hin32[((u32)b1.z << 6) + lane];
            u32 pb7 = hin32[((u32)b1.w << 6) + lane];
            ax += bf_lo(pa0) + bf_lo(pa1) + bf_lo(pa2) + bf_lo(pa3);
            ay += bf_hi(pa0) + bf_hi(pa1) + bf_hi(pa2) + bf_hi(pa3);
            ax += bf_lo(pa4) + bf_lo(pa5) + bf_lo(pa6) + bf_lo(pa7);
            ay += bf_hi(pa4) + bf_hi(pa5) + bf_hi(pa6) + bf_hi(pa7);
            bx += bf_lo(pb0) + bf_lo(pb1) + bf_lo(pb2) + bf_lo(pb3);
            by += bf_hi(pb0) + bf_hi(pb1) + bf_hi(pb2) + bf_hi(pb3);
            bx += bf_lo(pb4) + bf_lo(pb5) + bf_lo(pb6) + bf_lo(pb7);
            by += bf_hi(pb4) + bf_hi(pb5) + bf_hi(pb6) + bf_hi(pb7);
            ia += 8; ib += 8;
        }
        while (ia + 8 <= ea) {
            int4 a0 = csr4[(u32)ia >> 2];
            int4 a1 = csr4[((u32)ia >> 2) + 1];
            u32 p0 = hin32[((u32)a0.x << 6) + lane];
            u32 p1 = hin32[((u32)a0.y << 6) + lane];
            u32 p2 = hin32[((u32)a0.z << 6) + lane];
            u32 p3 = hin32[((u32)a0.w << 6) + lane];
            u32 p4 = hin32[((u32)a1.x << 6) + lane];
            u32 p5 = hin32[((u32)a1.y << 6) + lane];
            u32 p6 = hin32[((u32)a1.z << 6) + lane];
            u32 p7 = hin32[((u32)a1.w << 6) + lane];
            ax += bf_lo(p0) + bf_lo(p1) + bf_lo(p2) + bf_lo(p3);
            ay += bf_hi(p0) + bf_hi(p1) + bf_hi(p2) + bf_hi(p3);
            ax += bf_lo(p4) + bf_lo(p5) + bf_lo(p6) + bf_lo(p7);
            ay += bf_hi(p4) + bf_hi(p5) + bf_hi(p6) + bf_hi(p7);
            ia += 8;
        }
        if (ia < ea) {
            int4 a0 = csr4[(u32)ia >> 2];
            u32 p0 = hin32[((u32)a0.x << 6) + lane];
            u32 p1 = hin32[((u32)a0.y << 6) + lane];
            u32 p2 = hin32[((u32)a0.z << 6) + lane];
            u32 p3 = hin32[((u32)a0.w << 6) + lane];
            ax += bf_lo(p0) + bf_lo(p1) + bf_lo(p2) + bf_lo(p3);
            ay += bf_hi(p0) + bf_hi(p1) + bf_hi(p2) + bf_hi(p3);
        }
        while (ib + 8 <= eb) {
            int4 b0 = csr4[(u32)ib >> 2];
            int4 b1 = csr4[((u32)ib >> 2) + 1];
            u32 p0 = hin32[((u32)b0.x << 6) + lane];
            u32 p1 = hin32[((u32)b0.y << 6) + lane];
            u32 p2 = hin32[((u32)b0.z << 6) + lane];
            u32 p3 = hin32[((u32)b0.w << 6) + lane];
            u32 p4 = hin32[((u32)b1.x << 6) + lane];
            u32 p5 = hin32[((u32)b1.y << 6) + lane];
            u32 p6 = hin32[((u32)b1.z << 6) + lane];
            u32 p7 = hin32[((u32)b1.w << 6) + lane];
            bx += bf_lo(p0) + bf_lo(p1) + bf_lo(p2) + bf_lo(p3);
            by += bf_hi(p0) + bf_hi(p1) + bf_hi(p2) + bf_hi(p3);
            bx += bf_lo(p4) + bf_lo(p5) + bf_lo(p6) + bf_lo(p7);
            by += bf_hi(p4) + bf_hi(p5) + bf_hi(p6) + bf_hi(p7);
            ib += 8;
        }
        if (ib < eb) {
            int4 b0 = csr4[(u32)ib >> 2];
            u32 p0 = hin32[((u32)b0.x << 6) + lane];
            u32 p1 = hin32[((u32)b0.y << 6) + lane];
            u32 p2 = hin32[((u32)b0.z << 6) + lane];
            u32 p3 = hin32[((u32)b0.w << 6) + lane];
            bx += bf_lo(p0) + bf_lo(p1) + bf_lo(p2) + bf_lo(p3);
            by += bf_hi(p0) + bf_hi(p1) + bf_hi(p2) + bf_hi(p3);
        }
        if (hA) {
            sS[(wave * 8 + j) * 65 + lane] =
                (u32)f2bf(dva * ax) | ((u32)f2bf(dva * ay) << 16);
            if (lane == 0) dS[wave * 8 + j] = dva;
        }
        if (hB) {
            sS[(wave * 8 + j + 1) * 65 + lane] =
                (u32)f2bf(dvb * bx) | ((u32)f2bf(dvb * by) << 16);
            if (lane == 0) dS[wave * 8 + j + 1] = dvb;
        }
    }
    __syncthreads();

    // ---- Phase B: MFMA. Wave handles col-tiles {2w, 2w+1} x row-tiles {0,1}.
    f32x4 acc[2][2] = {{{0.f,0.f,0.f,0.f},{0.f,0.f,0.f,0.f}},
                       {{0.f,0.f,0.f,0.f},{0.f,0.f,0.f,0.f}}};
    int mA = lane & 15;
    int qA = lane >> 4;
    #pragma unroll
    for (int k0 = 0; k0 < 4; ++k0) {
        union { u32 u[4]; bf16x8 v; } A0, A1;
        int ub = k0 * 16 + qA * 4;
        #pragma unroll
        for (int tt = 0; tt < 4; ++tt) {
            A0.u[tt] = sS[mA * 65 + ub + tt];
            A1.u[tt] = sS[(mA + 16) * 65 + ub + tt];
        }
        #pragma unroll
        for (int ct = 0; ct < 2; ++ct) {
            int ntk = ((2 * wave + ct) * 4 + k0) * 64 + lane;
            union { uint4 q; bf16x8 v; } BH, BL;
            BH.q = ((const uint4*)whi)[ntk];
            BL.q = ((const uint4*)wlo)[ntk];
            acc[0][ct] = __builtin_amdgcn_mfma_f32_16x16x32_bf16(A0.v, BH.v, acc[0][ct], 0, 0, 0);
            acc[0][ct] = __builtin_amdgcn_mfma_f32_16x16x32_bf16(A0.v, BL.v, acc[0][ct], 0, 0, 0);
            acc[1][ct] = __builtin_amdgcn_mfma_f32_16x16x32_bf16(A1.v, BH.v, acc[1][ct], 0, 0, 0);
            acc[1][ct] = __builtin_amdgcn_mfma_f32_16x16x32_bf16(A1.v, BL.v, acc[1][ct], 0, 0, 0);
        }
    }
    // epilogue: D[col=lane&15, row=(lane>>4)*4+reg], bias+relu, bf16 store
    #pragma unroll
    for (int rt = 0; rt < 2; ++rt) {
        #pragma unroll
        for (int ct = 0; ct < 2; ++ct) {
            int col = (2 * wave + ct) * 16 + (lane & 15);
            float bb = bias[col];
            #pragma unroll
            for (int r = 0; r < 4; ++r) {
                int rloc = rt * 16 + (lane >> 4) * 4 + r;
                int row = row0 + rloc;
                if (row < N) {
                    float o = fmaxf(acc[rt][ct][r] + bb, 0.f);
                    if (scale_out) o *= dS[rloc];
                    hout[((u32)row << 7) + col] = f2bf(o);
                }
            }
        }
    }
}

// out[(N+1) x 16] = dis * (bf16 hin[N x 128] @ Wout[128 x C]); row N zeroed.
__global__ __launch_bounds__(256) void k_gemmout(const u16* __restrict__ hin,
                                                 const float* __restrict__ Wout,
                                                 const float* __restrict__ dis,
                                                 float* __restrict__ out, int N, int C) {
    __shared__ float hS[16 * 128];
    int tid = threadIdx.x;
    int row0 = blockIdx.x * 16;
    if (blockIdx.x == 0 && tid < 16) out[((u32)N << 4) + tid] = 0.f;  // dummy row
    int nrows = N - row0; if (nrows > 16) nrows = 16;
    const u32* src = (const u32*)(hin + (size_t)row0 * 128);
    int nvec = nrows * 64;   // dwords
    #pragma unroll
    for (int i = 0; i < 4; ++i) {
        int idx = tid + 256 * i;
        if (idx < nvec) {
            u32 p = src[idx];
            int r = idx >> 6, j = idx & 63;
            hS[r * 128 + 2 * j]     = bf_lo(p);
            hS[r * 128 + 2 * j + 1] = bf_hi(p);
        }
    }
    __syncthreads();
    int c = tid & 15;
    int rr = tid >> 4;
    int row = row0 + rr;
    if (row < N) {
        float acc = 0.f;
        if (c < C) {
            #pragma unroll 8
            for (int k = 0; k < 128; ++k) acc += hS[rr * 128 + k] * Wout[k * C + c];
            acc *= dis[row];   // pre-scale: t' = dis * t
        }
        out[((u32)row << 4) + c] = acc;   // c>=C lanes write 0 (acc=0)
    }
}

// Last-layer aggregate over t' = dis*t (stride 16, row N = zeros).
// Wave = 4 groups x 16 feature lanes; each group one node, 8-deep unroll over
// the PADDED csr. Plain coalesced store of the per-node row — NO atomics.
__global__ __launch_bounds__(256) void k_aggout(const float* __restrict__ tp,
                                                const int* __restrict__ rowptr,
                                                const int* __restrict__ csr,
                                                const float* __restrict__ dis,
                                                float* __restrict__ node,
                                                int N) {
    int tid = threadIdx.x;
    int wave = tid >> 6;
    int lane = tid & 63;
    int g = lane >> 4;
    int c = lane & 15;
    int v = blockIdx.x * 16 + wave * 4 + g;
    if (v >= N) return;
    const int4* csr4 = (const int4*)csr;
    float acc = tp[((u32)v << 4) + c];          // self term (t'_v)
    int i = rowptr[v], e = rowptr[v + 1];
    for (; i + 8 <= e; i += 8) {
        int4 q0 = csr4[(u32)i >> 2];
        int4 q1 = csr4[((u32)i >> 2) + 1];
        float p0 = tp[((u32)q0.x << 4) + c];
        float p1 = tp[((u32)q0.y << 4) + c];
        float p2 = tp[((u32)q0.z << 4) + c];
        float p3 = tp[((u32)q0.w << 4) + c];
        float p4 = tp[((u32)q1.x << 4) + c];
        float p5 = tp[((u32)q1.y << 4) + c];
        float p6 = tp[((u32)q1.z << 4) + c];
        float p7 = tp[((u32)q1.w << 4) + c];
        acc += p0 + p1 + p2 + p3 + p4 + p5 + p6 + p7;
    }
    if (i < e) {   // remainder is exactly 4
        int4 q0 = csr4[(u32)i >> 2];
        float p0 = tp[((u32)q0.x << 4) + c];
        float p1 = tp[((u32)q0.y << 4) + c];
        float p2 = tp[((u32)q0.z << 4) + c];
        float p3 = tp[((u32)q0.w << 4) + c];
        acc += p0 + p1 + p2 + p3;
    }
    node[((u32)v << 4) + c] = dis[v] * acc;     // bias folded into k_pool
}

// Block-per-graph mean pool over the sorted batch: binary-searched range,
// strided coalesced sum, LDS tree reduce. out = (sum + cnt*b)/max(cnt,1).
__global__ __launch_bounds__(256) void k_pool(const float* __restrict__ node,
                                              const int* __restrict__ batch,
                                              const float* __restrict__ bout,
                                              float* __restrict__ out,
                                              int N, int C) {
    __shared__ float red[256];
    int g = blockIdx.x;
    int tid = threadIdx.x;
    int c = tid & 15;
    int rg = tid >> 4;
    int lo = 0, hi = N;
    while (lo < hi) { int m = (lo + hi) >> 1; if (batch[m] < g) lo = m + 1; else hi = m; }
    int lb = lo;
    hi = N;
    while (lo < hi) { int m = (lo + hi) >> 1; if (batch[m] <= g) lo = m + 1; else hi = m; }
    int ub = lo;
    float acc = 0.f;
    for (int v = lb + rg; v < ub; v += 16)
        acc += node[((u32)v << 4) + c];
    red[tid] = acc;
    __syncthreads();
    #pragma unroll
    for (int s = 8; s >= 1; s >>= 1) {
        if (rg < s) red[tid] += red[tid + s * 16];
        __syncthreads();
    }
    if (tid < C) {
        float cnt = (float)(ub - lb);
        out[g * C + tid] = (red[tid] + cnt * bout[tid]) / fmaxf(cnt, 1.0f);
    }
}

extern "C" void kernel_launch(void* const* d_in, const int* in_sizes, int n_in,
                              void* d_out, int out_size, void* d_ws, size_t ws_size,
                              hipStream_t stream) {
    const float* x      = (const float*)d_in[0];
    const int*   ei     = (const int*)d_in[1];
    const int*   batch  = (const int*)d_in[2];
    const float* W_init = (const float*)d_in[3];
    const float* b_init = (const float*)d_in[4];
    const float* W_h0   = (const float*)d_in[5];
    const float* b_h0   = (const float*)d_in[6];
    const float* W_h1   = (const float*)d_in[7];
    const float* b_h1   = (const float*)d_in[8];
    const float* W_out  = (const float*)d_in[9];
    const float* b_out  = (const float*)d_in[10];

    int N = in_sizes[0] / 128;
    int E = in_sizes[1] / 2;
    int C = in_sizes[10];
    int G = out_size / C;

    size_t off = 0;
    auto alloc = [&](size_t bytes) -> char* {
        char* p = (char*)d_ws + off;
        off += (bytes + 255) & ~(size_t)255;
        return p;
    };
    u16*   bufX   = (u16*)  alloc((size_t)(N + 1) * 128 * 2);
    u16*   bufA   = (u16*)  alloc((size_t)(N + 1) * 128 * 2);
    u16*   bufB   = (u16*)  alloc((size_t)(N + 1) * 128 * 2);
    float* dis    = (float*)alloc((size_t)N * 4);
    int*   rowptr = (int*)  alloc((size_t)(N + 1) * 4);
    int*   csr    = (int*)  alloc(((size_t)E + 3 * (size_t)N + 8) * 4);
    int*   tsum   = (int*)  alloc((size_t)SCAN_THREADS * 4);
    u32*   whi    = (u32*)  alloc(3 * 2048 * 16);
    u32*   wlo    = (u32*)  alloc(3 * 2048 * 16);
    size_t zoff   = off;
    int*   cnt    = (int*)  alloc((size_t)N * 4);
    size_t zbytes = off - zoff;

    // aliases into dead regions:
    int*   rank   = (int*)bufB;      // live between k_count and k_fill, before
                                     // bufB's first write (k_cast zero-row)
    float* tmpC   = (float*)bufX;    // (N+1)x16 fp32; live after bufX is dead
    float* nodeP  = (float*)bufB;    // N x 16 fp32; live after bufB is dead
                                     // (post 3rd k_fused)

    hipMemsetAsync(cnt, 0, zbytes, stream);

    const int* rowi = ei;       // edge_index[0] = source
    const int* coli = ei + E;   // edge_index[1] = target

    int eb = (E + 255) / 256;
    k_count<<<eb, 256, 0, stream>>>(coli, E, cnt, rank);
    k_scan1<<<SCAN_BLOCKS, 256, 0, stream>>>(cnt, tsum, N);
    k_scan2<<<1, 1024, 0, stream>>>(tsum);
    k_scan3<<<SCAN_BLOCKS, 256, 0, stream>>>(cnt, tsum, rowptr, dis, csr, N);
    k_fill<<<eb, 256, 0, stream>>>(rowi, coli, E, rowptr, rank, csr);

    k_wprep3<<<24, 256, 0, stream>>>(W_init, W_h0, W_h1, whi, wlo);

    int cg = ((N + 1) * 32 + 255) / 256;
    k_cast<<<cg, 256, 0, stream>>>(x, dis, bufX, bufA, bufB, N);

    int fb = (N + 31) / 32;
    int ob = (N + 15) / 16;

    // hidden layers (activations stored as dis*h except the last)
    k_fused<<<fb, 256, 0, stream>>>(bufX, whi,         wlo,         b_init, bufA, rowptr, csr, dis, N, 1);
    k_fused<<<fb, 256, 0, stream>>>(bufA, whi + 8192,  wlo + 8192,  b_h0,   bufB, rowptr, csr, dis, N, 1);
    k_fused<<<fb, 256, 0, stream>>>(bufB, whi + 16384, wlo + 16384, b_h1,   bufA, rowptr, csr, dis, N, 0);

    // output head: transform-first (t' = dis*t, stride 16), aggregate, pool
    k_gemmout<<<ob, 256, 0, stream>>>(bufA, W_out, dis, tmpC, N, C);
    k_aggout <<<ob, 256, 0, stream>>>(tmpC, rowptr, csr, dis, nodeP, N);
    k_pool   <<<G, 256, 0, stream>>>(nodeP, batch, b_out, (float*)d_out, N, C);
}

// Round 12
// 506.103 us; speedup vs baseline: 2.5599x; 1.0187x over previous
//
#include <hip/hip_runtime.h>

// ---------------------------------------------------------------------------
// GCN (PyG-style) on MI355X.
//   h = relu(Ahat (h W) + b) x3, then Ahat (h W_out) + b_out, mean-pool.
// R1: hierarchical scan. R2: fusion Ahat(hW)=(Ahat h)W. R3: bf16 activations.
// R4: dis-prescaled activations. R5: padded CSR + paired 16-deep gather.
// R6: MFMA phase B (double-pumped W=Whi+Wlo), rank-based fill.
// R7: aggout 4 nodes/wave, t' = dis*t stride 16.
// R8: no-atomic pooling (segmented reduction over sorted batch).
// R10: gemmout fused into layer-3 k_fused epilogue (h3 -> LDS bf16 ->
//     128->C projection, dis folded), u16 rank.
// R11: resubmit (container infra failure; source audited clean: LDS bounds,
//     uniform barriers, alias liveness all verified).
// ---------------------------------------------------------------------------

#define SCAN_BLOCKS 64
#define SCAN_THREADS (SCAN_BLOCKS * 256)   // 16384

typedef unsigned short u16;
typedef unsigned int   u32;
typedef __attribute__((ext_vector_type(8))) short bf16x8;   // 8 bf16 (4 VGPRs)
typedef __attribute__((ext_vector_type(4))) float f32x4;

static __device__ __forceinline__ u16 f2bf(float x) {
    u32 u = __float_as_uint(x);
    u32 r = (u + 0x7fffu + ((u >> 16) & 1u)) >> 16;   // RNE
    return (u16)r;
}
static __device__ __forceinline__ float bf_lo(u32 p) { return __uint_as_float(p << 16); }
static __device__ __forceinline__ float bf_hi(u32 p) { return __uint_as_float(p & 0xffff0000u); }
static __device__ __forceinline__ float bf1(u16 h) { return __uint_as_float((u32)h << 16); }

__global__ __launch_bounds__(256) void k_count(const int* __restrict__ col, int E,
                                               int* __restrict__ cnt,
                                               u16* __restrict__ rank) {
    int e = blockIdx.x * 256 + threadIdx.x;
    if (e < E) rank[e] = (u16)atomicAdd(&cnt[col[e]], 1);
}

__global__ __launch_bounds__(256) void k_scan1(const int* __restrict__ cnt,
                                               int* __restrict__ tsum, int N) {
    int t = blockIdx.x * 256 + threadIdx.x;
    int strip = (N + SCAN_THREADS - 1) / SCAN_THREADS;
    int s0 = t * strip;
    int s1 = s0 + strip; if (s1 > N) s1 = N;
    int s = 0;
    for (int i = s0; i < s1; ++i) s += (cnt[i] + 3) & ~3;
    tsum[t] = s;
}

__global__ __launch_bounds__(1024) void k_scan2(int* __restrict__ tsum) {
    __shared__ int part[1024];
    int t = threadIdx.x;
    int base = t * 16;
    int local[16];
    int s = 0;
    #pragma unroll
    for (int i = 0; i < 16; ++i) { local[i] = tsum[base + i]; s += local[i]; }
    part[t] = s;
    __syncthreads();
    for (int off = 1; off < 1024; off <<= 1) {
        int v = part[t];
        int add = (t >= off) ? part[t - off] : 0;
        __syncthreads();
        part[t] = v + add;
        __syncthreads();
    }
    int run = (t == 0) ? 0 : part[t - 1];
    #pragma unroll
    for (int i = 0; i < 16; ++i) { int c = local[i]; tsum[base + i] = run; run += c; }
}

__global__ __launch_bounds__(256) void k_scan3(const int* __restrict__ cnt,
                                               const int* __restrict__ tsum,
                                               int* __restrict__ rowptr,
                                               float* __restrict__ dis,
                                               int* __restrict__ csr, int N) {
    int t = blockIdx.x * 256 + threadIdx.x;
    int strip = (N + SCAN_THREADS - 1) / SCAN_THREADS;
    int s0 = t * strip;
    int s1 = s0 + strip; if (s1 > N) s1 = N;
    int run = tsum[t];
    for (int i = s0; i < s1; ++i) {
        int c = cnt[i];
        int r = (c + 3) & ~3;
        rowptr[i] = run;
        for (int p = run + c; p < run + r; ++p) csr[p] = N;   // pads -> zero row
        run += r;
        dis[i] = rsqrtf((float)(c + 1));
    }
    if (t == SCAN_THREADS - 1) rowptr[N] = run;
}

// Scatter without atomics: rank captured during k_count.
__global__ __launch_bounds__(256) void k_fill(const int* __restrict__ row,
                                              const int* __restrict__ col, int E,
                                              const int* __restrict__ rowptr,
                                              const u16* __restrict__ rank,
                                              int* __restrict__ csr) {
    int e = blockIdx.x * 256 + threadIdx.x;
    if (e < E) {
        int c = col[e];
        csr[rowptr[c] + (int)rank[e]] = row[e];
    }
}

// fp32 -> bf16 cast pre-scaled by dis[v]; also zeroes dummy row N of all bufs.
__global__ __launch_bounds__(256) void k_cast(const float* __restrict__ src,
                                              const float* __restrict__ dis,
                                              u16* __restrict__ bX,
                                              u16* __restrict__ bA,
                                              u16* __restrict__ bB, int N) {
    int i = blockIdx.x * 256 + threadIdx.x;   // float4-group index over N+1 rows
    int total = (N + 1) * 32;
    if (i >= total) return;
    int v = i >> 5;
    if (v < N) {
        float dv = dis[v];
        float4 val = ((const float4*)src)[i];
        ushort4 o;
        o.x = f2bf(dv * val.x); o.y = f2bf(dv * val.y);
        o.z = f2bf(dv * val.z); o.w = f2bf(dv * val.w);
        ((ushort4*)bX)[i] = o;
    } else {
        ushort4 z = {0, 0, 0, 0};
        ((ushort4*)bX)[i] = z;
        ((ushort4*)bA)[i] = z;
        ((ushort4*)bB)[i] = z;
    }
}

// Pre-swizzle 3 weight matrices (128x128 fp32) into MFMA B-fragment order,
// split hi+lo bf16. One launch, grid 24: blockIdx/8 selects the matrix.
__global__ __launch_bounds__(256) void k_wprep3(const float* __restrict__ W0,
                                                const float* __restrict__ W1,
                                                const float* __restrict__ W2,
                                                u32* __restrict__ whi,
                                                u32* __restrict__ wlo) {
    int which = blockIdx.x >> 3;
    const float* W = (which == 0) ? W0 : (which == 1) ? W1 : W2;
    int t = (blockIdx.x & 7) * 256 + threadIdx.x;   // 0..2047
    int lane = t & 63;
    int nk = t >> 6;
    int k0 = nk & 3;
    int ntile = nk >> 2;
    int n = ntile * 16 + (lane & 15);
    int kbase = k0 * 32 + (lane >> 4) * 8;
    u32 hi[4], lo[4];
    #pragma unroll
    for (int tt = 0; tt < 4; ++tt) {
        float w0 = W[(kbase + 2 * tt) * 128 + n];
        float w1 = W[(kbase + 2 * tt + 1) * 128 + n];
        u16 h0 = f2bf(w0), h1 = f2bf(w1);
        u16 l0 = f2bf(w0 - __uint_as_float((u32)h0 << 16));
        u16 l1 = f2bf(w1 - __uint_as_float((u32)h1 << 16));
        hi[tt] = (u32)h0 | ((u32)h1 << 16);
        lo[tt] = (u32)l0 | ((u32)l1 << 16);
    }
    uint4 qh = {hi[0], hi[1], hi[2], hi[3]};
    uint4 ql = {lo[0], lo[1], lo[2], lo[3]};
    int base = which * 2048;
    ((uint4*)whi)[base + t] = qh;
    ((uint4*)wlo)[base + t] = ql;
}

// Fused hidden layer. hin holds g = dis*h (bf16, N+1 rows, row N zero).
// Phase A: paired 16-deep gather -> packed-bf16 s-tile in LDS (stride 65).
// Phase B: MFMA 16x16x32 bf16, W double-pumped (hi+lo), fp32 acc, bias+relu.
// proj=0: store bf16 activations (scaled by dis if scale_out).
// proj=1: keep h3 in LDS and project 128->C with W_out, write tmpC=dis*(h3 Wout).
__global__ __launch_bounds__(256) void k_fused(const u16* __restrict__ hin,
                                               const u32* __restrict__ whi,
                                               const u32* __restrict__ wlo,
                                               const float* __restrict__ bias,
                                               u16* __restrict__ hout,
                                               const int* __restrict__ rowptr,
                                               const int* __restrict__ csr,
                                               const float* __restrict__ dis,
                                               int N, int scale_out,
                                               int proj,
                                               const float* __restrict__ Wout,
                                               float* __restrict__ tmpC, int C) {
    __shared__ u32 sS[32 * 65];
    __shared__ float dS[32];
    int tid = threadIdx.x;
    int wave = tid >> 6;
    int lane = tid & 63;
    int row0 = blockIdx.x * 32;
    const u32* hin32 = (const u32*)hin;       // row stride 64 dwords
    const int4* csr4 = (const int4*)csr;      // rowptr always multiple of 4

    // ---- Phase A ----
    for (int j = 0; j < 8; j += 2) {
        int va = row0 + wave * 8 + j;
        int vb = va + 1;
        bool hA = va < N, hB = vb < N;
        float ax = 0.f, ay = 0.f, bx = 0.f, by = 0.f;
        int ia = 0, ea = 0, ib = 0, eb = 0;
        float dva = 1.f, dvb = 1.f;
        if (hA) {
            u32 p = hin32[((u32)va << 6) + lane];
            ax = bf_lo(p); ay = bf_hi(p);
            ia = rowptr[va]; ea = rowptr[va + 1];
            dva = dis[va];
        }
        if (hB) {
            u32 p = hin32[((u32)vb << 6) + lane];
            bx = bf_lo(p); by = bf_hi(p);
            ib = rowptr[vb]; eb = rowptr[vb + 1];
            dvb = dis[vb];
        }
        while ((ia + 8 <= ea) & (ib + 8 <= eb)) {
            int4 a0 = csr4[(u32)ia >> 2];
            int4 a1 = csr4[((u32)ia >> 2) + 1];
            int4 b0 = csr4[(u32)ib >> 2];
            int4 b1 = csr4[((u32)ib >> 2) + 1];
            u32 pa0 = hin32[((u32)a0.x << 6) + lane];
            u32 pa1 = hin32[((u32)a0.y << 6) + lane];
            u32 pa2 = hin32[((u32)a0.z << 6) + lane];
            u32 pa3 = hin32[((u32)a0.w << 6) + lane];
            u32 pa4 = hin32[((u32)a1.x << 6) + lane];
            u32 pa5 = hin32[((u32)a1.y << 6) + lane];
            u32 pa6 = hin32[((u32)a1.z << 6) + lane];
            u32 pa7 = hin32[((u32)a1.w << 6) + lane];
            u32 pb0 = hin32[((u32)b0.x << 6) + lane];
            u32 pb1 = hin32[((u32)b0.y << 6) + lane];
            u32 pb2 = hin32[((u32)b0.z << 6) + lane];
            u32 pb3 = hin32[((u32)b0.w << 6) + lane];
            u32 pb4 = hin32[((u32)b1.x << 6) + lane];
            u32 pb5 = hin32[((u32)b1.y << 6) + lane];
            u32 pb6 = hin32[((u32)b1.z << 6) + lane];
            u32 pb7 = hin32[((u32)b1.w << 6) + lane];
            ax += bf_lo(pa0) + bf_lo(pa1) + bf_lo(pa2) + bf_lo(pa3);
            ay += bf_hi(pa0) + bf_hi(pa1) + bf_hi(pa2) + bf_hi(pa3);
            ax += bf_lo(pa4) + bf_lo(pa5) + bf_lo(pa6) + bf_lo(pa7);
            ay += bf_hi(pa4) + bf_hi(pa5) + bf_hi(pa6) + bf_hi(pa7);
            bx += bf_lo(pb0) + bf_lo(pb1) + bf_lo(pb2) + bf_lo(pb3);
            by += bf_hi(pb0) + bf_hi(pb1) + bf_hi(pb2) + bf_hi(pb3);
            bx += bf_lo(pb4) + bf_lo(pb5) + bf_lo(pb6) + bf_lo(pb7);
            by += bf_hi(pb4) + bf_hi(pb5) + bf_hi(pb6) + bf_hi(pb7);
            ia += 8; ib += 8;
        }
        while (ia + 8 <= ea) {
            int4 a0 = csr4[(u32)ia >> 2];
            int4 a1 = csr4[((u32)ia >> 2) + 1];
            u32 p0 = hin32[((u32)a0.x << 6) + lane];
            u32 p1 = hin32[((u32)a0.y << 6) + lane];
            u32 p2 = hin32[((u32)a0.z << 6) + lane];
            u32 p3 = hin32[((u32)a0.w << 6) + lane];
            u32 p4 = hin32[((u32)a1.x << 6) + lane];
            u32 p5 = hin32[((u32)a1.y << 6) + lane];
            u32 p6 = hin32[((u32)a1.z << 6) + lane];
            u32 p7 = hin32[((u32)a1.w << 6) + lane];
            ax += bf_lo(p0) + bf_lo(p1) + bf_lo(p2) + bf_lo(p3);
            ay += bf_hi(p0) + bf_hi(p1) + bf_hi(p2) + bf_hi(p3);
            ax += bf_lo(p4) + bf_lo(p5) + bf_lo(p6) + bf_lo(p7);
            ay += bf_hi(p4) + bf_hi(p5) + bf_hi(p6) + bf_hi(p7);
            ia += 8;
        }
        if (ia < ea) {
            int4 a0 = csr4[(u32)ia >> 2];
            u32 p0 = hin32[((u32)a0.x << 6) + lane];
            u32 p1 = hin32[((u32)a0.y << 6) + lane];
            u32 p2 = hin32[((u32)a0.z << 6) + lane];
            u32 p3 = hin32[((u32)a0.w << 6) + lane];
            ax += bf_lo(p0) + bf_lo(p1) + bf_lo(p2) + bf_lo(p3);
            ay += bf_hi(p0) + bf_hi(p1) + bf_hi(p2) + bf_hi(p3);
        }
        while (ib + 8 <= eb) {
            int4 b0 = csr4[(u32)ib >> 2];
            int4 b1 = csr4[((u32)ib >> 2) + 1];
            u32 p0 = hin32[((u32)b0.x << 6) + lane];
            u32 p1 = hin32[((u32)b0.y << 6) + lane];
            u32 p2 = hin32[((u32)b0.z << 6) + lane];
            u32 p3 = hin32[((u32)b0.w << 6) + lane];
            u32 p4 = hin32[((u32)b1.x << 6) + lane];
            u32 p5 = hin32[((u32)b1.y << 6) + lane];
            u32 p6 = hin32[((u32)b1.z << 6) + lane];
            u32 p7 = hin32[((u32)b1.w << 6) + lane];
            bx += bf_lo(p0) + bf_lo(p1) + bf_lo(p2) + bf_lo(p3);
            by += bf_hi(p0) + bf_hi(p1) + bf_hi(p2) + bf_hi(p3);
            bx += bf_lo(p4) + bf_lo(p5) + bf_lo(p6) + bf_lo(p7);
            by += bf_hi(p4) + bf_hi(p5) + bf_hi(p6) + bf_hi(p7);
            ib += 8;
        }
        if (ib < eb) {
            int4 b0 = csr4[(u32)ib >> 2];
            u32 p0 = hin32[((u32)b0.x << 6) + lane];
            u32 p1 = hin32[((u32)b0.y << 6) + lane];
            u32 p2 = hin32[((u32)b0.z << 6) + lane];
            u32 p3 = hin32[((u32)b0.w << 6) + lane];
            bx += bf_lo(p0) + bf_lo(p1) + bf_lo(p2) + bf_lo(p3);
            by += bf_hi(p0) + bf_hi(p1) + bf_hi(p2) + bf_hi(p3);
        }
        if (hA) {
            sS[(wave * 8 + j) * 65 + lane] =
                (u32)f2bf(dva * ax) | ((u32)f2bf(dva * ay) << 16);
            if (lane == 0) dS[wave * 8 + j] = dva;
        }
        if (hB) {
            sS[(wave * 8 + j + 1) * 65 + lane] =
                (u32)f2bf(dvb * bx) | ((u32)f2bf(dvb * by) << 16);
            if (lane == 0) dS[wave * 8 + j + 1] = dvb;
        }
    }
    __syncthreads();

    // ---- Phase B: MFMA. Wave handles col-tiles {2w, 2w+1} x row-tiles {0,1}.
    f32x4 acc[2][2] = {{{0.f,0.f,0.f,0.f},{0.f,0.f,0.f,0.f}},
                       {{0.f,0.f,0.f,0.f},{0.f,0.f,0.f,0.f}}};
    int mA = lane & 15;
    int qA = lane >> 4;
    #pragma unroll
    for (int k0 = 0; k0 < 4; ++k0) {
        union { u32 u[4]; bf16x8 v; } A0, A1;
        int ub = k0 * 16 + qA * 4;
        #pragma unroll
        for (int tt = 0; tt < 4; ++tt) {
            A0.u[tt] = sS[mA * 65 + ub + tt];
            A1.u[tt] = sS[(mA + 16) * 65 + ub + tt];
        }
        #pragma unroll
        for (int ct = 0; ct < 2; ++ct) {
            int ntk = ((2 * wave + ct) * 4 + k0) * 64 + lane;
            union { uint4 q; bf16x8 v; } BH, BL;
            BH.q = ((const uint4*)whi)[ntk];
            BL.q = ((const uint4*)wlo)[ntk];
            acc[0][ct] = __builtin_amdgcn_mfma_f32_16x16x32_bf16(A0.v, BH.v, acc[0][ct], 0, 0, 0);
            acc[0][ct] = __builtin_amdgcn_mfma_f32_16x16x32_bf16(A0.v, BL.v, acc[0][ct], 0, 0, 0);
            acc[1][ct] = __builtin_amdgcn_mfma_f32_16x16x32_bf16(A1.v, BH.v, acc[1][ct], 0, 0, 0);
            acc[1][ct] = __builtin_amdgcn_mfma_f32_16x16x32_bf16(A1.v, BL.v, acc[1][ct], 0, 0, 0);
        }
    }

    if (!proj) {
        // epilogue: D[col=lane&15, row=(lane>>4)*4+reg], bias+relu, bf16 store
        #pragma unroll
        for (int rt = 0; rt < 2; ++rt) {
            #pragma unroll
            for (int ct = 0; ct < 2; ++ct) {
                int col = (2 * wave + ct) * 16 + (lane & 15);
                float bb = bias[col];
                #pragma unroll
                for (int r = 0; r < 4; ++r) {
                    int rloc = rt * 16 + (lane >> 4) * 4 + r;
                    int row = row0 + rloc;
                    if (row < N) {
                        float o = fmaxf(acc[rt][ct][r] + bb, 0.f);
                        if (scale_out) o *= dS[rloc];
                        hout[((u32)row << 7) + col] = f2bf(o);
                    }
                }
            }
        }
    } else {
        // h3 (bf16, identical rounding to the old store) -> LDS, then project.
        __syncthreads();   // all waves done reading sS
        u16* hS16 = (u16*)sS;   // view as [32][130]
        #pragma unroll
        for (int rt = 0; rt < 2; ++rt) {
            #pragma unroll
            for (int ct = 0; ct < 2; ++ct) {
                int col = (2 * wave + ct) * 16 + (lane & 15);
                float bb = bias[col];
                #pragma unroll
                for (int r = 0; r < 4; ++r) {
                    int rloc = rt * 16 + (lane >> 4) * 4 + r;
                    hS16[rloc * 130 + col] = f2bf(fmaxf(acc[rt][ct][r] + bb, 0.f));
                }
            }
        }
        __syncthreads();
        int c = tid & 15;
        int rl = tid >> 4;   // 0..15
        #pragma unroll
        for (int half = 0; half < 2; ++half) {
            int rr = rl + 16 * half;
            int row = row0 + rr;
            if (row < N) {
                float a2 = 0.f;
                if (c < C) {
                    #pragma unroll 8
                    for (int k = 0; k < 128; ++k)
                        a2 += bf1(hS16[rr * 130 + k]) * Wout[k * C + c];
                    a2 *= dS[rr];   // t' = dis * (h3 Wout)
                }
                tmpC[((u32)row << 4) + c] = a2;
            }
        }
        if (blockIdx.x == 0 && tid < 16) tmpC[((u32)N << 4) + tid] = 0.f;  // dummy
    }
}

// Last-layer aggregate over t' = dis*t (stride 16, row N = zeros).
// Wave = 4 groups x 16 feature lanes; each group one node, 8-deep unroll over
// the PADDED csr. Plain coalesced store of the per-node row — NO atomics.
__global__ __launch_bounds__(256) void k_aggout(const float* __restrict__ tp,
                                                const int* __restrict__ rowptr,
                                                const int* __restrict__ csr,
                                                const float* __restrict__ dis,
                                                float* __restrict__ node,
                                                int N) {
    int tid = threadIdx.x;
    int wave = tid >> 6;
    int lane = tid & 63;
    int g = lane >> 4;
    int c = lane & 15;
    int v = blockIdx.x * 16 + wave * 4 + g;
    if (v >= N) return;
    const int4* csr4 = (const int4*)csr;
    float acc = tp[((u32)v << 4) + c];          // self term (t'_v)
    int i = rowptr[v], e = rowptr[v + 1];
    for (; i + 8 <= e; i += 8) {
        int4 q0 = csr4[(u32)i >> 2];
        int4 q1 = csr4[((u32)i >> 2) + 1];
        float p0 = tp[((u32)q0.x << 4) + c];
        float p1 = tp[((u32)q0.y << 4) + c];
        float p2 = tp[((u32)q0.z << 4) + c];
        float p3 = tp[((u32)q0.w << 4) + c];
        float p4 = tp[((u32)q1.x << 4) + c];
        float p5 = tp[((u32)q1.y << 4) + c];
        float p6 = tp[((u32)q1.z << 4) + c];
        float p7 = tp[((u32)q1.w << 4) + c];
        acc += p0 + p1 + p2 + p3 + p4 + p5 + p6 + p7;
    }
    if (i < e) {   // remainder is exactly 4
        int4 q0 = csr4[(u32)i >> 2];
        float p0 = tp[((u32)q0.x << 4) + c];
        float p1 = tp[((u32)q0.y << 4) + c];
        float p2 = tp[((u32)q0.z << 4) + c];
        float p3 = tp[((u32)q0.w << 4) + c];
        acc += p0 + p1 + p2 + p3;
    }
    node[((u32)v << 4) + c] = dis[v] * acc;     // bias folded into k_pool
}

// Block-per-graph mean pool over the sorted batch: binary-searched range,
// strided coalesced sum, LDS tree reduce. out = (sum + cnt*b)/max(cnt,1).
__global__ __launch_bounds__(256) void k_pool(const float* __restrict__ node,
                                              const int* __restrict__ batch,
                                              const float* __restrict__ bout,
                                              float* __restrict__ out,
                                              int N, int C) {
    __shared__ float red[256];
    int g = blockIdx.x;
    int tid = threadIdx.x;
    int c = tid & 15;
    int rg = tid >> 4;
    int lo = 0, hi = N;
    while (lo < hi) { int m = (lo + hi) >> 1; if (batch[m] < g) lo = m + 1; else hi = m; }
    int lb = lo;
    hi = N;
    while (lo < hi) { int m = (lo + hi) >> 1; if (batch[m] <= g) lo = m + 1; else hi = m; }
    int ub = lo;
    float acc = 0.f;
    for (int v = lb + rg; v < ub; v += 16)
        acc += node[((u32)v << 4) + c];
    red[tid] = acc;
    __syncthreads();
    #pragma unroll
    for (int s = 8; s >= 1; s >>= 1) {
        if (rg < s) red[tid] += red[tid + s * 16];
        __syncthreads();
    }
    if (tid < C) {
        float cnt = (float)(ub - lb);
        out[g * C + tid] = (red[tid] + cnt * bout[tid]) / fmaxf(cnt, 1.0f);
    }
}

extern "C" void kernel_launch(void* const* d_in, const int* in_sizes, int n_in,
                              void* d_out, int out_size, void* d_ws, size_t ws_size,
                              hipStream_t stream) {
    const float* x      = (const float*)d_in[0];
    const int*   ei     = (const int*)d_in[1];
    const int*   batch  = (const int*)d_in[2];
    const float* W_init = (const float*)d_in[3];
    const float* b_init = (const float*)d_in[4];
    const float* W_h0   = (const float*)d_in[5];
    const float* b_h0   = (const float*)d_in[6];
    const float* W_h1   = (const float*)d_in[7];
    const float* b_h1   = (const float*)d_in[8];
    const float* W_out  = (const float*)d_in[9];
    const float* b_out  = (const float*)d_in[10];

    int N = in_sizes[0] / 128;
    int E = in_sizes[1] / 2;
    int C = in_sizes[10];
    int G = out_size / C;

    size_t off = 0;
    auto alloc = [&](size_t bytes) -> char* {
        char* p = (char*)d_ws + off;
        off += (bytes + 255) & ~(size_t)255;
        return p;
    };
    u16*   bufX   = (u16*)  alloc((size_t)(N + 1) * 128 * 2);
    u16*   bufA   = (u16*)  alloc((size_t)(N + 1) * 128 * 2);
    u16*   bufB   = (u16*)  alloc((size_t)(N + 1) * 128 * 2);
    float* dis    = (float*)alloc((size_t)N * 4);
    int*   rowptr = (int*)  alloc((size_t)(N + 1) * 4);
    int*   csr    = (int*)  alloc(((size_t)E + 3 * (size_t)N + 8) * 4);
    int*   tsum   = (int*)  alloc((size_t)SCAN_THREADS * 4);
    u32*   whi    = (u32*)  alloc(3 * 2048 * 16);
    u32*   wlo    = (u32*)  alloc(3 * 2048 * 16);
    size_t zoff   = off;
    int*   cnt    = (int*)  alloc((size_t)N * 4);
    size_t zbytes = off - zoff;

    // aliases into dead regions:
    u16*   rank   = (u16*)bufB;      // live between k_count and k_fill, before
                                     // bufB's first write (k_cast zero-row)
    float* tmpC   = (float*)bufX;    // (N+1)x16 fp32; live after bufX is dead
    float* nodeP  = (float*)bufB;    // N x 16 fp32; live after bufB is dead
                                     // (post 3rd k_fused)

    hipMemsetAsync(cnt, 0, zbytes, stream);

    const int* rowi = ei;       // edge_index[0] = source
    const int* coli = ei + E;   // edge_index[1] = target

    int eb = (E + 255) / 256;
    k_count<<<eb, 256, 0, stream>>>(coli, E, cnt, rank);
    k_scan1<<<SCAN_BLOCKS, 256, 0, stream>>>(cnt, tsum, N);
    k_scan2<<<1, 1024, 0, stream>>>(tsum);
    k_scan3<<<SCAN_BLOCKS, 256, 0, stream>>>(cnt, tsum, rowptr, dis, csr, N);
    k_fill<<<eb, 256, 0, stream>>>(rowi, coli, E, rowptr, rank, csr);

    k_wprep3<<<24, 256, 0, stream>>>(W_init, W_h0, W_h1, whi, wlo);

    int cg = ((N + 1) * 32 + 255) / 256;
    k_cast<<<cg, 256, 0, stream>>>(x, dis, bufX, bufA, bufB, N);

    int fb = (N + 31) / 32;
    int ob = (N + 15) / 16;

    // hidden layers (activations stored as dis*h except the last)
    k_fused<<<fb, 256, 0, stream>>>(bufX, whi,         wlo,         b_init, bufA, rowptr, csr, dis, N, 1, 0, nullptr, nullptr, C);
    k_fused<<<fb, 256, 0, stream>>>(bufA, whi + 8192,  wlo + 8192,  b_h0,   bufB, rowptr, csr, dis, N, 1, 0, nullptr, nullptr, C);
    // layer 3 + fused 128->C projection: writes tmpC = dis*(h3 Wout) directly
    k_fused<<<fb, 256, 0, stream>>>(bufB, whi + 16384, wlo + 16384, b_h1,   bufA, rowptr, csr, dis, N, 0, 1, W_out, tmpC, C);

    // output head: aggregate, pool
    k_aggout <<<ob, 256, 0, stream>>>(tmpC, rowptr, csr, dis, nodeP, N);
    k_pool   <<<G, 256, 0, stream>>>(nodeP, batch, b_out, (float*)d_out, N, C);
}

// Round 13
// 498.378 us; speedup vs baseline: 2.5995x; 1.0155x over previous
//
#include <hip/hip_runtime.h>

// ---------------------------------------------------------------------------
// GCN (PyG-style) on MI355X.
//   h = relu(Ahat (h W) + b) x3, then Ahat (h W_out) + b_out, mean-pool.
// R1: hierarchical scan. R2: fusion Ahat(hW)=(Ahat h)W. R3: bf16 activations.
// R4: dis-prescaled activations. R5: padded CSR + paired 16-deep gather.
// R6: MFMA phase B (double-pumped W=Whi+Wlo), rank-based fill.
// R8: no-atomic pooling. R10: proj fused into layer-3.
// R12 post-mortem: scalar-LDS projection cost 18us (99 vs 81us/layer).
// R13: projection on MFMA too (h3 -> LDS stride-136 bf16, A=ds_read_b128,
//     Wout pre-swizzled hi+lo zero-padded to 16 cols; waves 0-1, 16 MFMAs).
//     aggout+pool merged into block-per-graph k_aggpool (no nodeP roundtrip).
// ---------------------------------------------------------------------------

#define SCAN_BLOCKS 64
#define SCAN_THREADS (SCAN_BLOCKS * 256)   // 16384

typedef unsigned short u16;
typedef unsigned int   u32;
typedef __attribute__((ext_vector_type(8))) short bf16x8;   // 8 bf16 (4 VGPRs)
typedef __attribute__((ext_vector_type(4))) float f32x4;

static __device__ __forceinline__ u16 f2bf(float x) {
    u32 u = __float_as_uint(x);
    u32 r = (u + 0x7fffu + ((u >> 16) & 1u)) >> 16;   // RNE
    return (u16)r;
}
static __device__ __forceinline__ float bf_lo(u32 p) { return __uint_as_float(p << 16); }
static __device__ __forceinline__ float bf_hi(u32 p) { return __uint_as_float(p & 0xffff0000u); }

__global__ __launch_bounds__(256) void k_count(const int* __restrict__ col, int E,
                                               int* __restrict__ cnt,
                                               u16* __restrict__ rank) {
    int e = blockIdx.x * 256 + threadIdx.x;
    if (e < E) rank[e] = (u16)atomicAdd(&cnt[col[e]], 1);
}

__global__ __launch_bounds__(256) void k_scan1(const int* __restrict__ cnt,
                                               int* __restrict__ tsum, int N) {
    int t = blockIdx.x * 256 + threadIdx.x;
    int strip = (N + SCAN_THREADS - 1) / SCAN_THREADS;
    int s0 = t * strip;
    int s1 = s0 + strip; if (s1 > N) s1 = N;
    int s = 0;
    for (int i = s0; i < s1; ++i) s += (cnt[i] + 3) & ~3;
    tsum[t] = s;
}

__global__ __launch_bounds__(1024) void k_scan2(int* __restrict__ tsum) {
    __shared__ int part[1024];
    int t = threadIdx.x;
    int base = t * 16;
    int local[16];
    int s = 0;
    #pragma unroll
    for (int i = 0; i < 16; ++i) { local[i] = tsum[base + i]; s += local[i]; }
    part[t] = s;
    __syncthreads();
    for (int off = 1; off < 1024; off <<= 1) {
        int v = part[t];
        int add = (t >= off) ? part[t - off] : 0;
        __syncthreads();
        part[t] = v + add;
        __syncthreads();
    }
    int run = (t == 0) ? 0 : part[t - 1];
    #pragma unroll
    for (int i = 0; i < 16; ++i) { int c = local[i]; tsum[base + i] = run; run += c; }
}

__global__ __launch_bounds__(256) void k_scan3(const int* __restrict__ cnt,
                                               const int* __restrict__ tsum,
                                               int* __restrict__ rowptr,
                                               float* __restrict__ dis,
                                               int* __restrict__ csr, int N) {
    int t = blockIdx.x * 256 + threadIdx.x;
    int strip = (N + SCAN_THREADS - 1) / SCAN_THREADS;
    int s0 = t * strip;
    int s1 = s0 + strip; if (s1 > N) s1 = N;
    int run = tsum[t];
    for (int i = s0; i < s1; ++i) {
        int c = cnt[i];
        int r = (c + 3) & ~3;
        rowptr[i] = run;
        for (int p = run + c; p < run + r; ++p) csr[p] = N;   // pads -> zero row
        run += r;
        dis[i] = rsqrtf((float)(c + 1));
    }
    if (t == SCAN_THREADS - 1) rowptr[N] = run;
}

// Scatter without atomics: rank captured during k_count.
__global__ __launch_bounds__(256) void k_fill(const int* __restrict__ row,
                                              const int* __restrict__ col, int E,
                                              const int* __restrict__ rowptr,
                                              const u16* __restrict__ rank,
                                              int* __restrict__ csr) {
    int e = blockIdx.x * 256 + threadIdx.x;
    if (e < E) {
        int c = col[e];
        csr[rowptr[c] + (int)rank[e]] = row[e];
    }
}

// fp32 -> bf16 cast pre-scaled by dis[v]; also zeroes dummy row N of all bufs.
__global__ __launch_bounds__(256) void k_cast(const float* __restrict__ src,
                                              const float* __restrict__ dis,
                                              u16* __restrict__ bX,
                                              u16* __restrict__ bA,
                                              u16* __restrict__ bB, int N) {
    int i = blockIdx.x * 256 + threadIdx.x;   // float4-group index over N+1 rows
    int total = (N + 1) * 32;
    if (i >= total) return;
    int v = i >> 5;
    if (v < N) {
        float dv = dis[v];
        float4 val = ((const float4*)src)[i];
        ushort4 o;
        o.x = f2bf(dv * val.x); o.y = f2bf(dv * val.y);
        o.z = f2bf(dv * val.z); o.w = f2bf(dv * val.w);
        ((ushort4*)bX)[i] = o;
    } else {
        ushort4 z = {0, 0, 0, 0};
        ((ushort4*)bX)[i] = z;
        ((ushort4*)bA)[i] = z;
        ((ushort4*)bB)[i] = z;
    }
}

// Pre-swizzle weights into MFMA B-fragment order, split hi+lo bf16.
// Blocks 0..23: the three 128x128 W (8 blocks each). Block 24: Wout 128xC
// zero-padded to 16 cols, stored at uint4 offset 6144.
__global__ __launch_bounds__(256) void k_wprep4(const float* __restrict__ W0,
                                                const float* __restrict__ W1,
                                                const float* __restrict__ W2,
                                                const float* __restrict__ Wo,
                                                u32* __restrict__ whi,
                                                u32* __restrict__ wlo, int C) {
    if (blockIdx.x < 24) {
        int which = blockIdx.x >> 3;
        const float* W = (which == 0) ? W0 : (which == 1) ? W1 : W2;
        int t = (blockIdx.x & 7) * 256 + threadIdx.x;   // 0..2047
        int lane = t & 63;
        int nk = t >> 6;
        int k0 = nk & 3;
        int ntile = nk >> 2;
        int n = ntile * 16 + (lane & 15);
        int kbase = k0 * 32 + (lane >> 4) * 8;
        u32 hi[4], lo[4];
        #pragma unroll
        for (int tt = 0; tt < 4; ++tt) {
            float w0 = W[(kbase + 2 * tt) * 128 + n];
            float w1 = W[(kbase + 2 * tt + 1) * 128 + n];
            u16 h0 = f2bf(w0), h1 = f2bf(w1);
            u16 l0 = f2bf(w0 - __uint_as_float((u32)h0 << 16));
            u16 l1 = f2bf(w1 - __uint_as_float((u32)h1 << 16));
            hi[tt] = (u32)h0 | ((u32)h1 << 16);
            lo[tt] = (u32)l0 | ((u32)l1 << 16);
        }
        uint4 qh = {hi[0], hi[1], hi[2], hi[3]};
        uint4 ql = {lo[0], lo[1], lo[2], lo[3]};
        int base = which * 2048;
        ((uint4*)whi)[base + t] = qh;
        ((uint4*)wlo)[base + t] = ql;
    } else {
        int t = threadIdx.x;       // 0..255 == k0*64 + lane
        int lane = t & 63;
        int k0 = t >> 6;
        int n = lane & 15;
        int kbase = k0 * 32 + (lane >> 4) * 8;
        bool vc = (n < C);
        u32 hi[4], lo[4];
        #pragma unroll
        for (int tt = 0; tt < 4; ++tt) {
            float w0 = vc ? Wo[(kbase + 2 * tt) * C + n] : 0.f;
            float w1 = vc ? Wo[(kbase + 2 * tt + 1) * C + n] : 0.f;
            u16 h0 = f2bf(w0), h1 = f2bf(w1);
            u16 l0 = f2bf(w0 - __uint_as_float((u32)h0 << 16));
            u16 l1 = f2bf(w1 - __uint_as_float((u32)h1 << 16));
            hi[tt] = (u32)h0 | ((u32)h1 << 16);
            lo[tt] = (u32)l0 | ((u32)l1 << 16);
        }
        uint4 qh = {hi[0], hi[1], hi[2], hi[3]};
        uint4 ql = {lo[0], lo[1], lo[2], lo[3]};
        ((uint4*)whi)[6144 + t] = qh;
        ((uint4*)wlo)[6144 + t] = ql;
    }
}

// Fused hidden layer. hin holds g = dis*h (bf16, N+1 rows, row N zero).
// Phase A: paired 16-deep gather -> packed-bf16 s-tile in LDS (stride 65).
// Phase B: MFMA 16x16x32 bf16, W double-pumped (hi+lo), fp32 acc, bias+relu.
// proj=0: store bf16 activations (scaled by dis if scale_out).
// proj=1: h3 -> LDS (u16 stride 136, 16B-aligned rows) -> MFMA projection
//         with pre-swizzled Wout (pwhi/pwlo), write tmpC = dis*(h3 Wout).
__global__ __launch_bounds__(256) void k_fused(const u16* __restrict__ hin,
                                               const u32* __restrict__ whi,
                                               const u32* __restrict__ wlo,
                                               const float* __restrict__ bias,
                                               u16* __restrict__ hout,
                                               const int* __restrict__ rowptr,
                                               const int* __restrict__ csr,
                                               const float* __restrict__ dis,
                                               int N, int scale_out,
                                               int proj,
                                               const u32* __restrict__ pwhi,
                                               const u32* __restrict__ pwlo,
                                               float* __restrict__ tmpC) {
    __shared__ u32 sS[32 * 68];   // phase A/B: stride-65 u32; proj: stride-136 u16
    __shared__ float dS[32];
    int tid = threadIdx.x;
    int wave = tid >> 6;
    int lane = tid & 63;
    int row0 = blockIdx.x * 32;
    const u32* hin32 = (const u32*)hin;       // row stride 64 dwords
    const int4* csr4 = (const int4*)csr;      // rowptr always multiple of 4

    // ---- Phase A ----
    for (int j = 0; j < 8; j += 2) {
        int va = row0 + wave * 8 + j;
        int vb = va + 1;
        bool hA = va < N, hB = vb < N;
        float ax = 0.f, ay = 0.f, bx = 0.f, by = 0.f;
        int ia = 0, ea = 0, ib = 0, eb = 0;
        float dva = 1.f, dvb = 1.f;
        if (hA) {
            u32 p = hin32[((u32)va << 6) + lane];
            ax = bf_lo(p); ay = bf_hi(p);
            ia = rowptr[va]; ea = rowptr[va + 1];
            dva = dis[va];
        }
        if (hB) {
            u32 p = hin32[((u32)vb << 6) + lane];
            bx = bf_lo(p); by = bf_hi(p);
            ib = rowptr[vb]; eb = rowptr[vb + 1];
            dvb = dis[vb];
        }
        while ((ia + 8 <= ea) & (ib + 8 <= eb)) {
            int4 a0 = csr4[(u32)ia >> 2];
            int4 a1 = csr4[((u32)ia >> 2) + 1];
            int4 b0 = csr4[(u32)ib >> 2];
            int4 b1 = csr4[((u32)ib >> 2) + 1];
            u32 pa0 = hin32[((u32)a0.x << 6) + lane];
            u32 pa1 = hin32[((u32)a0.y << 6) + lane];
            u32 pa2 = hin32[((u32)a0.z << 6) + lane];
            u32 pa3 = hin32[((u32)a0.w << 6) + lane];
            u32 pa4 = hin32[((u32)a1.x << 6) + lane];
            u32 pa5 = hin32[((u32)a1.y << 6) + lane];
            u32 pa6 = hin32[((u32)a1.z << 6) + lane];
            u32 pa7 = hin32[((u32)a1.w << 6) + lane];
            u32 pb0 = hin32[((u32)b0.x << 6) + lane];
            u32 pb1 = hin32[((u32)b0.y << 6) + lane];
            u32 pb2 = hin32[((u32)b0.z << 6) + lane];
            u32 pb3 = hin32[((u32)b0.w << 6) + lane];
            u32 pb4 = hin32[((u32)b1.x << 6) + lane];
            u32 pb5 = hin32[((u32)b1.y << 6) + lane];
            u32 pb6 = hin32[((u32)b1.z << 6) + lane];
            u32 pb7 = hin32[((u32)b1.w << 6) + lane];
            ax += bf_lo(pa0) + bf_lo(pa1) + bf_lo(pa2) + bf_lo(pa3);
            ay += bf_hi(pa0) + bf_hi(pa1) + bf_hi(pa2) + bf_hi(pa3);
            ax += bf_lo(pa4) + bf_lo(pa5) + bf_lo(pa6) + bf_lo(pa7);
            ay += bf_hi(pa4) + bf_hi(pa5) + bf_hi(pa6) + bf_hi(pa7);
            bx += bf_lo(pb0) + bf_lo(pb1) + bf_lo(pb2) + bf_lo(pb3);
            by += bf_hi(pb0) + bf_hi(pb1) + bf_hi(pb2) + bf_hi(pb3);
            bx += bf_lo(pb4) + bf_lo(pb5) + bf_lo(pb6) + bf_lo(pb7);
            by += bf_hi(pb4) + bf_hi(pb5) + bf_hi(pb6) + bf_hi(pb7);
            ia += 8; ib += 8;
        }
        while (ia + 8 <= ea) {
            int4 a0 = csr4[(u32)ia >> 2];
            int4 a1 = csr4[((u32)ia >> 2) + 1];
            u32 p0 = hin32[((u32)a0.x << 6) + lane];
            u32 p1 = hin32[((u32)a0.y << 6) + lane];
            u32 p2 = hin32[((u32)a0.z << 6) + lane];
            u32 p3 = hin32[((u32)a0.w << 6) + lane];
            u32 p4 = hin32[((u32)a1.x << 6) + lane];
            u32 p5 = hin32[((u32)a1.y << 6) + lane];
            u32 p6 = hin32[((u32)a1.z << 6) + lane];
            u32 p7 = hin32[((u32)a1.w << 6) + lane];
            ax += bf_lo(p0) + bf_lo(p1) + bf_lo(p2) + bf_lo(p3);
            ay += bf_hi(p0) + bf_hi(p1) + bf_hi(p2) + bf_hi(p3);
            ax += bf_lo(p4) + bf_lo(p5) + bf_lo(p6) + bf_lo(p7);
            ay += bf_hi(p4) + bf_hi(p5) + bf_hi(p6) + bf_hi(p7);
            ia += 8;
        }
        if (ia < ea) {
            int4 a0 = csr4[(u32)ia >> 2];
            u32 p0 = hin32[((u32)a0.x << 6) + lane];
            u32 p1 = hin32[((u32)a0.y << 6) + lane];
            u32 p2 = hin32[((u32)a0.z << 6) + lane];
            u32 p3 = hin32[((u32)a0.w << 6) + lane];
            ax += bf_lo(p0) + bf_lo(p1) + bf_lo(p2) + bf_lo(p3);
            ay += bf_hi(p0) + bf_hi(p1) + bf_hi(p2) + bf_hi(p3);
        }
        while (ib + 8 <= eb) {
            int4 b0 = csr4[(u32)ib >> 2];
            int4 b1 = csr4[((u32)ib >> 2) + 1];
            u32 p0 = hin32[((u32)b0.x << 6) + lane];
            u32 p1 = hin32[((u32)b0.y << 6) + lane];
            u32 p2 = hin32[((u32)b0.z << 6) + lane];
            u32 p3 = hin32[((u32)b0.w << 6) + lane];
            u32 p4 = hin32[((u32)b1.x << 6) + lane];
            u32 p5 = hin32[((u32)b1.y << 6) + lane];
            u32 p6 = hin32[((u32)b1.z << 6) + lane];
            u32 p7 = hin32[((u32)b1.w << 6) + lane];
            bx += bf_lo(p0) + bf_lo(p1) + bf_lo(p2) + bf_lo(p3);
            by += bf_hi(p0) + bf_hi(p1) + bf_hi(p2) + bf_hi(p3);
            bx += bf_lo(p4) + bf_lo(p5) + bf_lo(p6) + bf_lo(p7);
            by += bf_hi(p4) + bf_hi(p5) + bf_hi(p6) + bf_hi(p7);
            ib += 8;
        }
        if (ib < eb) {
            int4 b0 = csr4[(u32)ib >> 2];
            u32 p0 = hin32[((u32)b0.x << 6) + lane];
            u32 p1 = hin32[((u32)b0.y << 6) + lane];
            u32 p2 = hin32[((u32)b0.z << 6) + lane];
            u32 p3 = hin32[((u32)b0.w << 6) + lane];
            bx += bf_lo(p0) + bf_lo(p1) + bf_lo(p2) + bf_lo(p3);
            by += bf_hi(p0) + bf_hi(p1) + bf_hi(p2) + bf_hi(p3);
        }
        if (hA) {
            sS[(wave * 8 + j) * 65 + lane] =
                (u32)f2bf(dva * ax) | ((u32)f2bf(dva * ay) << 16);
            if (lane == 0) dS[wave * 8 + j] = dva;
        }
        if (hB) {
            sS[(wave * 8 + j + 1) * 65 + lane] =
                (u32)f2bf(dvb * bx) | ((u32)f2bf(dvb * by) << 16);
            if (lane == 0) dS[wave * 8 + j + 1] = dvb;
        }
    }
    __syncthreads();

    // ---- Phase B: MFMA. Wave handles col-tiles {2w, 2w+1} x row-tiles {0,1}.
    f32x4 acc[2][2] = {{{0.f,0.f,0.f,0.f},{0.f,0.f,0.f,0.f}},
                       {{0.f,0.f,0.f,0.f},{0.f,0.f,0.f,0.f}}};
    int mA = lane & 15;
    int qA = lane >> 4;
    #pragma unroll
    for (int k0 = 0; k0 < 4; ++k0) {
        union { u32 u[4]; bf16x8 v; } A0, A1;
        int ub = k0 * 16 + qA * 4;
        #pragma unroll
        for (int tt = 0; tt < 4; ++tt) {
            A0.u[tt] = sS[mA * 65 + ub + tt];
            A1.u[tt] = sS[(mA + 16) * 65 + ub + tt];
        }
        #pragma unroll
        for (int ct = 0; ct < 2; ++ct) {
            int ntk = ((2 * wave + ct) * 4 + k0) * 64 + lane;
            union { uint4 q; bf16x8 v; } BH, BL;
            BH.q = ((const uint4*)whi)[ntk];
            BL.q = ((const uint4*)wlo)[ntk];
            acc[0][ct] = __builtin_amdgcn_mfma_f32_16x16x32_bf16(A0.v, BH.v, acc[0][ct], 0, 0, 0);
            acc[0][ct] = __builtin_amdgcn_mfma_f32_16x16x32_bf16(A0.v, BL.v, acc[0][ct], 0, 0, 0);
            acc[1][ct] = __builtin_amdgcn_mfma_f32_16x16x32_bf16(A1.v, BH.v, acc[1][ct], 0, 0, 0);
            acc[1][ct] = __builtin_amdgcn_mfma_f32_16x16x32_bf16(A1.v, BL.v, acc[1][ct], 0, 0, 0);
        }
    }

    if (!proj) {
        // epilogue: D[col=lane&15, row=(lane>>4)*4+reg], bias+relu, bf16 store
        #pragma unroll
        for (int rt = 0; rt < 2; ++rt) {
            #pragma unroll
            for (int ct = 0; ct < 2; ++ct) {
                int col = (2 * wave + ct) * 16 + (lane & 15);
                float bb = bias[col];
                #pragma unroll
                for (int r = 0; r < 4; ++r) {
                    int rloc = rt * 16 + (lane >> 4) * 4 + r;
                    int row = row0 + rloc;
                    if (row < N) {
                        float o = fmaxf(acc[rt][ct][r] + bb, 0.f);
                        if (scale_out) o *= dS[rloc];
                        hout[((u32)row << 7) + col] = f2bf(o);
                    }
                }
            }
        }
    } else {
        // h3 (bias+relu, bf16 — same rounding as the old store) -> LDS stride 136
        __syncthreads();   // all waves done reading sS (phase B complete)
        u16* hS16 = (u16*)sS;   // [32][136], rows 16B-aligned (272B stride)
        #pragma unroll
        for (int rt = 0; rt < 2; ++rt) {
            #pragma unroll
            for (int ct = 0; ct < 2; ++ct) {
                int col = (2 * wave + ct) * 16 + (lane & 15);
                float bb = bias[col];
                #pragma unroll
                for (int r = 0; r < 4; ++r) {
                    int rloc = rt * 16 + (lane >> 4) * 4 + r;
                    hS16[rloc * 136 + col] = f2bf(fmaxf(acc[rt][ct][r] + bb, 0.f));
                }
            }
        }
        __syncthreads();
        // MFMA projection: row-tile = wave (0/1), single padded col-tile.
        if (wave < 2) {
            int m = lane & 15;
            int quad = lane >> 4;
            f32x4 a2 = {0.f, 0.f, 0.f, 0.f};
            #pragma unroll
            for (int k0 = 0; k0 < 4; ++k0) {
                bf16x8 Afrag = *(bf16x8*)&hS16[(wave * 16 + m) * 136 + k0 * 32 + quad * 8];
                union { uint4 q; bf16x8 v; } BH, BL;
                BH.q = ((const uint4*)pwhi)[k0 * 64 + lane];
                BL.q = ((const uint4*)pwlo)[k0 * 64 + lane];
                a2 = __builtin_amdgcn_mfma_f32_16x16x32_bf16(Afrag, BH.v, a2, 0, 0, 0);
                a2 = __builtin_amdgcn_mfma_f32_16x16x32_bf16(Afrag, BL.v, a2, 0, 0, 0);
            }
            #pragma unroll
            for (int r = 0; r < 4; ++r) {
                int rloc = wave * 16 + quad * 4 + r;
                int row = row0 + rloc;
                if (row < N) tmpC[((u32)row << 4) + m] = a2[r] * dS[rloc];
            }
        }
        if (blockIdx.x == 0 && tid < 16) tmpC[((u32)N << 4) + tid] = 0.f;  // dummy
    }
}

// Block-per-graph: aggregate t' over padded CSR (zero row soaks pads) and
// mean-pool in one pass. 16 node-groups x 16 feature lanes, LDS tree reduce.
__global__ __launch_bounds__(256) void k_aggpool(const float* __restrict__ tp,
                                                 const int* __restrict__ rowptr,
                                                 const int* __restrict__ csr,
                                                 const float* __restrict__ dis,
                                                 const int* __restrict__ batch,
                                                 const float* __restrict__ bout,
                                                 float* __restrict__ out,
                                                 int N, int C) {
    __shared__ float red[256];
    int g = blockIdx.x;
    int tid = threadIdx.x;
    int c = tid & 15;
    int rg = tid >> 4;
    int lo = 0, hi = N;
    while (lo < hi) { int m = (lo + hi) >> 1; if (batch[m] < g) lo = m + 1; else hi = m; }
    int lb = lo;
    hi = N;
    while (lo < hi) { int m = (lo + hi) >> 1; if (batch[m] <= g) lo = m + 1; else hi = m; }
    int ub = lo;
    const int4* csr4 = (const int4*)csr;
    float pacc = 0.f;
    for (int v = lb + rg; v < ub; v += 16) {
        float acc = tp[((u32)v << 4) + c];      // self term
        int i = rowptr[v], e = rowptr[v + 1];
        for (; i + 8 <= e; i += 8) {
            int4 q0 = csr4[(u32)i >> 2];
            int4 q1 = csr4[((u32)i >> 2) + 1];
            acc += tp[((u32)q0.x << 4) + c] + tp[((u32)q0.y << 4) + c]
                 + tp[((u32)q0.z << 4) + c] + tp[((u32)q0.w << 4) + c]
                 + tp[((u32)q1.x << 4) + c] + tp[((u32)q1.y << 4) + c]
                 + tp[((u32)q1.z << 4) + c] + tp[((u32)q1.w << 4) + c];
        }
        if (i < e) {   // remainder is exactly 4
            int4 q0 = csr4[(u32)i >> 2];
            acc += tp[((u32)q0.x << 4) + c] + tp[((u32)q0.y << 4) + c]
                 + tp[((u32)q0.z << 4) + c] + tp[((u32)q0.w << 4) + c];
        }
        pacc += dis[v] * acc;
    }
    red[tid] = pacc;
    __syncthreads();
    #pragma unroll
    for (int s = 8; s >= 1; s >>= 1) {
        if (rg < s) red[tid] += red[tid + s * 16];
        __syncthreads();
    }
    if (tid < C) {
        float cnt = (float)(ub - lb);
        out[g * C + tid] = (red[tid] + cnt * bout[tid]) / fmaxf(cnt, 1.0f);
    }
}

extern "C" void kernel_launch(void* const* d_in, const int* in_sizes, int n_in,
                              void* d_out, int out_size, void* d_ws, size_t ws_size,
                              hipStream_t stream) {
    const float* x      = (const float*)d_in[0];
    const int*   ei     = (const int*)d_in[1];
    const int*   batch  = (const int*)d_in[2];
    const float* W_init = (const float*)d_in[3];
    const float* b_init = (const float*)d_in[4];
    const float* W_h0   = (const float*)d_in[5];
    const float* b_h0   = (const float*)d_in[6];
    const float* W_h1   = (const float*)d_in[7];
    const float* b_h1   = (const float*)d_in[8];
    const float* W_out  = (const float*)d_in[9];
    const float* b_out  = (const float*)d_in[10];

    int N = in_sizes[0] / 128;
    int E = in_sizes[1] / 2;
    int C = in_sizes[10];
    int G = out_size / C;

    size_t off = 0;
    auto alloc = [&](size_t bytes) -> char* {
        char* p = (char*)d_ws + off;
        off += (bytes + 255) & ~(size_t)255;
        return p;
    };
    u16*   bufX   = (u16*)  alloc((size_t)(N + 1) * 128 * 2);
    u16*   bufA   = (u16*)  alloc((size_t)(N + 1) * 128 * 2);
    u16*   bufB   = (u16*)  alloc((size_t)(N + 1) * 128 * 2);
    float* dis    = (float*)alloc((size_t)N * 4);
    int*   rowptr = (int*)  alloc((size_t)(N + 1) * 4);
    int*   csr    = (int*)  alloc(((size_t)E + 3 * (size_t)N + 8) * 4);
    int*   tsum   = (int*)  alloc((size_t)SCAN_THREADS * 4);
    u32*   whi    = (u32*)  alloc((3 * 2048 + 256) * 16);
    u32*   wlo    = (u32*)  alloc((3 * 2048 + 256) * 16);
    size_t zoff   = off;
    int*   cnt    = (int*)  alloc((size_t)N * 4);
    size_t zbytes = off - zoff;

    // aliases into dead regions:
    u16*   rank   = (u16*)bufB;      // live between k_count and k_fill, before
                                     // bufB's first write (k_cast zero-row)
    float* tmpC   = (float*)bufX;    // (N+1)x16 fp32; live after bufX is dead

    hipMemsetAsync(cnt, 0, zbytes, stream);

    const int* rowi = ei;       // edge_index[0] = source
    const int* coli = ei + E;   // edge_index[1] = target

    int eb = (E + 255) / 256;
    k_count<<<eb, 256, 0, stream>>>(coli, E, cnt, rank);
    k_scan1<<<SCAN_BLOCKS, 256, 0, stream>>>(cnt, tsum, N);
    k_scan2<<<1, 1024, 0, stream>>>(tsum);
    k_scan3<<<SCAN_BLOCKS, 256, 0, stream>>>(cnt, tsum, rowptr, dis, csr, N);
    k_fill<<<eb, 256, 0, stream>>>(rowi, coli, E, rowptr, rank, csr);

    k_wprep4<<<25, 256, 0, stream>>>(W_init, W_h0, W_h1, W_out, whi, wlo, C);

    int cg = ((N + 1) * 32 + 255) / 256;
    k_cast<<<cg, 256, 0, stream>>>(x, dis, bufX, bufA, bufB, N);

    int fb = (N + 31) / 32;

    // hidden layers (activations stored as dis*h except the last)
    k_fused<<<fb, 256, 0, stream>>>(bufX, whi,         wlo,         b_init, bufA, rowptr, csr, dis, N, 1, 0, nullptr, nullptr, nullptr);
    k_fused<<<fb, 256, 0, stream>>>(bufA, whi + 8192,  wlo + 8192,  b_h0,   bufB, rowptr, csr, dis, N, 1, 0, nullptr, nullptr, nullptr);
    // layer 3 + MFMA 128->C projection: writes tmpC = dis*(h3 Wout) directly
    k_fused<<<fb, 256, 0, stream>>>(bufB, whi + 16384, wlo + 16384, b_h1,   bufA, rowptr, csr, dis, N, 0, 1, whi + 24576, wlo + 24576, tmpC);

    // output head: aggregate + pool fused (block per graph, no atomics)
    k_aggpool<<<G, 256, 0, stream>>>(tmpC, rowptr, csr, dis, batch, b_out, (float*)d_out, N, C);
}